// Round 1
// baseline (3905.880 us; speedup 1.0000x reference)
//
#include <hip/hip_runtime.h>
#include <cstdint>
#include <cstddef>

#define N_NODES 50000
#define N_EDGES 800000
#define N_TRIP  800000

__device__ __forceinline__ float silu_f(float x) { return x / (1.f + __expf(-x)); }
__device__ __forceinline__ float sigm_f(float x) { return 1.f / (1.f + __expf(-x)); }

// Accumulate NI4*4 input rows into hacc[64]: hacc[j] += x[i] * W[(base+i)*64 + j]
// Weight rows are wave-uniform (scalar-load friendly); x is per-thread.
#define MAC_CHUNK(NI4, HACC, XPTR, WBASE)                                   \
  for (int i4 = 0; i4 < (NI4); ++i4) {                                      \
    float4 xv = (XPTR)[i4];                                                 \
    const float* __restrict__ Wr = (WBASE) + i4 * 256;                      \
    _Pragma("unroll")                                                       \
    for (int s_ = 0; s_ < 4; ++s_) {                                        \
      float xs = (s_ == 0) ? xv.x : (s_ == 1) ? xv.y : (s_ == 2) ? xv.z : xv.w; \
      _Pragma("unroll")                                                     \
      for (int j_ = 0; j_ < 64; ++j_) (HACC)[j_] += xs * Wr[s_ * 64 + j_];  \
    }                                                                       \
  }

// Dual-accumulator variant (two weight matrices, shared x)
#define MAC_CHUNK_DUAL(NI4, HA, HB, XPTR, WA, WB)                           \
  for (int i4 = 0; i4 < (NI4); ++i4) {                                      \
    float4 xv = (XPTR)[i4];                                                 \
    const float* __restrict__ Wra = (WA) + i4 * 256;                        \
    const float* __restrict__ Wrb = (WB) + i4 * 256;                        \
    _Pragma("unroll")                                                       \
    for (int s_ = 0; s_ < 4; ++s_) {                                        \
      float xs = (s_ == 0) ? xv.x : (s_ == 1) ? xv.y : (s_ == 2) ? xv.z : xv.w; \
      _Pragma("unroll")                                                     \
      for (int j_ = 0; j_ < 64; ++j_) {                                     \
        (HA)[j_] += xs * Wra[s_ * 64 + j_];                                 \
        (HB)[j_] += xs * Wrb[s_ * 64 + j_];                                 \
      }                                                                     \
    }                                                                       \
  }

// ---------------- Kernel T: triplet MLP + atomic segment-sum into angle_agg [E,64]
__global__ __launch_bounds__(64) void ktrip(
    const int* __restrict__ tkj, const int* __restrict__ tji,
    const float* __restrict__ erbf, const float* __restrict__ afeat,
    const float* __restrict__ W1, const float* __restrict__ b1,
    const float* __restrict__ W2, const float* __restrict__ b2,
    float* __restrict__ aagg)
{
  __shared__ float xp[64 * 64];
  const int lane = threadIdx.x;
  const int t = blockIdx.x * 64 + lane;
  const int kj = tkj[t];
  const int ji = tji[t];

  float hacc[64];
#pragma unroll
  for (int j = 0; j < 64; ++j) hacc[j] = b1[j];

  const float4* xk = (const float4*)(erbf + (size_t)kj * 64);
  MAC_CHUNK(16, hacc, xk, W1);
  const float4* xj = (const float4*)(erbf + (size_t)ji * 64);
  MAC_CHUNK(16, hacc, xj, W1 + 64 * 64);
  const float4* xa = (const float4*)(afeat + (size_t)t * 16);
  MAC_CHUNK(4, hacc, xa, W1 + 128 * 64);

  // stage silu(h) in rotate-swizzled own row (conflict-free)
#pragma unroll
  for (int j = 0; j < 64; ++j) xp[lane * 64 + ((j + lane) & 63)] = silu_f(hacc[j]);
  __syncthreads();

  float oacc[64];
#pragma unroll
  for (int j = 0; j < 64; ++j) oacc[j] = b2[j];
  for (int k = 0; k < 64; ++k) {
    float hk = xp[lane * 64 + ((k + lane) & 63)];
    const float* __restrict__ Wr = W2 + k * 64;
#pragma unroll
    for (int j = 0; j < 64; ++j) oacc[j] += hk * Wr[j];
  }
  __syncthreads();

  // transpose via LDS, then coalesced feature-parallel atomic scatter
#pragma unroll
  for (int j = 0; j < 64; ++j) xp[lane * 64 + ((j + lane) & 63)] = oacc[j];
  __syncthreads();
  for (int t2 = 0; t2 < 64; ++t2) {
    int e = __shfl(ji, t2);
    float val = xp[t2 * 64 + ((lane + t2) & 63)];
    atomicAdd(aagg + (size_t)e * 64 + lane, val);
  }
}

// ---------------- Kernel M: edge message MLP + atomic scatter into agg_s [N,64], agg_v [N,64,3]
__global__ __launch_bounds__(64) void kmsg(
    const int* __restrict__ eidx,
    const float* __restrict__ s, const float* __restrict__ erbf,
    const float* __restrict__ aagg, const float* __restrict__ edir,
    const float* __restrict__ W1, const float* __restrict__ b1,
    const float* __restrict__ W2, const float* __restrict__ b2,
    float* __restrict__ aggs, float* __restrict__ aggv)
{
  __shared__ float xp[64 * 64];
  const int lane = threadIdx.x;
  const int e = blockIdx.x * 64 + lane;
  const int src = eidx[e];
  const int dst = eidx[N_EDGES + e];

  float hacc[64];
#pragma unroll
  for (int j = 0; j < 64; ++j) hacc[j] = b1[j];

  const float4* x0 = (const float4*)(s + (size_t)src * 64);
  MAC_CHUNK(16, hacc, x0, W1);
  const float4* x1 = (const float4*)(s + (size_t)dst * 64);
  MAC_CHUNK(16, hacc, x1, W1 + 64 * 64);
  const float4* x2 = (const float4*)(erbf + (size_t)e * 64);
  MAC_CHUNK(16, hacc, x2, W1 + 128 * 64);
  const float4* x3 = (const float4*)(aagg + (size_t)e * 64);
  MAC_CHUNK(16, hacc, x3, W1 + 192 * 64);

#pragma unroll
  for (int j = 0; j < 64; ++j) xp[lane * 64 + ((j + lane) & 63)] = silu_f(hacc[j]);
  __syncthreads();

  float oa[64], ob[64];
#pragma unroll
  for (int j = 0; j < 64; ++j) { oa[j] = b2[j]; ob[j] = b2[64 + j]; }
  for (int k = 0; k < 64; ++k) {
    float hk = xp[lane * 64 + ((k + lane) & 63)];
    const float* __restrict__ Wr = W2 + k * 128;
#pragma unroll
    for (int j = 0; j < 64; ++j) { oa[j] += hk * Wr[j]; ob[j] += hk * Wr[64 + j]; }
  }
  __syncthreads();

  // scatter m_s -> agg_s[dst]
#pragma unroll
  for (int j = 0; j < 64; ++j) xp[lane * 64 + ((j + lane) & 63)] = oa[j];
  __syncthreads();
  for (int t2 = 0; t2 < 64; ++t2) {
    int d = __shfl(dst, t2);
    float val = xp[t2 * 64 + ((lane + t2) & 63)];
    atomicAdd(aggs + (size_t)d * 64 + lane, val);
  }
  __syncthreads();

  // scatter m_v = coeff * dir -> agg_v[dst]
  float dx = edir[(size_t)e * 3 + 0];
  float dy = edir[(size_t)e * 3 + 1];
  float dz = edir[(size_t)e * 3 + 2];
#pragma unroll
  for (int j = 0; j < 64; ++j) xp[lane * 64 + ((j + lane) & 63)] = ob[j];
  __syncthreads();
  for (int t2 = 0; t2 < 64; ++t2) {
    int d = __shfl(dst, t2);
    float fx = __shfl(dx, t2), fy = __shfl(dy, t2), fz = __shfl(dz, t2);
    float c = xp[t2 * 64 + ((lane + t2) & 63)];
    size_t base = (size_t)d * 192 + (size_t)lane * 3;
    atomicAdd(aggv + base + 0, c * fx);
    atomicAdd(aggv + base + 1, c * fy);
    atomicAdd(aggv + base + 2, c * fz);
  }
}

// ---------------- Kernel N: node update MLPs + LN + gated vector update
__global__ __launch_bounds__(64) void knode(
    const float* __restrict__ s, const float* __restrict__ v,
    const float* __restrict__ aggs, const float* __restrict__ aggv,
    const float* __restrict__ WU1, const float* __restrict__ bU1,
    const float* __restrict__ WU2, const float* __restrict__ bU2,
    const float* __restrict__ WG1, const float* __restrict__ bG1,
    const float* __restrict__ WG2, const float* __restrict__ bG2,
    const float* __restrict__ lng, const float* __restrict__ lnb,
    float* __restrict__ outs, float* __restrict__ outv)
{
  __shared__ float xp[64 * 64];
  const int lane = threadIdx.x;
  const int n = blockIdx.x * 64 + lane;
  const bool valid = (n < N_NODES);
  const int nc = valid ? n : 0;

  float hu[64], hg[64];
#pragma unroll
  for (int j = 0; j < 64; ++j) { hu[j] = bU1[j]; hg[j] = bG1[j]; }

  const float4* sr = (const float4*)(s + (size_t)nc * 64);
  MAC_CHUNK_DUAL(16, hu, hg, sr, WU1, WG1);
  const float4* ar = (const float4*)(aggs + (size_t)nc * 64);
  MAC_CHUNK_DUAL(16, hu, hg, ar, WU1 + 64 * 64, WG1 + 64 * 64);

  // v_norm chunk (rows 128..191), computed on the fly
  const float4* vr = (const float4*)(v + (size_t)nc * 192);
  for (int j4 = 0; j4 < 16; ++j4) {
    float4 a = vr[3 * j4], b = vr[3 * j4 + 1], c = vr[3 * j4 + 2];
    float4 xv;
    xv.x = sqrtf(a.x * a.x + a.y * a.y + a.z * a.z);
    xv.y = sqrtf(a.w * a.w + b.x * b.x + b.y * b.y);
    xv.z = sqrtf(b.z * b.z + b.w * b.w + c.x * c.x);
    xv.w = sqrtf(c.y * c.y + c.z * c.z + c.w * c.w);
    const float* __restrict__ Wra = WU1 + (128 + j4 * 4) * 64;
    const float* __restrict__ Wrb = WG1 + (128 + j4 * 4) * 64;
#pragma unroll
    for (int s_ = 0; s_ < 4; ++s_) {
      float xs = (s_ == 0) ? xv.x : (s_ == 1) ? xv.y : (s_ == 2) ? xv.z : xv.w;
#pragma unroll
      for (int j_ = 0; j_ < 64; ++j_) {
        hu[j_] += xs * Wra[s_ * 64 + j_];
        hg[j_] += xs * Wrb[s_ * 64 + j_];
      }
    }
  }

  // ---- u path
#pragma unroll
  for (int j = 0; j < 64; ++j) xp[lane * 64 + ((j + lane) & 63)] = silu_f(hu[j]);
  __syncthreads();
  float ou[64];
#pragma unroll
  for (int j = 0; j < 64; ++j) ou[j] = bU2[j];
  for (int k = 0; k < 64; ++k) {
    float hk = xp[lane * 64 + ((k + lane) & 63)];
    const float* __restrict__ Wr = WU2 + k * 64;
#pragma unroll
    for (int j = 0; j < 64; ++j) ou[j] += hk * Wr[j];
  }
  // s_new = s + ou; LayerNorm; silu; store
#pragma unroll
  for (int j4 = 0; j4 < 16; ++j4) {
    float4 sv = sr[j4];
    ou[4 * j4 + 0] += sv.x; ou[4 * j4 + 1] += sv.y;
    ou[4 * j4 + 2] += sv.z; ou[4 * j4 + 3] += sv.w;
  }
  float mu = 0.f;
#pragma unroll
  for (int j = 0; j < 64; ++j) mu += ou[j];
  mu *= (1.f / 64.f);
  float var = 0.f;
#pragma unroll
  for (int j = 0; j < 64; ++j) { float d = ou[j] - mu; var += d * d; }
  var *= (1.f / 64.f);
  float rstd = rsqrtf(var + 1e-5f);
  if (valid) {
    float4* os4 = (float4*)(outs + (size_t)n * 64);
#pragma unroll
    for (int j4 = 0; j4 < 16; ++j4) {
      float4 o;
      float y0 = (ou[4 * j4 + 0] - mu) * rstd * lng[4 * j4 + 0] + lnb[4 * j4 + 0];
      float y1 = (ou[4 * j4 + 1] - mu) * rstd * lng[4 * j4 + 1] + lnb[4 * j4 + 1];
      float y2 = (ou[4 * j4 + 2] - mu) * rstd * lng[4 * j4 + 2] + lnb[4 * j4 + 2];
      float y3 = (ou[4 * j4 + 3] - mu) * rstd * lng[4 * j4 + 3] + lnb[4 * j4 + 3];
      o.x = silu_f(y0); o.y = silu_f(y1); o.z = silu_f(y2); o.w = silu_f(y3);
      os4[j4] = o;
    }
  }

  // ---- g path
  __syncthreads();
#pragma unroll
  for (int j = 0; j < 64; ++j) xp[lane * 64 + ((j + lane) & 63)] = silu_f(hg[j]);
  __syncthreads();
  float og[64];
#pragma unroll
  for (int j = 0; j < 64; ++j) og[j] = bG2[j];
  for (int k = 0; k < 64; ++k) {
    float hk = xp[lane * 64 + ((k + lane) & 63)];
    const float* __restrict__ Wr = WG2 + k * 64;
#pragma unroll
    for (int j = 0; j < 64; ++j) og[j] += hk * Wr[j];
  }

  if (valid) {
    const float4* av = (const float4*)(aggv + (size_t)nc * 192);
    float4* ov = (float4*)(outv + (size_t)n * 192);
#pragma unroll
    for (int j4 = 0; j4 < 16; ++j4) {
      float4 a = vr[3 * j4], b = vr[3 * j4 + 1], c = vr[3 * j4 + 2];
      float4 A = av[3 * j4], B = av[3 * j4 + 1], C = av[3 * j4 + 2];
      float g0 = sigm_f(og[4 * j4 + 0]);
      float g1 = sigm_f(og[4 * j4 + 1]);
      float g2 = sigm_f(og[4 * j4 + 2]);
      float g3 = sigm_f(og[4 * j4 + 3]);
      float4 o0, o1, o2;
      o0.x = a.x + g0 * A.x; o0.y = a.y + g0 * A.y; o0.z = a.z + g0 * A.z; o0.w = a.w + g1 * A.w;
      o1.x = b.x + g1 * B.x; o1.y = b.y + g1 * B.y; o1.z = b.z + g2 * B.z; o1.w = b.w + g2 * B.w;
      o2.x = c.x + g2 * C.x; o2.y = c.y + g3 * C.y; o2.z = c.z + g3 * C.z; o2.w = c.w + g3 * C.w;
      ov[3 * j4] = o0; ov[3 * j4 + 1] = o1; ov[3 * j4 + 2] = o2;
    }
  }
}

extern "C" void kernel_launch(void* const* d_in, const int* in_sizes, int n_in,
                              void* d_out, int out_size, void* d_ws, size_t ws_size,
                              hipStream_t stream)
{
  const float* s     = (const float*)d_in[0];
  const float* v     = (const float*)d_in[1];
  const int*   eidx  = (const int*)d_in[2];
  const float* erbf  = (const float*)d_in[3];
  const float* edir  = (const float*)d_in[4];
  const int*   tkj   = (const int*)d_in[5];
  const int*   tji   = (const int*)d_in[6];
  const float* afeat = (const float*)d_in[7];
  const float* W_t1  = (const float*)d_in[8];
  const float* b_t1  = (const float*)d_in[9];
  const float* W_t2  = (const float*)d_in[10];
  const float* b_t2  = (const float*)d_in[11];
  const float* W_m1  = (const float*)d_in[12];
  const float* b_m1  = (const float*)d_in[13];
  const float* W_m2  = (const float*)d_in[14];
  const float* b_m2  = (const float*)d_in[15];
  const float* W_u1  = (const float*)d_in[16];
  const float* b_u1  = (const float*)d_in[17];
  const float* W_u2  = (const float*)d_in[18];
  const float* b_u2  = (const float*)d_in[19];
  const float* W_g1  = (const float*)d_in[20];
  const float* b_g1  = (const float*)d_in[21];
  const float* W_g2  = (const float*)d_in[22];
  const float* b_g2  = (const float*)d_in[23];
  const float* ln_g  = (const float*)d_in[24];
  const float* ln_b  = (const float*)d_in[25];

  float* aagg = (float*)d_ws;                          // [E,64]
  float* aggs = aagg + (size_t)N_EDGES * 64;           // [N,64]
  float* aggv = aggs + (size_t)N_NODES * 64;           // [N,64,3]
  size_t zbytes = ((size_t)N_EDGES * 64 + (size_t)N_NODES * 64 + (size_t)N_NODES * 192) * sizeof(float);
  hipMemsetAsync(d_ws, 0, zbytes, stream);

  ktrip<<<N_TRIP / 64, 64, 0, stream>>>(tkj, tji, erbf, afeat, W_t1, b_t1, W_t2, b_t2, aagg);
  kmsg<<<N_EDGES / 64, 64, 0, stream>>>(eidx, s, erbf, aagg, edir, W_m1, b_m1, W_m2, b_m2, aggs, aggv);

  float* out_s = (float*)d_out;
  float* out_v = out_s + (size_t)N_NODES * 64;
  knode<<<(N_NODES + 63) / 64, 64, 0, stream>>>(s, v, aggs, aggv, W_u1, b_u1, W_u2, b_u2,
                                                W_g1, b_g1, W_g2, b_g2, ln_g, ln_b, out_s, out_v);
}

// Round 2
// 2039.845 us; speedup vs baseline: 1.9148x; 1.9148x over previous
//
#include <hip/hip_runtime.h>
#include <cstdint>
#include <cstddef>

#define NN 50000
#define NE 800000
#define NT 800000

typedef unsigned short u16;
typedef unsigned int u32;

__device__ __forceinline__ float silu_f(float x) { return x / (1.f + __expf(-x)); }
__device__ __forceinline__ float sigm_f(float x) { return 1.f / (1.f + __expf(-x)); }
__device__ __forceinline__ u16 f2b(float x) {
  u32 u = __float_as_uint(x);
  u32 r = u + 0x7fffu + ((u >> 16) & 1u);
  return (u16)(r >> 16);
}
__device__ __forceinline__ float b2f(u16 h) { return __uint_as_float(((u32)h) << 16); }

// hacc[j] += x[i] * W[(base+i)*64 + j]; weights wave-uniform (scalar loads), x per-thread.
#define MAC_CHUNK(NI4, HACC, XPTR, WBASE)                                   \
  for (int i4 = 0; i4 < (NI4); ++i4) {                                      \
    float4 xv = (XPTR)[i4];                                                 \
    const float* __restrict__ Wr = (WBASE) + i4 * 256;                      \
    _Pragma("unroll")                                                       \
    for (int s_ = 0; s_ < 4; ++s_) {                                        \
      float xs = (s_ == 0) ? xv.x : (s_ == 1) ? xv.y : (s_ == 2) ? xv.z : xv.w; \
      _Pragma("unroll")                                                     \
      for (int j_ = 0; j_ < 64; ++j_) (HACC)[j_] += xs * Wr[s_ * 64 + j_];  \
    }                                                                       \
  }

#define MAC_CHUNK_DUAL(NI4, HA, HB, XPTR, WA, WB)                           \
  for (int i4 = 0; i4 < (NI4); ++i4) {                                      \
    float4 xv = (XPTR)[i4];                                                 \
    const float* __restrict__ Wra = (WA) + i4 * 256;                        \
    const float* __restrict__ Wrb = (WB) + i4 * 256;                        \
    _Pragma("unroll")                                                       \
    for (int s_ = 0; s_ < 4; ++s_) {                                        \
      float xs = (s_ == 0) ? xv.x : (s_ == 1) ? xv.y : (s_ == 2) ? xv.z : xv.w; \
      _Pragma("unroll")                                                     \
      for (int j_ = 0; j_ < 64; ++j_) {                                     \
        (HA)[j_] += xs * Wra[s_ * 64 + j_];                                 \
        (HB)[j_] += xs * Wrb[s_ * 64 + j_];                                 \
      }                                                                     \
    }                                                                       \
  }

// ---------------- CSR building: histogram, 2-level exclusive scan, id scatter
__global__ __launch_bounds__(256) void khist(const int* __restrict__ keys, int n,
                                             int* __restrict__ cnt) {
  int i = blockIdx.x * 256 + threadIdx.x;
  if (i < n) atomicAdd(&cnt[keys[i]], 1);
}

__global__ __launch_bounds__(256) void kscan1(const int* __restrict__ in, int n,
                                              int* __restrict__ out, int* __restrict__ bsum) {
  __shared__ int sh[256];
  int tid = threadIdx.x;
  size_t base = (size_t)blockIdx.x * 1024;
  int v[4];
  int acc = 0;
#pragma unroll
  for (int q = 0; q < 4; ++q) {
    size_t i = base + (size_t)tid * 4 + q;
    int x = (i < (size_t)n) ? in[i] : 0;
    v[q] = acc;
    acc += x;
  }
  sh[tid] = acc;
  __syncthreads();
  for (int off = 1; off < 256; off <<= 1) {
    int y = (tid >= off) ? sh[tid - off] : 0;
    __syncthreads();
    sh[tid] += y;
    __syncthreads();
  }
  int excl = (tid == 0) ? 0 : sh[tid - 1];
  if (tid == 255) bsum[blockIdx.x] = sh[255];
#pragma unroll
  for (int q = 0; q < 4; ++q) {
    size_t i = base + (size_t)tid * 4 + q;
    if (i < (size_t)n) out[i] = excl + v[q];
  }
}

__global__ __launch_bounds__(1024) void kscan2(int* __restrict__ bsum, int nb) {
  __shared__ int sh[1024];
  int tid = threadIdx.x;
  sh[tid] = (tid < nb) ? bsum[tid] : 0;
  __syncthreads();
  for (int off = 1; off < 1024; off <<= 1) {
    int y = (tid >= off) ? sh[tid - off] : 0;
    __syncthreads();
    sh[tid] += y;
    __syncthreads();
  }
  if (tid < nb) bsum[tid] = (tid == 0) ? 0 : sh[tid - 1];
}

__global__ __launch_bounds__(256) void kscan3(int* __restrict__ out, const int* __restrict__ bsum,
                                              int n, int total) {
  int i = blockIdx.x * 256 + threadIdx.x;
  if (i < n) out[i] += bsum[i >> 10];
  else if (i == n) out[n] = total;
}

__global__ __launch_bounds__(256) void kscatter(const int* __restrict__ keys,
                                                const int* __restrict__ off, int n,
                                                int* __restrict__ cnt, int* __restrict__ ids) {
  int i = blockIdx.x * 256 + threadIdx.x;
  if (i < n) {
    int k = keys[i];
    int slot = off[k] + (atomicSub(&cnt[k], 1) - 1);
    ids[slot] = i;
  }
}

// ---------------- Kernel T: triplet MLP -> tmsg[t][64] bf16 (natural order, no atomics)
__global__ __launch_bounds__(256) void ktrip(
    const int* __restrict__ tkj, const int* __restrict__ tji,
    const float* __restrict__ erbf, const float* __restrict__ afeat,
    const float* __restrict__ W1, const float* __restrict__ b1,
    const float* __restrict__ W2, const float* __restrict__ b2,
    u16* __restrict__ tmsg) {
  __shared__ u16 xp[256 * 64];  // 32KB: private 128B bf16 row per thread
  const int tid = threadIdx.x;
  const int t = blockIdx.x * 256 + tid;
  const int kj = tkj[t];
  const int ji = tji[t];

  float h[64];
#pragma unroll
  for (int j = 0; j < 64; ++j) h[j] = b1[j];

  const float4* xk = (const float4*)(erbf + (size_t)kj * 64);
  MAC_CHUNK(16, h, xk, W1);
  const float4* xj = (const float4*)(erbf + (size_t)ji * 64);
  MAC_CHUNK(16, h, xj, W1 + 64 * 64);
  const float4* xa = (const float4*)(afeat + (size_t)t * 16);
  MAC_CHUNK(4, h, xa, W1 + 128 * 64);

#pragma unroll
  for (int j = 0; j < 64; ++j) xp[tid * 64 + ((j + tid) & 63)] = f2b(silu_f(h[j]));

  float o[64];
#pragma unroll
  for (int j = 0; j < 64; ++j) o[j] = b2[j];
  for (int k = 0; k < 64; ++k) {
    float hk = b2f(xp[tid * 64 + ((k + tid) & 63)]);
    const float* __restrict__ Wr = W2 + k * 64;
#pragma unroll
    for (int j = 0; j < 64; ++j) o[j] += hk * Wr[j];
  }

  uint4* dst = (uint4*)(tmsg + (size_t)t * 64);
#pragma unroll
  for (int q = 0; q < 8; ++q) {
    uint4 p;
    p.x = (u32)f2b(o[q * 8 + 0]) | ((u32)f2b(o[q * 8 + 1]) << 16);
    p.y = (u32)f2b(o[q * 8 + 2]) | ((u32)f2b(o[q * 8 + 3]) << 16);
    p.z = (u32)f2b(o[q * 8 + 4]) | ((u32)f2b(o[q * 8 + 5]) << 16);
    p.w = (u32)f2b(o[q * 8 + 6]) | ((u32)f2b(o[q * 8 + 7]) << 16);
    dst[q] = p;
  }
}

// ---------------- Kernel M: edge MLP; aagg gathered inline from CSR; -> msg[e][128] bf16
__global__ __launch_bounds__(256) void kmsg(
    const int* __restrict__ eidx, const float* __restrict__ s,
    const float* __restrict__ erbf,
    const int* __restrict__ toff, const int* __restrict__ tids,
    const u16* __restrict__ tmsg,
    const float* __restrict__ W1, const float* __restrict__ b1,
    const float* __restrict__ W2, const float* __restrict__ b2,
    u16* __restrict__ msg) {
  __shared__ u16 xp[256 * 64];
  const int tid = threadIdx.x;
  const int e = blockIdx.x * 256 + tid;
  const int src = eidx[e];
  const int dst = eidx[NE + e];

  // aagg[e] = sum of this edge's triplet messages -> private LDS row (bf16)
  {
    float ag[64];
#pragma unroll
    for (int j = 0; j < 64; ++j) ag[j] = 0.f;
    const int r0 = toff[e], r1 = toff[e + 1];
    for (int r = r0; r < r1; ++r) {
      const uint4* row = (const uint4*)(tmsg + (size_t)tids[r] * 64);
#pragma unroll
      for (int q = 0; q < 8; ++q) {
        uint4 p = row[q];
        ag[q * 8 + 0] += b2f((u16)(p.x & 0xffff));
        ag[q * 8 + 1] += b2f((u16)(p.x >> 16));
        ag[q * 8 + 2] += b2f((u16)(p.y & 0xffff));
        ag[q * 8 + 3] += b2f((u16)(p.y >> 16));
        ag[q * 8 + 4] += b2f((u16)(p.z & 0xffff));
        ag[q * 8 + 5] += b2f((u16)(p.z >> 16));
        ag[q * 8 + 6] += b2f((u16)(p.w & 0xffff));
        ag[q * 8 + 7] += b2f((u16)(p.w >> 16));
      }
    }
#pragma unroll
    for (int j = 0; j < 64; ++j) xp[tid * 64 + ((j + tid) & 63)] = f2b(ag[j]);
  }

  float h[64];
#pragma unroll
  for (int j = 0; j < 64; ++j) h[j] = b1[j];

  // aagg chunk (W1 rows 192..255) via private-LDS broadcast-free reads
  for (int i = 0; i < 64; ++i) {
    float x = b2f(xp[tid * 64 + ((i + tid) & 63)]);
    const float* __restrict__ Wr = W1 + (192 + i) * 64;
#pragma unroll
    for (int j = 0; j < 64; ++j) h[j] += x * Wr[j];
  }
  const float4* x0 = (const float4*)(s + (size_t)src * 64);
  MAC_CHUNK(16, h, x0, W1);
  const float4* x1 = (const float4*)(s + (size_t)dst * 64);
  MAC_CHUNK(16, h, x1, W1 + 64 * 64);
  const float4* x2 = (const float4*)(erbf + (size_t)e * 64);
  MAC_CHUNK(16, h, x2, W1 + 128 * 64);

#pragma unroll
  for (int j = 0; j < 64; ++j) xp[tid * 64 + ((j + tid) & 63)] = f2b(silu_f(h[j]));

  uint4* out0 = (uint4*)(msg + (size_t)e * 128);
  {
    float oa[64];
#pragma unroll
    for (int j = 0; j < 64; ++j) oa[j] = b2[j];
    for (int k = 0; k < 64; ++k) {
      float hk = b2f(xp[tid * 64 + ((k + tid) & 63)]);
      const float* __restrict__ Wr = W2 + k * 128;
#pragma unroll
      for (int j = 0; j < 64; ++j) oa[j] += hk * Wr[j];
    }
#pragma unroll
    for (int q = 0; q < 8; ++q) {
      uint4 p;
      p.x = (u32)f2b(oa[q * 8 + 0]) | ((u32)f2b(oa[q * 8 + 1]) << 16);
      p.y = (u32)f2b(oa[q * 8 + 2]) | ((u32)f2b(oa[q * 8 + 3]) << 16);
      p.z = (u32)f2b(oa[q * 8 + 4]) | ((u32)f2b(oa[q * 8 + 5]) << 16);
      p.w = (u32)f2b(oa[q * 8 + 6]) | ((u32)f2b(oa[q * 8 + 7]) << 16);
      out0[q] = p;
    }
  }
  {
    float ob[64];
#pragma unroll
    for (int j = 0; j < 64; ++j) ob[j] = b2[64 + j];
    for (int k = 0; k < 64; ++k) {
      float hk = b2f(xp[tid * 64 + ((k + tid) & 63)]);
      const float* __restrict__ Wr = W2 + k * 128 + 64;
#pragma unroll
      for (int j = 0; j < 64; ++j) ob[j] += hk * Wr[j];
    }
#pragma unroll
    for (int q = 0; q < 8; ++q) {
      uint4 p;
      p.x = (u32)f2b(ob[q * 8 + 0]) | ((u32)f2b(ob[q * 8 + 1]) << 16);
      p.y = (u32)f2b(ob[q * 8 + 2]) | ((u32)f2b(ob[q * 8 + 3]) << 16);
      p.z = (u32)f2b(ob[q * 8 + 4]) | ((u32)f2b(ob[q * 8 + 5]) << 16);
      p.w = (u32)f2b(ob[q * 8 + 6]) | ((u32)f2b(ob[q * 8 + 7]) << 16);
      out0[8 + q] = p;
    }
  }
}

// ---------------- Kernel A: wave-per-node CSR gather -> aggs[N,64], aggv[N,64,3]
__global__ __launch_bounds__(256) void kagg(
    const int* __restrict__ noff, const int* __restrict__ eids,
    const u16* __restrict__ msg, const float* __restrict__ edir,
    float* __restrict__ aggs, float* __restrict__ aggv) {
  const int lane = threadIdx.x & 63;
  const int wv = threadIdx.x >> 6;
  const int n = blockIdx.x * 4 + wv;
  if (n >= NN) return;
  const int r0 = noff[n], r1 = noff[n + 1];
  float as = 0.f, a0 = 0.f, a1 = 0.f, a2 = 0.f;
  for (int r = r0; r < r1; ++r) {
    const int e = eids[r];
    const u16* row = msg + (size_t)e * 128;
    float ms = b2f(row[lane]);
    float mc = b2f(row[64 + lane]);
    float dx = edir[(size_t)e * 3 + 0];
    float dy = edir[(size_t)e * 3 + 1];
    float dz = edir[(size_t)e * 3 + 2];
    as += ms;
    a0 += mc * dx;
    a1 += mc * dy;
    a2 += mc * dz;
  }
  aggs[(size_t)n * 64 + lane] = as;
  float* av = aggv + (size_t)n * 192 + (size_t)lane * 3;
  av[0] = a0;
  av[1] = a1;
  av[2] = a2;
}

// ---------------- Kernel N: node update MLPs + LN + gated vector update (round-0, unchanged)
__global__ __launch_bounds__(64) void knode(
    const float* __restrict__ s, const float* __restrict__ v,
    const float* __restrict__ aggs, const float* __restrict__ aggv,
    const float* __restrict__ WU1, const float* __restrict__ bU1,
    const float* __restrict__ WU2, const float* __restrict__ bU2,
    const float* __restrict__ WG1, const float* __restrict__ bG1,
    const float* __restrict__ WG2, const float* __restrict__ bG2,
    const float* __restrict__ lng, const float* __restrict__ lnb,
    float* __restrict__ outs, float* __restrict__ outv) {
  __shared__ float xp[64 * 64];
  const int lane = threadIdx.x;
  const int n = blockIdx.x * 64 + lane;
  const bool valid = (n < NN);
  const int nc = valid ? n : 0;

  float hu[64], hg[64];
#pragma unroll
  for (int j = 0; j < 64; ++j) { hu[j] = bU1[j]; hg[j] = bG1[j]; }

  const float4* sr = (const float4*)(s + (size_t)nc * 64);
  MAC_CHUNK_DUAL(16, hu, hg, sr, WU1, WG1);
  const float4* ar = (const float4*)(aggs + (size_t)nc * 64);
  MAC_CHUNK_DUAL(16, hu, hg, ar, WU1 + 64 * 64, WG1 + 64 * 64);

  const float4* vr = (const float4*)(v + (size_t)nc * 192);
  for (int j4 = 0; j4 < 16; ++j4) {
    float4 a = vr[3 * j4], b = vr[3 * j4 + 1], c = vr[3 * j4 + 2];
    float4 xv;
    xv.x = sqrtf(a.x * a.x + a.y * a.y + a.z * a.z);
    xv.y = sqrtf(a.w * a.w + b.x * b.x + b.y * b.y);
    xv.z = sqrtf(b.z * b.z + b.w * b.w + c.x * c.x);
    xv.w = sqrtf(c.y * c.y + c.z * c.z + c.w * c.w);
    const float* __restrict__ Wra = WU1 + (128 + j4 * 4) * 64;
    const float* __restrict__ Wrb = WG1 + (128 + j4 * 4) * 64;
#pragma unroll
    for (int s_ = 0; s_ < 4; ++s_) {
      float xs = (s_ == 0) ? xv.x : (s_ == 1) ? xv.y : (s_ == 2) ? xv.z : xv.w;
#pragma unroll
      for (int j_ = 0; j_ < 64; ++j_) {
        hu[j_] += xs * Wra[s_ * 64 + j_];
        hg[j_] += xs * Wrb[s_ * 64 + j_];
      }
    }
  }

#pragma unroll
  for (int j = 0; j < 64; ++j) xp[lane * 64 + ((j + lane) & 63)] = silu_f(hu[j]);
  __syncthreads();
  float ou[64];
#pragma unroll
  for (int j = 0; j < 64; ++j) ou[j] = bU2[j];
  for (int k = 0; k < 64; ++k) {
    float hk = xp[lane * 64 + ((k + lane) & 63)];
    const float* __restrict__ Wr = WU2 + k * 64;
#pragma unroll
    for (int j = 0; j < 64; ++j) ou[j] += hk * Wr[j];
  }
#pragma unroll
  for (int j4 = 0; j4 < 16; ++j4) {
    float4 sv = sr[j4];
    ou[4 * j4 + 0] += sv.x; ou[4 * j4 + 1] += sv.y;
    ou[4 * j4 + 2] += sv.z; ou[4 * j4 + 3] += sv.w;
  }
  float mu = 0.f;
#pragma unroll
  for (int j = 0; j < 64; ++j) mu += ou[j];
  mu *= (1.f / 64.f);
  float var = 0.f;
#pragma unroll
  for (int j = 0; j < 64; ++j) { float d = ou[j] - mu; var += d * d; }
  var *= (1.f / 64.f);
  float rstd = rsqrtf(var + 1e-5f);
  if (valid) {
    float4* os4 = (float4*)(outs + (size_t)n * 64);
#pragma unroll
    for (int j4 = 0; j4 < 16; ++j4) {
      float4 o;
      float y0 = (ou[4 * j4 + 0] - mu) * rstd * lng[4 * j4 + 0] + lnb[4 * j4 + 0];
      float y1 = (ou[4 * j4 + 1] - mu) * rstd * lng[4 * j4 + 1] + lnb[4 * j4 + 1];
      float y2 = (ou[4 * j4 + 2] - mu) * rstd * lng[4 * j4 + 2] + lnb[4 * j4 + 2];
      float y3 = (ou[4 * j4 + 3] - mu) * rstd * lng[4 * j4 + 3] + lnb[4 * j4 + 3];
      o.x = silu_f(y0); o.y = silu_f(y1); o.z = silu_f(y2); o.w = silu_f(y3);
      os4[j4] = o;
    }
  }

  __syncthreads();
#pragma unroll
  for (int j = 0; j < 64; ++j) xp[lane * 64 + ((j + lane) & 63)] = silu_f(hg[j]);
  __syncthreads();
  float og[64];
#pragma unroll
  for (int j = 0; j < 64; ++j) og[j] = bG2[j];
  for (int k = 0; k < 64; ++k) {
    float hk = xp[lane * 64 + ((k + lane) & 63)];
    const float* __restrict__ Wr = WG2 + k * 64;
#pragma unroll
    for (int j = 0; j < 64; ++j) og[j] += hk * Wr[j];
  }

  if (valid) {
    const float4* av = (const float4*)(aggv + (size_t)nc * 192);
    float4* ov = (float4*)(outv + (size_t)n * 192);
#pragma unroll
    for (int j4 = 0; j4 < 16; ++j4) {
      float4 a = vr[3 * j4], b = vr[3 * j4 + 1], c = vr[3 * j4 + 2];
      float4 A = av[3 * j4], B = av[3 * j4 + 1], C = av[3 * j4 + 2];
      float g0 = sigm_f(og[4 * j4 + 0]);
      float g1 = sigm_f(og[4 * j4 + 1]);
      float g2 = sigm_f(og[4 * j4 + 2]);
      float g3 = sigm_f(og[4 * j4 + 3]);
      float4 o0, o1, o2;
      o0.x = a.x + g0 * A.x; o0.y = a.y + g0 * A.y; o0.z = a.z + g0 * A.z; o0.w = a.w + g1 * A.w;
      o1.x = b.x + g1 * B.x; o1.y = b.y + g1 * B.y; o1.z = b.z + g2 * B.z; o1.w = b.w + g2 * B.w;
      o2.x = c.x + g2 * C.x; o2.y = c.y + g3 * C.y; o2.z = c.z + g3 * C.z; o2.w = c.w + g3 * C.w;
      ov[3 * j4] = o0; ov[3 * j4 + 1] = o1; ov[3 * j4 + 2] = o2;
    }
  }
}

extern "C" void kernel_launch(void* const* d_in, const int* in_sizes, int n_in,
                              void* d_out, int out_size, void* d_ws, size_t ws_size,
                              hipStream_t stream) {
  const float* s     = (const float*)d_in[0];
  const float* v     = (const float*)d_in[1];
  const int*   eidx  = (const int*)d_in[2];
  const float* erbf  = (const float*)d_in[3];
  const float* edir  = (const float*)d_in[4];
  const int*   tkj   = (const int*)d_in[5];
  const int*   tji   = (const int*)d_in[6];
  const float* afeat = (const float*)d_in[7];
  const float* W_t1  = (const float*)d_in[8];
  const float* b_t1  = (const float*)d_in[9];
  const float* W_t2  = (const float*)d_in[10];
  const float* b_t2  = (const float*)d_in[11];
  const float* W_m1  = (const float*)d_in[12];
  const float* b_m1  = (const float*)d_in[13];
  const float* W_m2  = (const float*)d_in[14];
  const float* b_m2  = (const float*)d_in[15];
  const float* W_u1  = (const float*)d_in[16];
  const float* b_u1  = (const float*)d_in[17];
  const float* W_u2  = (const float*)d_in[18];
  const float* b_u2  = (const float*)d_in[19];
  const float* W_g1  = (const float*)d_in[20];
  const float* b_g1  = (const float*)d_in[21];
  const float* W_g2  = (const float*)d_in[22];
  const float* b_g2  = (const float*)d_in[23];
  const float* ln_g  = (const float*)d_in[24];
  const float* ln_b  = (const float*)d_in[25];

  char* w = (char*)d_ws;
  auto alloc = [&](size_t bytes) -> char* {
    char* p = w;
    w += (bytes + 255) & ~(size_t)255;
    return p;
  };
  int* toff = (int*)alloc((size_t)(NE + 1) * 4);
  int* noff = (int*)alloc((size_t)(NN + 1) * 4);
  int* tcnt = (int*)alloc((size_t)NE * 4);
  int* ncnt = (int*)alloc((size_t)NN * 4);
  int* tids = (int*)alloc((size_t)NT * 4);
  int* eids = (int*)alloc((size_t)NE * 4);
  int* bsum = (int*)alloc(1024 * 4);
  u16* msg  = (u16*)alloc((size_t)NE * 128 * 2);   // 204.8 MB
  u16* tmsg = (u16*)alloc((size_t)NT * 64 * 2);    // 102.4 MB
  // aggs/aggv alias tmsg's region (tmsg is dead after kmsg; 51.2 MB <= 102.4 MB)
  float* aggs = (float*)tmsg;
  float* aggv = aggs + (size_t)NN * 64;

  hipMemsetAsync(tcnt, 0, (size_t)NE * 4, stream);
  hipMemsetAsync(ncnt, 0, (size_t)NN * 4, stream);

  khist<<<(NT + 255) / 256, 256, 0, stream>>>(tji, NT, tcnt);
  khist<<<(NE + 255) / 256, 256, 0, stream>>>(eidx + NE, NE, ncnt);

  // toff = exclusive scan of tcnt (len NE), toff[NE] = NT
  kscan1<<<(NE + 1023) / 1024, 256, 0, stream>>>(tcnt, NE, toff, bsum);
  kscan2<<<1, 1024, 0, stream>>>(bsum, (NE + 1023) / 1024);
  kscan3<<<(NE + 1 + 255) / 256, 256, 0, stream>>>(toff, bsum, NE, NT);

  kscatter<<<(NT + 255) / 256, 256, 0, stream>>>(tji, toff, NT, tcnt, tids);

  // noff = exclusive scan of ncnt (len NN), noff[NN] = NE
  kscan1<<<(NN + 1023) / 1024, 256, 0, stream>>>(ncnt, NN, noff, bsum);
  kscan2<<<1, 1024, 0, stream>>>(bsum, (NN + 1023) / 1024);
  kscan3<<<(NN + 1 + 255) / 256, 256, 0, stream>>>(noff, bsum, NN, NE);

  kscatter<<<(NE + 255) / 256, 256, 0, stream>>>(eidx + NE, noff, NE, ncnt, eids);

  ktrip<<<NT / 256, 256, 0, stream>>>(tkj, tji, erbf, afeat, W_t1, b_t1, W_t2, b_t2, tmsg);
  kmsg<<<NE / 256, 256, 0, stream>>>(eidx, s, erbf, toff, tids, tmsg,
                                     W_m1, b_m1, W_m2, b_m2, msg);
  kagg<<<(NN + 3) / 4, 256, 0, stream>>>(noff, eids, msg, edir, aggs, aggv);

  float* out_s = (float*)d_out;
  float* out_v = out_s + (size_t)NN * 64;
  knode<<<(NN + 63) / 64, 64, 0, stream>>>(s, v, aggs, aggv, W_u1, b_u1, W_u2, b_u2,
                                           W_g1, b_g1, W_g2, b_g2, ln_g, ln_b, out_s, out_v);
}

// Round 4
// 1690.286 us; speedup vs baseline: 2.3108x; 1.2068x over previous
//
#include <hip/hip_runtime.h>
#include <cstdint>
#include <cstddef>

#define NN 50000
#define NE 800000
#define NT 800000

typedef unsigned short u16;
typedef unsigned int u32;
typedef __attribute__((ext_vector_type(8))) short short8;
typedef __attribute__((ext_vector_type(4))) float f32x4;

__device__ __forceinline__ float silu_f(float x) { return x / (1.f + __expf(-x)); }
__device__ __forceinline__ float sigm_f(float x) { return 1.f / (1.f + __expf(-x)); }
__device__ __forceinline__ u16 f2b(float x) {
  u32 u = __float_as_uint(x);
  u32 r = u + 0x7fffu + ((u >> 16) & 1u);
  return (u16)(r >> 16);
}
__device__ __forceinline__ float b2f(u16 h) { return __uint_as_float(((u32)h) << 16); }

// XOR-swizzled LDS elem offset for row-major [*][RW] u16 tiles (16B-chunk ^ (r&7)).
template <int RW>
__device__ __forceinline__ int lx(int r, int c) {
  return r * RW + ((((c >> 3) ^ (r & 7)) << 3) | (c & 7));
}

// hacc[j] += x[i] * W[(base+i)*64 + j]
#define MAC_CHUNK(NI4, HACC, XPTR, WBASE)                                   \
  for (int i4 = 0; i4 < (NI4); ++i4) {                                      \
    float4 xv = (XPTR)[i4];                                                 \
    const float* __restrict__ Wr = (WBASE) + i4 * 256;                      \
    _Pragma("unroll")                                                       \
    for (int s_ = 0; s_ < 4; ++s_) {                                        \
      float xs = (s_ == 0) ? xv.x : (s_ == 1) ? xv.y : (s_ == 2) ? xv.z : xv.w; \
      _Pragma("unroll")                                                     \
      for (int j_ = 0; j_ < 64; ++j_) (HACC)[j_] += xs * Wr[s_ * 64 + j_];  \
    }                                                                       \
  }

#define MAC_CHUNK_DUAL(NI4, HA, HB, XPTR, WA, WB)                           \
  for (int i4 = 0; i4 < (NI4); ++i4) {                                      \
    float4 xv = (XPTR)[i4];                                                 \
    const float* __restrict__ Wra = (WA) + i4 * 256;                        \
    const float* __restrict__ Wrb = (WB) + i4 * 256;                        \
    _Pragma("unroll")                                                       \
    for (int s_ = 0; s_ < 4; ++s_) {                                        \
      float xs = (s_ == 0) ? xv.x : (s_ == 1) ? xv.y : (s_ == 2) ? xv.z : xv.w; \
      _Pragma("unroll")                                                     \
      for (int j_ = 0; j_ < 64; ++j_) {                                     \
        (HA)[j_] += xs * Wra[s_ * 64 + j_];                                 \
        (HB)[j_] += xs * Wrb[s_ * 64 + j_];                                 \
      }                                                                     \
    }                                                                       \
  }

// ---------------- CSR building (verbatim round 2)
__global__ __launch_bounds__(256) void khist(const int* __restrict__ keys, int n,
                                             int* __restrict__ cnt) {
  int i = blockIdx.x * 256 + threadIdx.x;
  if (i < n) atomicAdd(&cnt[keys[i]], 1);
}

__global__ __launch_bounds__(256) void kscan1(const int* __restrict__ in, int n,
                                              int* __restrict__ out, int* __restrict__ bsum) {
  __shared__ int sh[256];
  int tid = threadIdx.x;
  size_t base = (size_t)blockIdx.x * 1024;
  int v[4];
  int acc = 0;
#pragma unroll
  for (int q = 0; q < 4; ++q) {
    size_t i = base + (size_t)tid * 4 + q;
    int x = (i < (size_t)n) ? in[i] : 0;
    v[q] = acc;
    acc += x;
  }
  sh[tid] = acc;
  __syncthreads();
  for (int off = 1; off < 256; off <<= 1) {
    int y = (tid >= off) ? sh[tid - off] : 0;
    __syncthreads();
    sh[tid] += y;
    __syncthreads();
  }
  int excl = (tid == 0) ? 0 : sh[tid - 1];
  if (tid == 255) bsum[blockIdx.x] = sh[255];
#pragma unroll
  for (int q = 0; q < 4; ++q) {
    size_t i = base + (size_t)tid * 4 + q;
    if (i < (size_t)n) out[i] = excl + v[q];
  }
}

__global__ __launch_bounds__(1024) void kscan2(int* __restrict__ bsum, int nb) {
  __shared__ int sh[1024];
  int tid = threadIdx.x;
  sh[tid] = (tid < nb) ? bsum[tid] : 0;
  __syncthreads();
  for (int off = 1; off < 1024; off <<= 1) {
    int y = (tid >= off) ? sh[tid - off] : 0;
    __syncthreads();
    sh[tid] += y;
    __syncthreads();
  }
  if (tid < nb) bsum[tid] = (tid == 0) ? 0 : sh[tid - 1];
}

__global__ __launch_bounds__(256) void kscan3(int* __restrict__ out, const int* __restrict__ bsum,
                                              int n, int total) {
  int i = blockIdx.x * 256 + threadIdx.x;
  if (i < n) out[i] += bsum[i >> 10];
  else if (i == n) out[n] = total;
}

__global__ __launch_bounds__(256) void kscatter(const int* __restrict__ keys,
                                                const int* __restrict__ off, int n,
                                                int* __restrict__ cnt, int* __restrict__ ids) {
  int i = blockIdx.x * 256 + threadIdx.x;
  if (i < n) {
    int k = keys[i];
    int slot = off[k] + (atomicSub(&cnt[k], 1) - 1);
    ids[slot] = i;
  }
}

// ---------------- Weight prep: f32 [K x N] -> bf16 B-fragment pack for 16x16x32 MFMA.
__global__ __launch_bounds__(256) void kprepw(const float* __restrict__ W, int K, int Kp, int N,
                                              u16* __restrict__ out) {
  int tid = blockIdx.x * 256 + threadIdx.x;
  int total = (Kp / 32) * (N / 16) * 64;
  if (tid >= total) return;
  int l = tid & 63;
  int f = tid >> 6;
  int nt = f % (N / 16);
  int kt = f / (N / 16);
  int k0 = kt * 32 + (l >> 4) * 8;
  int n = nt * 16 + (l & 15);
  u16 vals[8];
#pragma unroll
  for (int j = 0; j < 8; ++j) {
    int kk = k0 + j;
    vals[j] = (kk < K) ? f2b(W[(size_t)kk * N + n]) : (u16)0;
  }
  uint4* dst = (uint4*)(out + (size_t)f * 512 + l * 8);
  uint4 p;
  p.x = (u32)vals[0] | ((u32)vals[1] << 16);
  p.y = (u32)vals[2] | ((u32)vals[3] << 16);
  p.z = (u32)vals[4] | ((u32)vals[5] << 16);
  p.w = (u32)vals[6] | ((u32)vals[7] << 16);
  *dst = p;
}

// ---------------- Kernel T (MFMA, under test this round): triplet MLP -> tmsg[t][64] bf16
__global__ __launch_bounds__(256) void ktrip_mfma(
    const int* __restrict__ tkj, const int* __restrict__ tji,
    const float* __restrict__ erbf, const float* __restrict__ afeat,
    const u16* __restrict__ Wp1, const float* __restrict__ b1,
    const u16* __restrict__ Wp2, const float* __restrict__ b2,
    u16* __restrict__ tmsg) {
  __shared__ u16 Xs[64 * 192];
  __shared__ u16 Hs[64 * 64];
  const int tid = threadIdx.x;
  const int l = tid & 63;
  const int w = tid >> 6;
  const int t0 = blockIdx.x * 64;

  // stage gathered erbf rows (half-wave per row, coalesced 256B)
  {
    const int hw = tid >> 5, p = tid & 31;
    for (int it = 0; it < 16; ++it) {
      int task = it * 8 + hw;
      int sel = task >> 6, r = task & 63;
      int t = t0 + r;
      int idx = sel ? tji[t] : tkj[t];
      float2 v = *(const float2*)&erbf[(size_t)idx * 64 + p * 2];
      *(u32*)&Xs[lx<192>(r, sel * 64 + p * 2)] = (u32)f2b(v.x) | ((u32)f2b(v.y) << 16);
    }
    {
      int r = tid >> 2, c = (tid & 3) * 4;
      const float4 v = *(const float4*)&afeat[(size_t)(t0 + r) * 16 + c];
      u32* q = (u32*)&Xs[lx<192>(r, 128 + c)];
      q[0] = (u32)f2b(v.x) | ((u32)f2b(v.y) << 16);
      q[1] = (u32)f2b(v.z) | ((u32)f2b(v.w) << 16);
    }
    for (int i = 0; i < 2; ++i) {
      int idx = i * 256 + tid;
      int r = idx >> 3, c = 144 + (idx & 7) * 2;
      *(u32*)&Xs[lx<192>(r, c)] = 0;
    }
  }
  __syncthreads();

  // layer 1: [64 x 160] x [160 x 64]; wave w owns n-tile w
  f32x4 acc1[4];
  {
    float bias = b1[w * 16 + (l & 15)];
#pragma unroll
    for (int mt = 0; mt < 4; ++mt) acc1[mt] = (f32x4){bias, bias, bias, bias};
    for (int ks = 0; ks < 5; ++ks) {
      short8 bf = *(const short8*)(Wp1 + ((size_t)(ks * 4 + w) * 64 + l) * 8);
#pragma unroll
      for (int mt = 0; mt < 4; ++mt) {
        short8 af = *(const short8*)&Xs[lx<192>(mt * 16 + (l & 15), ks * 32 + ((l >> 4) << 3))];
        acc1[mt] = __builtin_amdgcn_mfma_f32_16x16x32_bf16(af, bf, acc1[mt], 0, 0, 0);
      }
    }
  }
#pragma unroll
  for (int mt = 0; mt < 4; ++mt)
#pragma unroll
    for (int q = 0; q < 4; ++q) {
      int r = mt * 16 + (l >> 4) * 4 + q;
      Hs[lx<64>(r, w * 16 + (l & 15))] = f2b(silu_f(acc1[mt][q]));
    }
  __syncthreads();

  // layer 2: [64 x 64] x [64 x 64]
  f32x4 acc2[4];
  {
    float bias = b2[w * 16 + (l & 15)];
#pragma unroll
    for (int mt = 0; mt < 4; ++mt) acc2[mt] = (f32x4){bias, bias, bias, bias};
    for (int ks = 0; ks < 2; ++ks) {
      short8 bf = *(const short8*)(Wp2 + ((size_t)(ks * 4 + w) * 64 + l) * 8);
#pragma unroll
      for (int mt = 0; mt < 4; ++mt) {
        short8 af = *(const short8*)&Hs[lx<64>(mt * 16 + (l & 15), ks * 32 + ((l >> 4) << 3))];
        acc2[mt] = __builtin_amdgcn_mfma_f32_16x16x32_bf16(af, bf, acc2[mt], 0, 0, 0);
      }
    }
  }
  __syncthreads();
#pragma unroll
  for (int mt = 0; mt < 4; ++mt)
#pragma unroll
    for (int q = 0; q < 4; ++q) {
      int r = mt * 16 + (l >> 4) * 4 + q;
      Xs[lx<64>(r, w * 16 + (l & 15))] = f2b(acc2[mt][q]);
    }
  __syncthreads();
  for (int i = 0; i < 2; ++i) {
    int idx = i * 256 + tid;
    int r = idx >> 3, c0 = (idx & 7) << 3;
    uint4 val = *(const uint4*)&Xs[lx<64>(r, c0)];
    *(uint4*)(tmsg + (size_t)(t0 + r) * 64 + c0) = val;
  }
}

// ---------------- Kernel M (VALU, verbatim round 2 — PASSING): edge MLP -> msg[e][128] bf16
__global__ __launch_bounds__(256) void kmsg(
    const int* __restrict__ eidx, const float* __restrict__ s,
    const float* __restrict__ erbf,
    const int* __restrict__ toff, const int* __restrict__ tids,
    const u16* __restrict__ tmsg,
    const float* __restrict__ W1, const float* __restrict__ b1,
    const float* __restrict__ W2, const float* __restrict__ b2,
    u16* __restrict__ msg) {
  __shared__ u16 xp[256 * 64];
  const int tid = threadIdx.x;
  const int e = blockIdx.x * 256 + tid;
  const int src = eidx[e];
  const int dst = eidx[NE + e];

  {
    float ag[64];
#pragma unroll
    for (int j = 0; j < 64; ++j) ag[j] = 0.f;
    const int r0 = toff[e], r1 = toff[e + 1];
    for (int r = r0; r < r1; ++r) {
      const uint4* row = (const uint4*)(tmsg + (size_t)tids[r] * 64);
#pragma unroll
      for (int q = 0; q < 8; ++q) {
        uint4 p = row[q];
        ag[q * 8 + 0] += b2f((u16)(p.x & 0xffff));
        ag[q * 8 + 1] += b2f((u16)(p.x >> 16));
        ag[q * 8 + 2] += b2f((u16)(p.y & 0xffff));
        ag[q * 8 + 3] += b2f((u16)(p.y >> 16));
        ag[q * 8 + 4] += b2f((u16)(p.z & 0xffff));
        ag[q * 8 + 5] += b2f((u16)(p.z >> 16));
        ag[q * 8 + 6] += b2f((u16)(p.w & 0xffff));
        ag[q * 8 + 7] += b2f((u16)(p.w >> 16));
      }
    }
#pragma unroll
    for (int j = 0; j < 64; ++j) xp[tid * 64 + ((j + tid) & 63)] = f2b(ag[j]);
  }

  float h[64];
#pragma unroll
  for (int j = 0; j < 64; ++j) h[j] = b1[j];

  for (int i = 0; i < 64; ++i) {
    float x = b2f(xp[tid * 64 + ((i + tid) & 63)]);
    const float* __restrict__ Wr = W1 + (192 + i) * 64;
#pragma unroll
    for (int j = 0; j < 64; ++j) h[j] += x * Wr[j];
  }
  const float4* x0 = (const float4*)(s + (size_t)src * 64);
  MAC_CHUNK(16, h, x0, W1);
  const float4* x1 = (const float4*)(s + (size_t)dst * 64);
  MAC_CHUNK(16, h, x1, W1 + 64 * 64);
  const float4* x2 = (const float4*)(erbf + (size_t)e * 64);
  MAC_CHUNK(16, h, x2, W1 + 128 * 64);

#pragma unroll
  for (int j = 0; j < 64; ++j) xp[tid * 64 + ((j + tid) & 63)] = f2b(silu_f(h[j]));

  uint4* out0 = (uint4*)(msg + (size_t)e * 128);
  {
    float oa[64];
#pragma unroll
    for (int j = 0; j < 64; ++j) oa[j] = b2[j];
    for (int k = 0; k < 64; ++k) {
      float hk = b2f(xp[tid * 64 + ((k + tid) & 63)]);
      const float* __restrict__ Wr = W2 + k * 128;
#pragma unroll
      for (int j = 0; j < 64; ++j) oa[j] += hk * Wr[j];
    }
#pragma unroll
    for (int q = 0; q < 8; ++q) {
      uint4 p;
      p.x = (u32)f2b(oa[q * 8 + 0]) | ((u32)f2b(oa[q * 8 + 1]) << 16);
      p.y = (u32)f2b(oa[q * 8 + 2]) | ((u32)f2b(oa[q * 8 + 3]) << 16);
      p.z = (u32)f2b(oa[q * 8 + 4]) | ((u32)f2b(oa[q * 8 + 5]) << 16);
      p.w = (u32)f2b(oa[q * 8 + 6]) | ((u32)f2b(oa[q * 8 + 7]) << 16);
      out0[q] = p;
    }
  }
  {
    float ob[64];
#pragma unroll
    for (int j = 0; j < 64; ++j) ob[j] = b2[64 + j];
    for (int k = 0; k < 64; ++k) {
      float hk = b2f(xp[tid * 64 + ((k + tid) & 63)]);
      const float* __restrict__ Wr = W2 + k * 128 + 64;
#pragma unroll
      for (int j = 0; j < 64; ++j) ob[j] += hk * Wr[j];
    }
#pragma unroll
    for (int q = 0; q < 8; ++q) {
      uint4 p;
      p.x = (u32)f2b(ob[q * 8 + 0]) | ((u32)f2b(ob[q * 8 + 1]) << 16);
      p.y = (u32)f2b(ob[q * 8 + 2]) | ((u32)f2b(ob[q * 8 + 3]) << 16);
      p.z = (u32)f2b(ob[q * 8 + 4]) | ((u32)f2b(ob[q * 8 + 5]) << 16);
      p.w = (u32)f2b(ob[q * 8 + 6]) | ((u32)f2b(ob[q * 8 + 7]) << 16);
      out0[8 + q] = p;
    }
  }
}

// ---------------- Kernel A (verbatim round 2)
__global__ __launch_bounds__(256) void kagg(
    const int* __restrict__ noff, const int* __restrict__ eids,
    const u16* __restrict__ msg, const float* __restrict__ edir,
    float* __restrict__ aggs, float* __restrict__ aggv) {
  const int lane = threadIdx.x & 63;
  const int wv = threadIdx.x >> 6;
  const int n = blockIdx.x * 4 + wv;
  if (n >= NN) return;
  const int r0 = noff[n], r1 = noff[n + 1];
  float as = 0.f, a0 = 0.f, a1 = 0.f, a2 = 0.f;
  for (int r = r0; r < r1; ++r) {
    const int e = eids[r];
    const u16* row = msg + (size_t)e * 128;
    float ms = b2f(row[lane]);
    float mc = b2f(row[64 + lane]);
    float dx = edir[(size_t)e * 3 + 0];
    float dy = edir[(size_t)e * 3 + 1];
    float dz = edir[(size_t)e * 3 + 2];
    as += ms;
    a0 += mc * dx;
    a1 += mc * dy;
    a2 += mc * dz;
  }
  aggs[(size_t)n * 64 + lane] = as;
  float* av = aggv + (size_t)n * 192 + (size_t)lane * 3;
  av[0] = a0;
  av[1] = a1;
  av[2] = a2;
}

// ---------------- Kernel N (verbatim round 2)
__global__ __launch_bounds__(64) void knode(
    const float* __restrict__ s, const float* __restrict__ v,
    const float* __restrict__ aggs, const float* __restrict__ aggv,
    const float* __restrict__ WU1, const float* __restrict__ bU1,
    const float* __restrict__ WU2, const float* __restrict__ bU2,
    const float* __restrict__ WG1, const float* __restrict__ bG1,
    const float* __restrict__ WG2, const float* __restrict__ bG2,
    const float* __restrict__ lng, const float* __restrict__ lnb,
    float* __restrict__ outs, float* __restrict__ outv) {
  __shared__ float xp[64 * 64];
  const int lane = threadIdx.x;
  const int n = blockIdx.x * 64 + lane;
  const bool valid = (n < NN);
  const int nc = valid ? n : 0;

  float hu[64], hg[64];
#pragma unroll
  for (int j = 0; j < 64; ++j) { hu[j] = bU1[j]; hg[j] = bG1[j]; }

  const float4* sr = (const float4*)(s + (size_t)nc * 64);
  MAC_CHUNK_DUAL(16, hu, hg, sr, WU1, WG1);
  const float4* ar = (const float4*)(aggs + (size_t)nc * 64);
  MAC_CHUNK_DUAL(16, hu, hg, ar, WU1 + 64 * 64, WG1 + 64 * 64);

  const float4* vr = (const float4*)(v + (size_t)nc * 192);
  for (int j4 = 0; j4 < 16; ++j4) {
    float4 a = vr[3 * j4], b = vr[3 * j4 + 1], c = vr[3 * j4 + 2];
    float4 xv;
    xv.x = sqrtf(a.x * a.x + a.y * a.y + a.z * a.z);
    xv.y = sqrtf(a.w * a.w + b.x * b.x + b.y * b.y);
    xv.z = sqrtf(b.z * b.z + b.w * b.w + c.x * c.x);
    xv.w = sqrtf(c.y * c.y + c.z * c.z + c.w * c.w);
    const float* __restrict__ Wra = WU1 + (128 + j4 * 4) * 64;
    const float* __restrict__ Wrb = WG1 + (128 + j4 * 4) * 64;
#pragma unroll
    for (int s_ = 0; s_ < 4; ++s_) {
      float xs = (s_ == 0) ? xv.x : (s_ == 1) ? xv.y : (s_ == 2) ? xv.z : xv.w;
#pragma unroll
      for (int j_ = 0; j_ < 64; ++j_) {
        hu[j_] += xs * Wra[s_ * 64 + j_];
        hg[j_] += xs * Wrb[s_ * 64 + j_];
      }
    }
  }

#pragma unroll
  for (int j = 0; j < 64; ++j) xp[lane * 64 + ((j + lane) & 63)] = silu_f(hu[j]);
  __syncthreads();
  float ou[64];
#pragma unroll
  for (int j = 0; j < 64; ++j) ou[j] = bU2[j];
  for (int k = 0; k < 64; ++k) {
    float hk = xp[lane * 64 + ((k + lane) & 63)];
    const float* __restrict__ Wr = WU2 + k * 64;
#pragma unroll
    for (int j = 0; j < 64; ++j) ou[j] += hk * Wr[j];
  }
#pragma unroll
  for (int j4 = 0; j4 < 16; ++j4) {
    float4 sv = sr[j4];
    ou[4 * j4 + 0] += sv.x; ou[4 * j4 + 1] += sv.y;
    ou[4 * j4 + 2] += sv.z; ou[4 * j4 + 3] += sv.w;
  }
  float mu = 0.f;
#pragma unroll
  for (int j = 0; j < 64; ++j) mu += ou[j];
  mu *= (1.f / 64.f);
  float var = 0.f;
#pragma unroll
  for (int j = 0; j < 64; ++j) { float d = ou[j] - mu; var += d * d; }
  var *= (1.f / 64.f);
  float rstd = rsqrtf(var + 1e-5f);
  if (valid) {
    float4* os4 = (float4*)(outs + (size_t)n * 64);
#pragma unroll
    for (int j4 = 0; j4 < 16; ++j4) {
      float4 o;
      float y0 = (ou[4 * j4 + 0] - mu) * rstd * lng[4 * j4 + 0] + lnb[4 * j4 + 0];
      float y1 = (ou[4 * j4 + 1] - mu) * rstd * lng[4 * j4 + 1] + lnb[4 * j4 + 1];
      float y2 = (ou[4 * j4 + 2] - mu) * rstd * lng[4 * j4 + 2] + lnb[4 * j4 + 2];
      float y3 = (ou[4 * j4 + 3] - mu) * rstd * lng[4 * j4 + 3] + lnb[4 * j4 + 3];
      o.x = silu_f(y0); o.y = silu_f(y1); o.z = silu_f(y2); o.w = silu_f(y3);
      os4[j4] = o;
    }
  }

  __syncthreads();
#pragma unroll
  for (int j = 0; j < 64; ++j) xp[lane * 64 + ((j + lane) & 63)] = silu_f(hg[j]);
  __syncthreads();
  float og[64];
#pragma unroll
  for (int j = 0; j < 64; ++j) og[j] = bG2[j];
  for (int k = 0; k < 64; ++k) {
    float hk = xp[lane * 64 + ((k + lane) & 63)];
    const float* __restrict__ Wr = WG2 + k * 64;
#pragma unroll
    for (int j = 0; j < 64; ++j) og[j] += hk * Wr[j];
  }

  if (valid) {
    const float4* av = (const float4*)(aggv + (size_t)nc * 192);
    float4* ov = (float4*)(outv + (size_t)n * 192);
#pragma unroll
    for (int j4 = 0; j4 < 16; ++j4) {
      float4 a = vr[3 * j4], b = vr[3 * j4 + 1], c = vr[3 * j4 + 2];
      float4 A = av[3 * j4], B = av[3 * j4 + 1], C = av[3 * j4 + 2];
      float g0 = sigm_f(og[4 * j4 + 0]);
      float g1 = sigm_f(og[4 * j4 + 1]);
      float g2 = sigm_f(og[4 * j4 + 2]);
      float g3 = sigm_f(og[4 * j4 + 3]);
      float4 o0, o1, o2;
      o0.x = a.x + g0 * A.x; o0.y = a.y + g0 * A.y; o0.z = a.z + g0 * A.z; o0.w = a.w + g1 * A.w;
      o1.x = b.x + g1 * B.x; o1.y = b.y + g1 * B.y; o1.z = b.z + g2 * B.z; o1.w = b.w + g2 * B.w;
      o2.x = c.x + g2 * C.x; o2.y = c.y + g3 * C.y; o2.z = c.z + g3 * C.z; o2.w = c.w + g3 * C.w;
      ov[3 * j4] = o0; ov[3 * j4 + 1] = o1; ov[3 * j4 + 2] = o2;
    }
  }
}

extern "C" void kernel_launch(void* const* d_in, const int* in_sizes, int n_in,
                              void* d_out, int out_size, void* d_ws, size_t ws_size,
                              hipStream_t stream) {
  const float* s     = (const float*)d_in[0];
  const float* v     = (const float*)d_in[1];
  const int*   eidx  = (const int*)d_in[2];
  const float* erbf  = (const float*)d_in[3];
  const float* edir  = (const float*)d_in[4];
  const int*   tkj   = (const int*)d_in[5];
  const int*   tji   = (const int*)d_in[6];
  const float* afeat = (const float*)d_in[7];
  const float* W_t1  = (const float*)d_in[8];
  const float* b_t1  = (const float*)d_in[9];
  const float* W_t2  = (const float*)d_in[10];
  const float* b_t2  = (const float*)d_in[11];
  const float* W_m1  = (const float*)d_in[12];
  const float* b_m1  = (const float*)d_in[13];
  const float* W_m2  = (const float*)d_in[14];
  const float* b_m2  = (const float*)d_in[15];
  const float* W_u1  = (const float*)d_in[16];
  const float* b_u1  = (const float*)d_in[17];
  const float* W_u2  = (const float*)d_in[18];
  const float* b_u2  = (const float*)d_in[19];
  const float* W_g1  = (const float*)d_in[20];
  const float* b_g1  = (const float*)d_in[21];
  const float* W_g2  = (const float*)d_in[22];
  const float* b_g2  = (const float*)d_in[23];
  const float* ln_g  = (const float*)d_in[24];
  const float* ln_b  = (const float*)d_in[25];

  char* w = (char*)d_ws;
  auto alloc = [&](size_t bytes) -> char* {
    char* p = w;
    w += (bytes + 255) & ~(size_t)255;
    return p;
  };
  int* toff = (int*)alloc((size_t)(NE + 1) * 4);
  int* noff = (int*)alloc((size_t)(NN + 1) * 4);
  int* tcnt = (int*)alloc((size_t)NE * 4);
  int* ncnt = (int*)alloc((size_t)NN * 4);
  int* tids = (int*)alloc((size_t)NT * 4);
  int* eids = (int*)alloc((size_t)NE * 4);
  int* bsum = (int*)alloc(1024 * 4);
  u16* msg  = (u16*)alloc((size_t)NE * 128 * 2);   // 204.8 MB
  u16* tmsg = (u16*)alloc((size_t)NT * 64 * 2);    // 102.4 MB
  u16* Wp_t1 = (u16*)alloc((size_t)5 * 4 * 512 * 2);   // Kp=160 pack
  u16* Wp_t2 = (u16*)alloc((size_t)2 * 4 * 512 * 2);
  float* aggs = (float*)tmsg;  // alias: tmsg dead after kmsg
  float* aggv = aggs + (size_t)NN * 64;

  hipMemsetAsync(tcnt, 0, (size_t)NE * 4, stream);
  hipMemsetAsync(ncnt, 0, (size_t)NN * 4, stream);

  khist<<<(NT + 255) / 256, 256, 0, stream>>>(tji, NT, tcnt);
  khist<<<(NE + 255) / 256, 256, 0, stream>>>(eidx + NE, NE, ncnt);

  kscan1<<<(NE + 1023) / 1024, 256, 0, stream>>>(tcnt, NE, toff, bsum);
  kscan2<<<1, 1024, 0, stream>>>(bsum, (NE + 1023) / 1024);
  kscan3<<<(NE + 1 + 255) / 256, 256, 0, stream>>>(toff, bsum, NE, NT);
  kscatter<<<(NT + 255) / 256, 256, 0, stream>>>(tji, toff, NT, tcnt, tids);

  kscan1<<<(NN + 1023) / 1024, 256, 0, stream>>>(ncnt, NN, noff, bsum);
  kscan2<<<1, 1024, 0, stream>>>(bsum, (NN + 1023) / 1024);
  kscan3<<<(NN + 1 + 255) / 256, 256, 0, stream>>>(noff, bsum, NN, NE);
  kscatter<<<(NE + 255) / 256, 256, 0, stream>>>(eidx + NE, noff, NE, ncnt, eids);

  kprepw<<<5, 256, 0, stream>>>(W_t1, 144, 160, 64, Wp_t1);
  kprepw<<<2, 256, 0, stream>>>(W_t2, 64, 64, 64, Wp_t2);

  ktrip_mfma<<<NT / 64, 256, 0, stream>>>(tkj, tji, erbf, afeat, Wp_t1, b_t1, Wp_t2, b_t2, tmsg);
  kmsg<<<NE / 256, 256, 0, stream>>>(eidx, s, erbf, toff, tids, tmsg,
                                     W_m1, b_m1, W_m2, b_m2, msg);
  kagg<<<(NN + 3) / 4, 256, 0, stream>>>(noff, eids, msg, edir, aggs, aggv);

  float* out_s = (float*)d_out;
  float* out_v = out_s + (size_t)NN * 64;
  knode<<<(NN + 63) / 64, 64, 0, stream>>>(s, v, aggs, aggv, W_u1, b_u1, W_u2, b_u2,
                                           W_g1, b_g1, W_g2, b_g2, ln_g, ln_b, out_s, out_v);
}

// Round 5
// 1235.563 us; speedup vs baseline: 3.1612x; 1.3680x over previous
//
#include <hip/hip_runtime.h>
#include <cstdint>
#include <cstddef>

#define NN 50000
#define NE 800000
#define NT 800000

typedef unsigned short u16;
typedef unsigned int u32;
typedef __attribute__((ext_vector_type(8))) short short8;
typedef __attribute__((ext_vector_type(4))) float f32x4;

__device__ __forceinline__ float silu_f(float x) { return x / (1.f + __expf(-x)); }
__device__ __forceinline__ float sigm_f(float x) { return 1.f / (1.f + __expf(-x)); }
__device__ __forceinline__ u16 f2b(float x) {
  u32 u = __float_as_uint(x);
  u32 r = u + 0x7fffu + ((u >> 16) & 1u);
  return (u16)(r >> 16);
}
__device__ __forceinline__ float b2f(u16 h) { return __uint_as_float(((u32)h) << 16); }

// XOR-swizzled LDS elem offset for row-major [*][RW] u16 tiles (16B-chunk ^ (r&7)).
template <int RW>
__device__ __forceinline__ int lx(int r, int c) {
  return r * RW + ((((c >> 3) ^ (r & 7)) << 3) | (c & 7));
}

#define MAC_CHUNK_DUAL(NI4, HA, HB, XPTR, WA, WB)                           \
  for (int i4 = 0; i4 < (NI4); ++i4) {                                      \
    float4 xv = (XPTR)[i4];                                                 \
    const float* __restrict__ Wra = (WA) + i4 * 256;                        \
    const float* __restrict__ Wrb = (WB) + i4 * 256;                        \
    _Pragma("unroll")                                                       \
    for (int s_ = 0; s_ < 4; ++s_) {                                        \
      float xs = (s_ == 0) ? xv.x : (s_ == 1) ? xv.y : (s_ == 2) ? xv.z : xv.w; \
      _Pragma("unroll")                                                     \
      for (int j_ = 0; j_ < 64; ++j_) {                                     \
        (HA)[j_] += xs * Wra[s_ * 64 + j_];                                 \
        (HB)[j_] += xs * Wrb[s_ * 64 + j_];                                 \
      }                                                                     \
    }                                                                       \
  }

// ---------------- CSR building (verbatim, proven)
__global__ __launch_bounds__(256) void khist(const int* __restrict__ keys, int n,
                                             int* __restrict__ cnt) {
  int i = blockIdx.x * 256 + threadIdx.x;
  if (i < n) atomicAdd(&cnt[keys[i]], 1);
}

__global__ __launch_bounds__(256) void kscan1(const int* __restrict__ in, int n,
                                              int* __restrict__ out, int* __restrict__ bsum) {
  __shared__ int sh[256];
  int tid = threadIdx.x;
  size_t base = (size_t)blockIdx.x * 1024;
  int v[4];
  int acc = 0;
#pragma unroll
  for (int q = 0; q < 4; ++q) {
    size_t i = base + (size_t)tid * 4 + q;
    int x = (i < (size_t)n) ? in[i] : 0;
    v[q] = acc;
    acc += x;
  }
  sh[tid] = acc;
  __syncthreads();
  for (int off = 1; off < 256; off <<= 1) {
    int y = (tid >= off) ? sh[tid - off] : 0;
    __syncthreads();
    sh[tid] += y;
    __syncthreads();
  }
  int excl = (tid == 0) ? 0 : sh[tid - 1];
  if (tid == 255) bsum[blockIdx.x] = sh[255];
#pragma unroll
  for (int q = 0; q < 4; ++q) {
    size_t i = base + (size_t)tid * 4 + q;
    if (i < (size_t)n) out[i] = excl + v[q];
  }
}

__global__ __launch_bounds__(1024) void kscan2(int* __restrict__ bsum, int nb) {
  __shared__ int sh[1024];
  int tid = threadIdx.x;
  sh[tid] = (tid < nb) ? bsum[tid] : 0;
  __syncthreads();
  for (int off = 1; off < 1024; off <<= 1) {
    int y = (tid >= off) ? sh[tid - off] : 0;
    __syncthreads();
    sh[tid] += y;
    __syncthreads();
  }
  if (tid < nb) bsum[tid] = (tid == 0) ? 0 : sh[tid - 1];
}

__global__ __launch_bounds__(256) void kscan3(int* __restrict__ out, const int* __restrict__ bsum,
                                              int n, int total) {
  int i = blockIdx.x * 256 + threadIdx.x;
  if (i < n) out[i] += bsum[i >> 10];
  else if (i == n) out[n] = total;
}

__global__ __launch_bounds__(256) void kscatter(const int* __restrict__ keys,
                                                const int* __restrict__ off, int n,
                                                int* __restrict__ cnt, int* __restrict__ ids) {
  int i = blockIdx.x * 256 + threadIdx.x;
  if (i < n) {
    int k = keys[i];
    int slot = off[k] + (atomicSub(&cnt[k], 1) - 1);
    ids[slot] = i;
  }
}

// ---------------- Weight prep: f32 [K x N] -> bf16 B-fragment pack for 16x16x32 MFMA (proven)
__global__ __launch_bounds__(256) void kprepw(const float* __restrict__ W, int K, int Kp, int N,
                                              u16* __restrict__ out) {
  int tid = blockIdx.x * 256 + threadIdx.x;
  int total = (Kp / 32) * (N / 16) * 64;
  if (tid >= total) return;
  int l = tid & 63;
  int f = tid >> 6;
  int nt = f % (N / 16);
  int kt = f / (N / 16);
  int k0 = kt * 32 + (l >> 4) * 8;
  int n = nt * 16 + (l & 15);
  u16 vals[8];
#pragma unroll
  for (int j = 0; j < 8; ++j) {
    int kk = k0 + j;
    vals[j] = (kk < K) ? f2b(W[(size_t)kk * N + n]) : (u16)0;
  }
  uint4* dst = (uint4*)(out + (size_t)f * 512 + l * 8);
  uint4 p;
  p.x = (u32)vals[0] | ((u32)vals[1] << 16);
  p.y = (u32)vals[2] | ((u32)vals[3] << 16);
  p.z = (u32)vals[4] | ((u32)vals[5] << 16);
  p.w = (u32)vals[6] | ((u32)vals[7] << 16);
  *dst = p;
}

// ---------------- Kernel T (MFMA, validated round 4): triplet MLP -> tmsg[t][64] bf16
__global__ __launch_bounds__(256) void ktrip_mfma(
    const int* __restrict__ tkj, const int* __restrict__ tji,
    const float* __restrict__ erbf, const float* __restrict__ afeat,
    const u16* __restrict__ Wp1, const float* __restrict__ b1,
    const u16* __restrict__ Wp2, const float* __restrict__ b2,
    u16* __restrict__ tmsg) {
  __shared__ u16 Xs[64 * 192];
  __shared__ u16 Hs[64 * 64];
  const int tid = threadIdx.x;
  const int l = tid & 63;
  const int w = tid >> 6;
  const int t0 = blockIdx.x * 64;

  {
    const int hw = tid >> 5, p = tid & 31;
    for (int it = 0; it < 16; ++it) {
      int task = it * 8 + hw;
      int sel = task >> 6, r = task & 63;
      int t = t0 + r;
      int idx = sel ? tji[t] : tkj[t];
      float2 v = *(const float2*)&erbf[(size_t)idx * 64 + p * 2];
      *(u32*)&Xs[lx<192>(r, sel * 64 + p * 2)] = (u32)f2b(v.x) | ((u32)f2b(v.y) << 16);
    }
    {
      int r = tid >> 2, c = (tid & 3) * 4;
      const float4 v = *(const float4*)&afeat[(size_t)(t0 + r) * 16 + c];
      u32* q = (u32*)&Xs[lx<192>(r, 128 + c)];
      q[0] = (u32)f2b(v.x) | ((u32)f2b(v.y) << 16);
      q[1] = (u32)f2b(v.z) | ((u32)f2b(v.w) << 16);
    }
    for (int i = 0; i < 2; ++i) {
      int idx = i * 256 + tid;
      int r = idx >> 3, c = 144 + (idx & 7) * 2;
      *(u32*)&Xs[lx<192>(r, c)] = 0;
    }
  }
  __syncthreads();

  f32x4 acc1[4];
  {
    float bias = b1[w * 16 + (l & 15)];
#pragma unroll
    for (int mt = 0; mt < 4; ++mt) acc1[mt] = (f32x4){bias, bias, bias, bias};
    for (int ks = 0; ks < 5; ++ks) {
      short8 bf = *(const short8*)(Wp1 + ((size_t)(ks * 4 + w) * 64 + l) * 8);
#pragma unroll
      for (int mt = 0; mt < 4; ++mt) {
        short8 af = *(const short8*)&Xs[lx<192>(mt * 16 + (l & 15), ks * 32 + ((l >> 4) << 3))];
        acc1[mt] = __builtin_amdgcn_mfma_f32_16x16x32_bf16(af, bf, acc1[mt], 0, 0, 0);
      }
    }
  }
#pragma unroll
  for (int mt = 0; mt < 4; ++mt)
#pragma unroll
    for (int q = 0; q < 4; ++q) {
      int r = mt * 16 + (l >> 4) * 4 + q;
      Hs[lx<64>(r, w * 16 + (l & 15))] = f2b(silu_f(acc1[mt][q]));
    }
  __syncthreads();

  f32x4 acc2[4];
  {
    float bias = b2[w * 16 + (l & 15)];
#pragma unroll
    for (int mt = 0; mt < 4; ++mt) acc2[mt] = (f32x4){bias, bias, bias, bias};
    for (int ks = 0; ks < 2; ++ks) {
      short8 bf = *(const short8*)(Wp2 + ((size_t)(ks * 4 + w) * 64 + l) * 8);
#pragma unroll
      for (int mt = 0; mt < 4; ++mt) {
        short8 af = *(const short8*)&Hs[lx<64>(mt * 16 + (l & 15), ks * 32 + ((l >> 4) << 3))];
        acc2[mt] = __builtin_amdgcn_mfma_f32_16x16x32_bf16(af, bf, acc2[mt], 0, 0, 0);
      }
    }
  }
  __syncthreads();
#pragma unroll
  for (int mt = 0; mt < 4; ++mt)
#pragma unroll
    for (int q = 0; q < 4; ++q) {
      int r = mt * 16 + (l >> 4) * 4 + q;
      Xs[lx<64>(r, w * 16 + (l & 15))] = f2b(acc2[mt][q]);
    }
  __syncthreads();
  for (int i = 0; i < 2; ++i) {
    int idx = i * 256 + tid;
    int r = idx >> 3, c0 = (idx & 7) << 3;
    uint4 val = *(const uint4*)&Xs[lx<64>(r, c0)];
    *(uint4*)(tmsg + (size_t)(t0 + r) * 64 + c0) = val;
  }
}

// ---------------- Kernel M (MFMA, out-copy FIXED: 1024 chunks not 2048)
// Block: 64 edges, 256 threads. X [64][256] = s[src] | s[dst] | erbf[e] | aagg[e]
__global__ __launch_bounds__(256) void kmsg_mfma(
    const int* __restrict__ eidx, const float* __restrict__ s,
    const float* __restrict__ erbf,
    const int* __restrict__ toff, const int* __restrict__ tids,
    const u16* __restrict__ tmsg,
    const u16* __restrict__ Wp1, const float* __restrict__ b1,
    const u16* __restrict__ Wp2, const float* __restrict__ b2,
    u16* __restrict__ msg) {
  __shared__ u16 Xs[64 * 256];  // 32KB (reused as out-stage [64][128])
  __shared__ u16 Hs[64 * 64];   // 8KB
  const int tid = threadIdx.x;
  const int l = tid & 63;
  const int w = tid >> 6;
  const int e0 = blockIdx.x * 64;

  // stage erbf cols 128..191 (contiguous stream): 1024 float4
  for (int i = 0; i < 4; ++i) {
    int idx = i * 256 + tid;
    int r = idx >> 4, c = (idx & 15) * 4;
    const float4 v = *(const float4*)&erbf[(size_t)(e0 + r) * 64 + c];
    u32* q = (u32*)&Xs[lx<256>(r, 128 + c)];
    q[0] = (u32)f2b(v.x) | ((u32)f2b(v.y) << 16);
    q[1] = (u32)f2b(v.z) | ((u32)f2b(v.w) << 16);
  }
  // stage s[src], s[dst] (gather, half-wave per row) + aagg CSR sum (cols 192..255)
  {
    const int hw = tid >> 5, p = tid & 31;
    for (int it = 0; it < 24; ++it) {
      int task = it * 8 + hw;
      int sel = task >> 6, r = task & 63;
      int e = e0 + r;
      if (sel < 2) {
        int node = eidx[sel * NE + e];
        float2 v = *(const float2*)&s[(size_t)node * 64 + p * 2];
        *(u32*)&Xs[lx<256>(r, sel * 64 + p * 2)] = (u32)f2b(v.x) | ((u32)f2b(v.y) << 16);
      } else {
        int r0 = toff[e], r1 = toff[e + 1];
        float a0 = 0.f, a1 = 0.f;
        for (int ri = r0; ri < r1; ++ri) {
          int tt = tids[ri];
          u32 pk = *(const u32*)&tmsg[(size_t)tt * 64 + p * 2];
          a0 += b2f((u16)(pk & 0xffff));
          a1 += b2f((u16)(pk >> 16));
        }
        *(u32*)&Xs[lx<256>(r, 192 + p * 2)] = (u32)f2b(a0) | ((u32)f2b(a1) << 16);
      }
    }
  }
  __syncthreads();

  // layer 1: [64 x 256] x [256 x 64]; wave w owns n-tile w
  f32x4 acc1[4];
  {
    float bias = b1[w * 16 + (l & 15)];
#pragma unroll
    for (int mt = 0; mt < 4; ++mt) acc1[mt] = (f32x4){bias, bias, bias, bias};
    for (int ks = 0; ks < 8; ++ks) {
      short8 bf = *(const short8*)(Wp1 + ((size_t)(ks * 4 + w) * 64 + l) * 8);
#pragma unroll
      for (int mt = 0; mt < 4; ++mt) {
        short8 af = *(const short8*)&Xs[lx<256>(mt * 16 + (l & 15), ks * 32 + ((l >> 4) << 3))];
        acc1[mt] = __builtin_amdgcn_mfma_f32_16x16x32_bf16(af, bf, acc1[mt], 0, 0, 0);
      }
    }
  }
#pragma unroll
  for (int mt = 0; mt < 4; ++mt)
#pragma unroll
    for (int q = 0; q < 4; ++q) {
      int r = mt * 16 + (l >> 4) * 4 + q;
      Hs[lx<64>(r, w * 16 + (l & 15))] = f2b(silu_f(acc1[mt][q]));
    }
  __syncthreads();

  // layer 2: [64 x 64] x [64 x 128]; wave w owns n-tiles {2w, 2w+1}
  f32x4 acc2[2][4];
#pragma unroll
  for (int pp = 0; pp < 2; ++pp) {
    int nt = w * 2 + pp;
    float bias = b2[nt * 16 + (l & 15)];
#pragma unroll
    for (int mt = 0; mt < 4; ++mt) acc2[pp][mt] = (f32x4){bias, bias, bias, bias};
    for (int ks = 0; ks < 2; ++ks) {
      short8 bf = *(const short8*)(Wp2 + ((size_t)(ks * 8 + nt) * 64 + l) * 8);
#pragma unroll
      for (int mt = 0; mt < 4; ++mt) {
        short8 af = *(const short8*)&Hs[lx<64>(mt * 16 + (l & 15), ks * 32 + ((l >> 4) << 3))];
        acc2[pp][mt] = __builtin_amdgcn_mfma_f32_16x16x32_bf16(af, bf, acc2[pp][mt], 0, 0, 0);
      }
    }
  }
  __syncthreads();  // all Xs reads done; reuse as out-stage [64][128]
#pragma unroll
  for (int pp = 0; pp < 2; ++pp)
#pragma unroll
    for (int mt = 0; mt < 4; ++mt)
#pragma unroll
      for (int q = 0; q < 4; ++q) {
        int r = mt * 16 + (l >> 4) * 4 + q;
        Xs[lx<128>(r, (w * 2 + pp) * 16 + (l & 15))] = f2b(acc2[pp][mt][q]);
      }
  __syncthreads();
  // coalesced out copy: 64 rows x 128 u16 = 64*16 = 1024 uint4 chunks (FIX: was 2048)
  for (int i = 0; i < 4; ++i) {
    int idx = i * 256 + tid;
    int r = idx >> 4, c0 = (idx & 15) << 3;
    uint4 val = *(const uint4*)&Xs[lx<128>(r, c0)];
    *(uint4*)(msg + (size_t)(e0 + r) * 128 + c0) = val;
  }
}

// ---------------- Kernel A (verbatim, proven)
__global__ __launch_bounds__(256) void kagg(
    const int* __restrict__ noff, const int* __restrict__ eids,
    const u16* __restrict__ msg, const float* __restrict__ edir,
    float* __restrict__ aggs, float* __restrict__ aggv) {
  const int lane = threadIdx.x & 63;
  const int wv = threadIdx.x >> 6;
  const int n = blockIdx.x * 4 + wv;
  if (n >= NN) return;
  const int r0 = noff[n], r1 = noff[n + 1];
  float as = 0.f, a0 = 0.f, a1 = 0.f, a2 = 0.f;
  for (int r = r0; r < r1; ++r) {
    const int e = eids[r];
    const u16* row = msg + (size_t)e * 128;
    float ms = b2f(row[lane]);
    float mc = b2f(row[64 + lane]);
    float dx = edir[(size_t)e * 3 + 0];
    float dy = edir[(size_t)e * 3 + 1];
    float dz = edir[(size_t)e * 3 + 2];
    as += ms;
    a0 += mc * dx;
    a1 += mc * dy;
    a2 += mc * dz;
  }
  aggs[(size_t)n * 64 + lane] = as;
  float* av = aggv + (size_t)n * 192 + (size_t)lane * 3;
  av[0] = a0;
  av[1] = a1;
  av[2] = a2;
}

// ---------------- Kernel N (verbatim, proven)
__global__ __launch_bounds__(64) void knode(
    const float* __restrict__ s, const float* __restrict__ v,
    const float* __restrict__ aggs, const float* __restrict__ aggv,
    const float* __restrict__ WU1, const float* __restrict__ bU1,
    const float* __restrict__ WU2, const float* __restrict__ bU2,
    const float* __restrict__ WG1, const float* __restrict__ bG1,
    const float* __restrict__ WG2, const float* __restrict__ bG2,
    const float* __restrict__ lng, const float* __restrict__ lnb,
    float* __restrict__ outs, float* __restrict__ outv) {
  __shared__ float xp[64 * 64];
  const int lane = threadIdx.x;
  const int n = blockIdx.x * 64 + lane;
  const bool valid = (n < NN);
  const int nc = valid ? n : 0;

  float hu[64], hg[64];
#pragma unroll
  for (int j = 0; j < 64; ++j) { hu[j] = bU1[j]; hg[j] = bG1[j]; }

  const float4* sr = (const float4*)(s + (size_t)nc * 64);
  MAC_CHUNK_DUAL(16, hu, hg, sr, WU1, WG1);
  const float4* ar = (const float4*)(aggs + (size_t)nc * 64);
  MAC_CHUNK_DUAL(16, hu, hg, ar, WU1 + 64 * 64, WG1 + 64 * 64);

  const float4* vr = (const float4*)(v + (size_t)nc * 192);
  for (int j4 = 0; j4 < 16; ++j4) {
    float4 a = vr[3 * j4], b = vr[3 * j4 + 1], c = vr[3 * j4 + 2];
    float4 xv;
    xv.x = sqrtf(a.x * a.x + a.y * a.y + a.z * a.z);
    xv.y = sqrtf(a.w * a.w + b.x * b.x + b.y * b.y);
    xv.z = sqrtf(b.z * b.z + b.w * b.w + c.x * c.x);
    xv.w = sqrtf(c.y * c.y + c.z * c.z + c.w * c.w);
    const float* __restrict__ Wra = WU1 + (128 + j4 * 4) * 64;
    const float* __restrict__ Wrb = WG1 + (128 + j4 * 4) * 64;
#pragma unroll
    for (int s_ = 0; s_ < 4; ++s_) {
      float xs = (s_ == 0) ? xv.x : (s_ == 1) ? xv.y : (s_ == 2) ? xv.z : xv.w;
#pragma unroll
      for (int j_ = 0; j_ < 64; ++j_) {
        hu[j_] += xs * Wra[s_ * 64 + j_];
        hg[j_] += xs * Wrb[s_ * 64 + j_];
      }
    }
  }

#pragma unroll
  for (int j = 0; j < 64; ++j) xp[lane * 64 + ((j + lane) & 63)] = silu_f(hu[j]);
  __syncthreads();
  float ou[64];
#pragma unroll
  for (int j = 0; j < 64; ++j) ou[j] = bU2[j];
  for (int k = 0; k < 64; ++k) {
    float hk = xp[lane * 64 + ((k + lane) & 63)];
    const float* __restrict__ Wr = WU2 + k * 64;
#pragma unroll
    for (int j = 0; j < 64; ++j) ou[j] += hk * Wr[j];
  }
#pragma unroll
  for (int j4 = 0; j4 < 16; ++j4) {
    float4 sv = sr[j4];
    ou[4 * j4 + 0] += sv.x; ou[4 * j4 + 1] += sv.y;
    ou[4 * j4 + 2] += sv.z; ou[4 * j4 + 3] += sv.w;
  }
  float mu = 0.f;
#pragma unroll
  for (int j = 0; j < 64; ++j) mu += ou[j];
  mu *= (1.f / 64.f);
  float var = 0.f;
#pragma unroll
  for (int j = 0; j < 64; ++j) { float d = ou[j] - mu; var += d * d; }
  var *= (1.f / 64.f);
  float rstd = rsqrtf(var + 1e-5f);
  if (valid) {
    float4* os4 = (float4*)(outs + (size_t)n * 64);
#pragma unroll
    for (int j4 = 0; j4 < 16; ++j4) {
      float4 o;
      float y0 = (ou[4 * j4 + 0] - mu) * rstd * lng[4 * j4 + 0] + lnb[4 * j4 + 0];
      float y1 = (ou[4 * j4 + 1] - mu) * rstd * lng[4 * j4 + 1] + lnb[4 * j4 + 1];
      float y2 = (ou[4 * j4 + 2] - mu) * rstd * lng[4 * j4 + 2] + lnb[4 * j4 + 2];
      float y3 = (ou[4 * j4 + 3] - mu) * rstd * lng[4 * j4 + 3] + lnb[4 * j4 + 3];
      o.x = silu_f(y0); o.y = silu_f(y1); o.z = silu_f(y2); o.w = silu_f(y3);
      os4[j4] = o;
    }
  }

  __syncthreads();
#pragma unroll
  for (int j = 0; j < 64; ++j) xp[lane * 64 + ((j + lane) & 63)] = silu_f(hg[j]);
  __syncthreads();
  float og[64];
#pragma unroll
  for (int j = 0; j < 64; ++j) og[j] = bG2[j];
  for (int k = 0; k < 64; ++k) {
    float hk = xp[lane * 64 + ((k + lane) & 63)];
    const float* __restrict__ Wr = WG2 + k * 64;
#pragma unroll
    for (int j = 0; j < 64; ++j) og[j] += hk * Wr[j];
  }

  if (valid) {
    const float4* av = (const float4*)(aggv + (size_t)nc * 192);
    float4* ov = (float4*)(outv + (size_t)n * 192);
#pragma unroll
    for (int j4 = 0; j4 < 16; ++j4) {
      float4 a = vr[3 * j4], b = vr[3 * j4 + 1], c = vr[3 * j4 + 2];
      float4 A = av[3 * j4], B = av[3 * j4 + 1], C = av[3 * j4 + 2];
      float g0 = sigm_f(og[4 * j4 + 0]);
      float g1 = sigm_f(og[4 * j4 + 1]);
      float g2 = sigm_f(og[4 * j4 + 2]);
      float g3 = sigm_f(og[4 * j4 + 3]);
      float4 o0, o1, o2;
      o0.x = a.x + g0 * A.x; o0.y = a.y + g0 * A.y; o0.z = a.z + g0 * A.z; o0.w = a.w + g1 * A.w;
      o1.x = b.x + g1 * B.x; o1.y = b.y + g1 * B.y; o1.z = b.z + g2 * B.z; o1.w = b.w + g2 * B.w;
      o2.x = c.x + g2 * C.x; o2.y = c.y + g3 * C.y; o2.z = c.z + g3 * C.z; o2.w = c.w + g3 * C.w;
      ov[3 * j4] = o0; ov[3 * j4 + 1] = o1; ov[3 * j4 + 2] = o2;
    }
  }
}

extern "C" void kernel_launch(void* const* d_in, const int* in_sizes, int n_in,
                              void* d_out, int out_size, void* d_ws, size_t ws_size,
                              hipStream_t stream) {
  const float* s     = (const float*)d_in[0];
  const float* v     = (const float*)d_in[1];
  const int*   eidx  = (const int*)d_in[2];
  const float* erbf  = (const float*)d_in[3];
  const float* edir  = (const float*)d_in[4];
  const int*   tkj   = (const int*)d_in[5];
  const int*   tji   = (const int*)d_in[6];
  const float* afeat = (const float*)d_in[7];
  const float* W_t1  = (const float*)d_in[8];
  const float* b_t1  = (const float*)d_in[9];
  const float* W_t2  = (const float*)d_in[10];
  const float* b_t2  = (const float*)d_in[11];
  const float* W_m1  = (const float*)d_in[12];
  const float* b_m1  = (const float*)d_in[13];
  const float* W_m2  = (const float*)d_in[14];
  const float* b_m2  = (const float*)d_in[15];
  const float* W_u1  = (const float*)d_in[16];
  const float* b_u1  = (const float*)d_in[17];
  const float* W_u2  = (const float*)d_in[18];
  const float* b_u2  = (const float*)d_in[19];
  const float* W_g1  = (const float*)d_in[20];
  const float* b_g1  = (const float*)d_in[21];
  const float* W_g2  = (const float*)d_in[22];
  const float* b_g2  = (const float*)d_in[23];
  const float* ln_g  = (const float*)d_in[24];
  const float* ln_b  = (const float*)d_in[25];

  char* w = (char*)d_ws;
  auto alloc = [&](size_t bytes) -> char* {
    char* p = w;
    w += (bytes + 255) & ~(size_t)255;
    return p;
  };
  int* toff = (int*)alloc((size_t)(NE + 1) * 4);
  int* noff = (int*)alloc((size_t)(NN + 1) * 4);
  int* tcnt = (int*)alloc((size_t)NE * 4);
  int* ncnt = (int*)alloc((size_t)NN * 4);
  int* tids = (int*)alloc((size_t)NT * 4);
  int* eids = (int*)alloc((size_t)NE * 4);
  int* bsum = (int*)alloc(1024 * 4);
  u16* msg  = (u16*)alloc((size_t)NE * 128 * 2);   // 204.8 MB
  u16* tmsg = (u16*)alloc((size_t)NT * 64 * 2);    // 102.4 MB
  u16* Wp_t1 = (u16*)alloc((size_t)5 * 4 * 512 * 2);   // Kp=160
  u16* Wp_t2 = (u16*)alloc((size_t)2 * 4 * 512 * 2);
  u16* Wp_m1 = (u16*)alloc((size_t)8 * 4 * 512 * 2);   // Kp=256
  u16* Wp_m2 = (u16*)alloc((size_t)2 * 8 * 512 * 2);
  float* aggs = (float*)tmsg;  // alias: tmsg dead after kmsg
  float* aggv = aggs + (size_t)NN * 64;

  hipMemsetAsync(tcnt, 0, (size_t)NE * 4, stream);
  hipMemsetAsync(ncnt, 0, (size_t)NN * 4, stream);

  khist<<<(NT + 255) / 256, 256, 0, stream>>>(tji, NT, tcnt);
  khist<<<(NE + 255) / 256, 256, 0, stream>>>(eidx + NE, NE, ncnt);

  kscan1<<<(NE + 1023) / 1024, 256, 0, stream>>>(tcnt, NE, toff, bsum);
  kscan2<<<1, 1024, 0, stream>>>(bsum, (NE + 1023) / 1024);
  kscan3<<<(NE + 1 + 255) / 256, 256, 0, stream>>>(toff, bsum, NE, NT);
  kscatter<<<(NT + 255) / 256, 256, 0, stream>>>(tji, toff, NT, tcnt, tids);

  kscan1<<<(NN + 1023) / 1024, 256, 0, stream>>>(ncnt, NN, noff, bsum);
  kscan2<<<1, 1024, 0, stream>>>(bsum, (NN + 1023) / 1024);
  kscan3<<<(NN + 1 + 255) / 256, 256, 0, stream>>>(noff, bsum, NN, NE);
  kscatter<<<(NE + 255) / 256, 256, 0, stream>>>(eidx + NE, noff, NE, ncnt, eids);

  kprepw<<<5, 256, 0, stream>>>(W_t1, 144, 160, 64, Wp_t1);
  kprepw<<<2, 256, 0, stream>>>(W_t2, 64, 64, 64, Wp_t2);
  kprepw<<<8, 256, 0, stream>>>(W_m1, 256, 256, 64, Wp_m1);
  kprepw<<<4, 256, 0, stream>>>(W_m2, 64, 64, 128, Wp_m2);

  ktrip_mfma<<<NT / 64, 256, 0, stream>>>(tkj, tji, erbf, afeat, Wp_t1, b_t1, Wp_t2, b_t2, tmsg);
  kmsg_mfma<<<NE / 64, 256, 0, stream>>>(eidx, s, erbf, toff, tids, tmsg,
                                         Wp_m1, b_m1, Wp_m2, b_m2, msg);
  kagg<<<(NN + 3) / 4, 256, 0, stream>>>(noff, eids, msg, edir, aggs, aggv);

  float* out_s = (float*)d_out;
  float* out_v = out_s + (size_t)NN * 64;
  knode<<<(NN + 63) / 64, 64, 0, stream>>>(s, v, aggs, aggv, W_u1, b_u1, W_u2, b_u2,
                                           W_g1, b_g1, W_g2, b_g2, ln_g, ln_b, out_s, out_v);
}

// Round 6
// 1158.508 us; speedup vs baseline: 3.3715x; 1.0665x over previous
//
#include <hip/hip_runtime.h>
#include <cstdint>
#include <cstddef>

#define NN 50000
#define NE 800000
#define NT 800000

typedef unsigned short u16;
typedef unsigned int u32;
typedef __attribute__((ext_vector_type(8))) short short8;
typedef __attribute__((ext_vector_type(4))) float f32x4;

__device__ __forceinline__ float silu_f(float x) { return x / (1.f + __expf(-x)); }
__device__ __forceinline__ float sigm_f(float x) { return 1.f / (1.f + __expf(-x)); }
__device__ __forceinline__ u16 f2b(float x) {
  u32 u = __float_as_uint(x);
  u32 r = u + 0x7fffu + ((u >> 16) & 1u);
  return (u16)(r >> 16);
}
__device__ __forceinline__ float b2f(u16 h) { return __uint_as_float(((u32)h) << 16); }

// XOR-swizzled LDS elem offset for row-major [*][RW] u16 tiles (16B-chunk ^ (r&7)).
template <int RW>
__device__ __forceinline__ int lx(int r, int c) {
  return r * RW + ((((c >> 3) ^ (r & 7)) << 3) | (c & 7));
}

#define MAC_CHUNK_DUAL(NI4, HA, HB, XPTR, WA, WB)                           \
  for (int i4 = 0; i4 < (NI4); ++i4) {                                      \
    float4 xv = (XPTR)[i4];                                                 \
    const float* __restrict__ Wra = (WA) + i4 * 256;                        \
    const float* __restrict__ Wrb = (WB) + i4 * 256;                        \
    _Pragma("unroll")                                                       \
    for (int s_ = 0; s_ < 4; ++s_) {                                        \
      float xs = (s_ == 0) ? xv.x : (s_ == 1) ? xv.y : (s_ == 2) ? xv.z : xv.w; \
      _Pragma("unroll")                                                     \
      for (int j_ = 0; j_ < 64; ++j_) {                                     \
        (HA)[j_] += xs * Wra[s_ * 64 + j_];                                 \
        (HB)[j_] += xs * Wrb[s_ * 64 + j_];                                 \
      }                                                                     \
    }                                                                       \
  }

// ---------------- bf16 pre-conversion (streaming)
__global__ __launch_bounds__(256) void kcvt(const float* __restrict__ in,
                                            u16* __restrict__ out, int n4) {
  int i = blockIdx.x * 256 + threadIdx.x;
  if (i >= n4) return;
  float4 v = ((const float4*)in)[i];
  uint2 p;
  p.x = (u32)f2b(v.x) | ((u32)f2b(v.y) << 16);
  p.y = (u32)f2b(v.z) | ((u32)f2b(v.w) << 16);
  ((uint2*)out)[i] = p;
}

// ---------------- CSR building
__global__ __launch_bounds__(256) void khist(const int* __restrict__ keys, int n,
                                             int* __restrict__ cnt) {
  int i = blockIdx.x * 256 + threadIdx.x;
  if (i < n) atomicAdd(&cnt[keys[i]], 1);
}

__global__ __launch_bounds__(256) void kscan1(const int* __restrict__ in, int n,
                                              int* __restrict__ out, int* __restrict__ bsum) {
  __shared__ int sh[256];
  int tid = threadIdx.x;
  size_t base = (size_t)blockIdx.x * 1024;
  int v[4];
  int acc = 0;
#pragma unroll
  for (int q = 0; q < 4; ++q) {
    size_t i = base + (size_t)tid * 4 + q;
    int x = (i < (size_t)n) ? in[i] : 0;
    v[q] = acc;
    acc += x;
  }
  sh[tid] = acc;
  __syncthreads();
  for (int off = 1; off < 256; off <<= 1) {
    int y = (tid >= off) ? sh[tid - off] : 0;
    __syncthreads();
    sh[tid] += y;
    __syncthreads();
  }
  int excl = (tid == 0) ? 0 : sh[tid - 1];
  if (tid == 255) bsum[blockIdx.x] = sh[255];
#pragma unroll
  for (int q = 0; q < 4; ++q) {
    size_t i = base + (size_t)tid * 4 + q;
    if (i < (size_t)n) out[i] = excl + v[q];
  }
}

__global__ __launch_bounds__(1024) void kscan2(int* __restrict__ bsum, int nb) {
  __shared__ int sh[1024];
  int tid = threadIdx.x;
  sh[tid] = (tid < nb) ? bsum[tid] : 0;
  __syncthreads();
  for (int off = 1; off < 1024; off <<= 1) {
    int y = (tid >= off) ? sh[tid - off] : 0;
    __syncthreads();
    sh[tid] += y;
    __syncthreads();
  }
  if (tid < nb) bsum[tid] = (tid == 0) ? 0 : sh[tid - 1];
}

__global__ __launch_bounds__(256) void kscan3(int* __restrict__ out, const int* __restrict__ bsum,
                                              int n, int total) {
  int i = blockIdx.x * 256 + threadIdx.x;
  if (i < n) out[i] += bsum[i >> 10];
  else if (i == n) out[n] = total;
}

// inverse-permutation scatter: inv[i] = slot of item i in key-sorted order
__global__ __launch_bounds__(256) void kscatter_inv(const int* __restrict__ keys,
                                                    const int* __restrict__ off, int n,
                                                    int* __restrict__ cnt, int* __restrict__ inv) {
  int i = blockIdx.x * 256 + threadIdx.x;
  if (i < n) {
    int k = keys[i];
    int slot = off[k] + (atomicSub(&cnt[k], 1) - 1);
    inv[i] = slot;
  }
}

// edge variant: also pre-sort edge_dir into slot order
__global__ __launch_bounds__(256) void kscatter_inv_dir(const int* __restrict__ keys,
                                                        const int* __restrict__ off, int n,
                                                        int* __restrict__ cnt, int* __restrict__ inv,
                                                        const float* __restrict__ dir,
                                                        float* __restrict__ dir_s) {
  int i = blockIdx.x * 256 + threadIdx.x;
  if (i < n) {
    int k = keys[i];
    int slot = off[k] + (atomicSub(&cnt[k], 1) - 1);
    inv[i] = slot;
    dir_s[(size_t)slot * 3 + 0] = dir[(size_t)i * 3 + 0];
    dir_s[(size_t)slot * 3 + 1] = dir[(size_t)i * 3 + 1];
    dir_s[(size_t)slot * 3 + 2] = dir[(size_t)i * 3 + 2];
  }
}

// ---------------- Weight prep: f32 [K x N] -> bf16 B-fragment pack for 16x16x32 MFMA (proven)
__global__ __launch_bounds__(256) void kprepw(const float* __restrict__ W, int K, int Kp, int N,
                                              u16* __restrict__ out) {
  int tid = blockIdx.x * 256 + threadIdx.x;
  int total = (Kp / 32) * (N / 16) * 64;
  if (tid >= total) return;
  int l = tid & 63;
  int f = tid >> 6;
  int nt = f % (N / 16);
  int kt = f / (N / 16);
  int k0 = kt * 32 + (l >> 4) * 8;
  int n = nt * 16 + (l & 15);
  u16 vals[8];
#pragma unroll
  for (int j = 0; j < 8; ++j) {
    int kk = k0 + j;
    vals[j] = (kk < K) ? f2b(W[(size_t)kk * N + n]) : (u16)0;
  }
  uint4* dst = (uint4*)(out + (size_t)f * 512 + l * 8);
  uint4 p;
  p.x = (u32)vals[0] | ((u32)vals[1] << 16);
  p.y = (u32)vals[2] | ((u32)vals[3] << 16);
  p.z = (u32)vals[4] | ((u32)vals[5] << 16);
  p.w = (u32)vals[6] | ((u32)vals[7] << 16);
  *dst = p;
}

// ---------------- Kernel T (MFMA): triplet MLP -> tmsg_s[tslot[t]][64] bf16 (edge-CSR order)
__global__ __launch_bounds__(256) void ktrip_mfma(
    const int* __restrict__ tkj, const int* __restrict__ tji,
    const u16* __restrict__ erbf_bf, const u16* __restrict__ afeat_bf,
    const int* __restrict__ tslot,
    const u16* __restrict__ Wp1, const float* __restrict__ b1,
    const u16* __restrict__ Wp2, const float* __restrict__ b2,
    u16* __restrict__ tmsg_s) {
  __shared__ u16 Xs[64 * 192];
  __shared__ u16 Hs[64 * 64];
  const int tid = threadIdx.x;
  const int l = tid & 63;
  const int w = tid >> 6;
  const int t0 = blockIdx.x * 64;

  // stage gathered bf16 erbf rows (half-wave per 128B row) — pure copies, no cvt
  {
    const int hw = tid >> 5, p = tid & 31;
    for (int it = 0; it < 16; ++it) {
      int task = it * 8 + hw;
      int sel = task >> 6, r = task & 63;
      int t = t0 + r;
      int idx = sel ? tji[t] : tkj[t];
      u32 pk = *(const u32*)&erbf_bf[(size_t)idx * 64 + p * 2];
      *(u32*)&Xs[lx<192>(r, sel * 64 + p * 2)] = pk;
    }
    {
      int r = tid >> 2, c = (tid & 3) * 4;
      uint2 p2 = *(const uint2*)&afeat_bf[(size_t)(t0 + r) * 16 + c];
      *(uint2*)&Xs[lx<192>(r, 128 + c)] = p2;
    }
    for (int i = 0; i < 2; ++i) {
      int idx = i * 256 + tid;
      int r = idx >> 3, c = 144 + (idx & 7) * 2;
      *(u32*)&Xs[lx<192>(r, c)] = 0;
    }
  }
  __syncthreads();

  f32x4 acc1[4];
  {
    float bias = b1[w * 16 + (l & 15)];
#pragma unroll
    for (int mt = 0; mt < 4; ++mt) acc1[mt] = (f32x4){bias, bias, bias, bias};
    for (int ks = 0; ks < 5; ++ks) {
      short8 bf = *(const short8*)(Wp1 + ((size_t)(ks * 4 + w) * 64 + l) * 8);
#pragma unroll
      for (int mt = 0; mt < 4; ++mt) {
        short8 af = *(const short8*)&Xs[lx<192>(mt * 16 + (l & 15), ks * 32 + ((l >> 4) << 3))];
        acc1[mt] = __builtin_amdgcn_mfma_f32_16x16x32_bf16(af, bf, acc1[mt], 0, 0, 0);
      }
    }
  }
#pragma unroll
  for (int mt = 0; mt < 4; ++mt)
#pragma unroll
    for (int q = 0; q < 4; ++q) {
      int r = mt * 16 + (l >> 4) * 4 + q;
      Hs[lx<64>(r, w * 16 + (l & 15))] = f2b(silu_f(acc1[mt][q]));
    }
  __syncthreads();

  f32x4 acc2[4];
  {
    float bias = b2[w * 16 + (l & 15)];
#pragma unroll
    for (int mt = 0; mt < 4; ++mt) acc2[mt] = (f32x4){bias, bias, bias, bias};
    for (int ks = 0; ks < 2; ++ks) {
      short8 bf = *(const short8*)(Wp2 + ((size_t)(ks * 4 + w) * 64 + l) * 8);
#pragma unroll
      for (int mt = 0; mt < 4; ++mt) {
        short8 af = *(const short8*)&Hs[lx<64>(mt * 16 + (l & 15), ks * 32 + ((l >> 4) << 3))];
        acc2[mt] = __builtin_amdgcn_mfma_f32_16x16x32_bf16(af, bf, acc2[mt], 0, 0, 0);
      }
    }
  }
  __syncthreads();
#pragma unroll
  for (int mt = 0; mt < 4; ++mt)
#pragma unroll
    for (int q = 0; q < 4; ++q) {
      int r = mt * 16 + (l >> 4) * 4 + q;
      Xs[lx<64>(r, w * 16 + (l & 15))] = f2b(acc2[mt][q]);
    }
  __syncthreads();
  // out: 64 rows x 8 chunks = 512 uint4, scattered by tslot (128B row granularity)
  for (int i = 0; i < 2; ++i) {
    int idx = i * 256 + tid;
    int r = idx >> 3, c0 = (idx & 7) << 3;
    int slot = tslot[t0 + r];
    uint4 val = *(const uint4*)&Xs[lx<64>(r, c0)];
    *(uint4*)(tmsg_s + (size_t)slot * 64 + c0) = val;
  }
}

// ---------------- Kernel M (MFMA): edge MLP -> msg_s[eslot[e]][128] bf16 (node-CSR order)
// aagg read is CONTIGUOUS rows [toff[e], toff[e+1]) of tmsg_s.
__global__ __launch_bounds__(256) void kmsg_mfma(
    const int* __restrict__ eidx, const u16* __restrict__ s_bf,
    const u16* __restrict__ erbf_bf,
    const int* __restrict__ toff, const u16* __restrict__ tmsg_s,
    const int* __restrict__ eslot,
    const u16* __restrict__ Wp1, const float* __restrict__ b1,
    const u16* __restrict__ Wp2, const float* __restrict__ b2,
    u16* __restrict__ msg_s) {
  __shared__ u16 Xs[64 * 256];  // 32KB (reused as out-stage [64][128])
  __shared__ u16 Hs[64 * 64];   // 8KB
  const int tid = threadIdx.x;
  const int l = tid & 63;
  const int w = tid >> 6;
  const int e0 = blockIdx.x * 64;

  // stage erbf cols 128..191: 64 rows x 8 chunks = 512 uint4 (pure copy)
  for (int i = 0; i < 2; ++i) {
    int idx = i * 256 + tid;
    int r = idx >> 3, c0 = (idx & 7) << 3;
    uint4 vv = *(const uint4*)&erbf_bf[(size_t)(e0 + r) * 64 + c0];
    *(uint4*)&Xs[lx<256>(r, 128 + c0)] = vv;
  }
  // stage s[src], s[dst] (bf16 gather, half-wave per 128B row) + aagg contiguous CSR sum
  {
    const int hw = tid >> 5, p = tid & 31;
    for (int it = 0; it < 24; ++it) {
      int task = it * 8 + hw;
      int sel = task >> 6, r = task & 63;
      int e = e0 + r;
      if (sel < 2) {
        int node = eidx[sel * NE + e];
        u32 pk = *(const u32*)&s_bf[(size_t)node * 64 + p * 2];
        *(u32*)&Xs[lx<256>(r, sel * 64 + p * 2)] = pk;
      } else {
        int r0 = toff[e], r1 = toff[e + 1];
        float a0 = 0.f, a1 = 0.f;
        for (int ri = r0; ri < r1; ++ri) {
          u32 pk = *(const u32*)&tmsg_s[(size_t)ri * 64 + p * 2];
          a0 += b2f((u16)(pk & 0xffff));
          a1 += b2f((u16)(pk >> 16));
        }
        *(u32*)&Xs[lx<256>(r, 192 + p * 2)] = (u32)f2b(a0) | ((u32)f2b(a1) << 16);
      }
    }
  }
  __syncthreads();

  // layer 1: [64 x 256] x [256 x 64]; wave w owns n-tile w
  f32x4 acc1[4];
  {
    float bias = b1[w * 16 + (l & 15)];
#pragma unroll
    for (int mt = 0; mt < 4; ++mt) acc1[mt] = (f32x4){bias, bias, bias, bias};
    for (int ks = 0; ks < 8; ++ks) {
      short8 bf = *(const short8*)(Wp1 + ((size_t)(ks * 4 + w) * 64 + l) * 8);
#pragma unroll
      for (int mt = 0; mt < 4; ++mt) {
        short8 af = *(const short8*)&Xs[lx<256>(mt * 16 + (l & 15), ks * 32 + ((l >> 4) << 3))];
        acc1[mt] = __builtin_amdgcn_mfma_f32_16x16x32_bf16(af, bf, acc1[mt], 0, 0, 0);
      }
    }
  }
#pragma unroll
  for (int mt = 0; mt < 4; ++mt)
#pragma unroll
    for (int q = 0; q < 4; ++q) {
      int r = mt * 16 + (l >> 4) * 4 + q;
      Hs[lx<64>(r, w * 16 + (l & 15))] = f2b(silu_f(acc1[mt][q]));
    }
  __syncthreads();

  // layer 2: [64 x 64] x [64 x 128]; wave w owns n-tiles {2w, 2w+1}
  f32x4 acc2[2][4];
#pragma unroll
  for (int pp = 0; pp < 2; ++pp) {
    int nt = w * 2 + pp;
    float bias = b2[nt * 16 + (l & 15)];
#pragma unroll
    for (int mt = 0; mt < 4; ++mt) acc2[pp][mt] = (f32x4){bias, bias, bias, bias};
    for (int ks = 0; ks < 2; ++ks) {
      short8 bf = *(const short8*)(Wp2 + ((size_t)(ks * 8 + nt) * 64 + l) * 8);
#pragma unroll
      for (int mt = 0; mt < 4; ++mt) {
        short8 af = *(const short8*)&Hs[lx<64>(mt * 16 + (l & 15), ks * 32 + ((l >> 4) << 3))];
        acc2[pp][mt] = __builtin_amdgcn_mfma_f32_16x16x32_bf16(af, bf, acc2[pp][mt], 0, 0, 0);
      }
    }
  }
  __syncthreads();  // all Xs reads done; reuse as out-stage [64][128]
#pragma unroll
  for (int pp = 0; pp < 2; ++pp)
#pragma unroll
    for (int mt = 0; mt < 4; ++mt)
#pragma unroll
      for (int q = 0; q < 4; ++q) {
        int r = mt * 16 + (l >> 4) * 4 + q;
        Xs[lx<128>(r, (w * 2 + pp) * 16 + (l & 15))] = f2b(acc2[pp][mt][q]);
      }
  __syncthreads();
  // out: 64 rows x 16 chunks = 1024 uint4, scattered by eslot (256B row granularity)
  for (int i = 0; i < 4; ++i) {
    int idx = i * 256 + tid;
    int r = idx >> 4, c0 = (idx & 15) << 3;
    int slot = eslot[e0 + r];
    uint4 val = *(const uint4*)&Xs[lx<128>(r, c0)];
    *(uint4*)(msg_s + (size_t)slot * 128 + c0) = val;
  }
}

// ---------------- Kernel A: wave-per-node STREAMING reduction over sorted msg rows
__global__ __launch_bounds__(256) void kagg(
    const int* __restrict__ noff, const u16* __restrict__ msg_s,
    const float* __restrict__ dir_s,
    float* __restrict__ aggs, float* __restrict__ aggv) {
  const int lane = threadIdx.x & 63;
  const int wv = threadIdx.x >> 6;
  const int n = blockIdx.x * 4 + wv;
  if (n >= NN) return;
  const int r0 = noff[n], r1 = noff[n + 1];
  float as = 0.f, a0 = 0.f, a1 = 0.f, a2 = 0.f;
  for (int r = r0; r < r1; ++r) {
    const u16* row = msg_s + (size_t)r * 128;
    float ms = b2f(row[lane]);
    float mc = b2f(row[64 + lane]);
    float dx = dir_s[(size_t)r * 3 + 0];
    float dy = dir_s[(size_t)r * 3 + 1];
    float dz = dir_s[(size_t)r * 3 + 2];
    as += ms;
    a0 += mc * dx;
    a1 += mc * dy;
    a2 += mc * dz;
  }
  aggs[(size_t)n * 64 + lane] = as;
  float* av = aggv + (size_t)n * 192 + (size_t)lane * 3;
  av[0] = a0;
  av[1] = a1;
  av[2] = a2;
}

// ---------------- Kernel N (verbatim, proven)
__global__ __launch_bounds__(64) void knode(
    const float* __restrict__ s, const float* __restrict__ v,
    const float* __restrict__ aggs, const float* __restrict__ aggv,
    const float* __restrict__ WU1, const float* __restrict__ bU1,
    const float* __restrict__ WU2, const float* __restrict__ bU2,
    const float* __restrict__ WG1, const float* __restrict__ bG1,
    const float* __restrict__ WG2, const float* __restrict__ bG2,
    const float* __restrict__ lng, const float* __restrict__ lnb,
    float* __restrict__ outs, float* __restrict__ outv) {
  __shared__ float xp[64 * 64];
  const int lane = threadIdx.x;
  const int n = blockIdx.x * 64 + lane;
  const bool valid = (n < NN);
  const int nc = valid ? n : 0;

  float hu[64], hg[64];
#pragma unroll
  for (int j = 0; j < 64; ++j) { hu[j] = bU1[j]; hg[j] = bG1[j]; }

  const float4* sr = (const float4*)(s + (size_t)nc * 64);
  MAC_CHUNK_DUAL(16, hu, hg, sr, WU1, WG1);
  const float4* ar = (const float4*)(aggs + (size_t)nc * 64);
  MAC_CHUNK_DUAL(16, hu, hg, ar, WU1 + 64 * 64, WG1 + 64 * 64);

  const float4* vr = (const float4*)(v + (size_t)nc * 192);
  for (int j4 = 0; j4 < 16; ++j4) {
    float4 a = vr[3 * j4], b = vr[3 * j4 + 1], c = vr[3 * j4 + 2];
    float4 xv;
    xv.x = sqrtf(a.x * a.x + a.y * a.y + a.z * a.z);
    xv.y = sqrtf(a.w * a.w + b.x * b.x + b.y * b.y);
    xv.z = sqrtf(b.z * b.z + b.w * b.w + c.x * c.x);
    xv.w = sqrtf(c.y * c.y + c.z * c.z + c.w * c.w);
    const float* __restrict__ Wra = WU1 + (128 + j4 * 4) * 64;
    const float* __restrict__ Wrb = WG1 + (128 + j4 * 4) * 64;
#pragma unroll
    for (int s_ = 0; s_ < 4; ++s_) {
      float xs = (s_ == 0) ? xv.x : (s_ == 1) ? xv.y : (s_ == 2) ? xv.z : xv.w;
#pragma unroll
      for (int j_ = 0; j_ < 64; ++j_) {
        hu[j_] += xs * Wra[s_ * 64 + j_];
        hg[j_] += xs * Wrb[s_ * 64 + j_];
      }
    }
  }

#pragma unroll
  for (int j = 0; j < 64; ++j) xp[lane * 64 + ((j + lane) & 63)] = silu_f(hu[j]);
  __syncthreads();
  float ou[64];
#pragma unroll
  for (int j = 0; j < 64; ++j) ou[j] = bU2[j];
  for (int k = 0; k < 64; ++k) {
    float hk = xp[lane * 64 + ((k + lane) & 63)];
    const float* __restrict__ Wr = WU2 + k * 64;
#pragma unroll
    for (int j = 0; j < 64; ++j) ou[j] += hk * Wr[j];
  }
#pragma unroll
  for (int j4 = 0; j4 < 16; ++j4) {
    float4 sv = sr[j4];
    ou[4 * j4 + 0] += sv.x; ou[4 * j4 + 1] += sv.y;
    ou[4 * j4 + 2] += sv.z; ou[4 * j4 + 3] += sv.w;
  }
  float mu = 0.f;
#pragma unroll
  for (int j = 0; j < 64; ++j) mu += ou[j];
  mu *= (1.f / 64.f);
  float var = 0.f;
#pragma unroll
  for (int j = 0; j < 64; ++j) { float d = ou[j] - mu; var += d * d; }
  var *= (1.f / 64.f);
  float rstd = rsqrtf(var + 1e-5f);
  if (valid) {
    float4* os4 = (float4*)(outs + (size_t)n * 64);
#pragma unroll
    for (int j4 = 0; j4 < 16; ++j4) {
      float4 o;
      float y0 = (ou[4 * j4 + 0] - mu) * rstd * lng[4 * j4 + 0] + lnb[4 * j4 + 0];
      float y1 = (ou[4 * j4 + 1] - mu) * rstd * lng[4 * j4 + 1] + lnb[4 * j4 + 1];
      float y2 = (ou[4 * j4 + 2] - mu) * rstd * lng[4 * j4 + 2] + lnb[4 * j4 + 2];
      float y3 = (ou[4 * j4 + 3] - mu) * rstd * lng[4 * j4 + 3] + lnb[4 * j4 + 3];
      o.x = silu_f(y0); o.y = silu_f(y1); o.z = silu_f(y2); o.w = silu_f(y3);
      os4[j4] = o;
    }
  }

  __syncthreads();
#pragma unroll
  for (int j = 0; j < 64; ++j) xp[lane * 64 + ((j + lane) & 63)] = silu_f(hg[j]);
  __syncthreads();
  float og[64];
#pragma unroll
  for (int j = 0; j < 64; ++j) og[j] = bG2[j];
  for (int k = 0; k < 64; ++k) {
    float hk = xp[lane * 64 + ((k + lane) & 63)];
    const float* __restrict__ Wr = WG2 + k * 64;
#pragma unroll
    for (int j = 0; j < 64; ++j) og[j] += hk * Wr[j];
  }

  if (valid) {
    const float4* av = (const float4*)(aggv + (size_t)nc * 192);
    float4* ov = (float4*)(outv + (size_t)n * 192);
#pragma unroll
    for (int j4 = 0; j4 < 16; ++j4) {
      float4 a = vr[3 * j4], b = vr[3 * j4 + 1], c = vr[3 * j4 + 2];
      float4 A = av[3 * j4], B = av[3 * j4 + 1], C = av[3 * j4 + 2];
      float g0 = sigm_f(og[4 * j4 + 0]);
      float g1 = sigm_f(og[4 * j4 + 1]);
      float g2 = sigm_f(og[4 * j4 + 2]);
      float g3 = sigm_f(og[4 * j4 + 3]);
      float4 o0, o1, o2;
      o0.x = a.x + g0 * A.x; o0.y = a.y + g0 * A.y; o0.z = a.z + g0 * A.z; o0.w = a.w + g1 * A.w;
      o1.x = b.x + g1 * B.x; o1.y = b.y + g1 * B.y; o1.z = b.z + g2 * B.z; o1.w = b.w + g2 * B.w;
      o2.x = c.x + g2 * C.x; o2.y = c.y + g3 * C.y; o2.z = c.z + g3 * C.z; o2.w = c.w + g3 * C.w;
      ov[3 * j4] = o0; ov[3 * j4 + 1] = o1; ov[3 * j4 + 2] = o2;
    }
  }
}

extern "C" void kernel_launch(void* const* d_in, const int* in_sizes, int n_in,
                              void* d_out, int out_size, void* d_ws, size_t ws_size,
                              hipStream_t stream) {
  const float* s     = (const float*)d_in[0];
  const float* v     = (const float*)d_in[1];
  const int*   eidx  = (const int*)d_in[2];
  const float* erbf  = (const float*)d_in[3];
  const float* edir  = (const float*)d_in[4];
  const int*   tkj   = (const int*)d_in[5];
  const int*   tji   = (const int*)d_in[6];
  const float* afeat = (const float*)d_in[7];
  const float* W_t1  = (const float*)d_in[8];
  const float* b_t1  = (const float*)d_in[9];
  const float* W_t2  = (const float*)d_in[10];
  const float* b_t2  = (const float*)d_in[11];
  const float* W_m1  = (const float*)d_in[12];
  const float* b_m1  = (const float*)d_in[13];
  const float* W_m2  = (const float*)d_in[14];
  const float* b_m2  = (const float*)d_in[15];
  const float* W_u1  = (const float*)d_in[16];
  const float* b_u1  = (const float*)d_in[17];
  const float* W_u2  = (const float*)d_in[18];
  const float* b_u2  = (const float*)d_in[19];
  const float* W_g1  = (const float*)d_in[20];
  const float* b_g1  = (const float*)d_in[21];
  const float* W_g2  = (const float*)d_in[22];
  const float* b_g2  = (const float*)d_in[23];
  const float* ln_g  = (const float*)d_in[24];
  const float* ln_b  = (const float*)d_in[25];

  char* w = (char*)d_ws;
  auto alloc = [&](size_t bytes) -> char* {
    char* p = w;
    w += (bytes + 255) & ~(size_t)255;
    return p;
  };
  int* toff  = (int*)alloc((size_t)(NE + 1) * 4);
  int* noff  = (int*)alloc((size_t)(NN + 1) * 4);
  int* tcnt  = (int*)alloc((size_t)NE * 4);
  int* ncnt  = (int*)alloc((size_t)NN * 4);
  int* tslot = (int*)alloc((size_t)NT * 4);
  int* eslot = (int*)alloc((size_t)NE * 4);
  int* bsum  = (int*)alloc(1024 * 4);
  float* dir_s = (float*)alloc((size_t)NE * 3 * 4);     // 9.6 MB
  u16* msg_s  = (u16*)alloc((size_t)NE * 128 * 2);      // 204.8 MB
  u16* tmsg_s = (u16*)alloc((size_t)NT * 64 * 2);       // 102.4 MB
  u16* erbf_bf = (u16*)alloc((size_t)NE * 64 * 2);      // 102.4 MB
  u16* s_bf    = (u16*)alloc((size_t)NN * 64 * 2);      // 6.4 MB
  u16* Wp_t1 = (u16*)alloc((size_t)5 * 4 * 512 * 2);    // Kp=160
  u16* Wp_t2 = (u16*)alloc((size_t)2 * 4 * 512 * 2);
  u16* Wp_m1 = (u16*)alloc((size_t)8 * 4 * 512 * 2);    // Kp=256
  u16* Wp_m2 = (u16*)alloc((size_t)2 * 8 * 512 * 2);
  // afeat_bf aliases msg_s head: read only by ktrip, msg_s written only later by kmsg
  u16* afeat_bf = msg_s;                                // 25.6 MB < 204.8 MB
  // aggs/aggv alias tmsg_s (dead after kmsg)
  float* aggs = (float*)tmsg_s;
  float* aggv = aggs + (size_t)NN * 64;

  hipMemsetAsync(tcnt, 0, (size_t)NE * 4, stream);
  hipMemsetAsync(ncnt, 0, (size_t)NN * 4, stream);

  // bf16 pre-conversion
  kcvt<<<(NE * 16 + 255) / 256, 256, 0, stream>>>(erbf, erbf_bf, NE * 16);
  kcvt<<<(NN * 16 + 255) / 256, 256, 0, stream>>>(s, s_bf, NN * 16);
  kcvt<<<(NT * 4 + 255) / 256, 256, 0, stream>>>(afeat, afeat_bf, NT * 4);

  khist<<<(NT + 255) / 256, 256, 0, stream>>>(tji, NT, tcnt);
  khist<<<(NE + 255) / 256, 256, 0, stream>>>(eidx + NE, NE, ncnt);

  kscan1<<<(NE + 1023) / 1024, 256, 0, stream>>>(tcnt, NE, toff, bsum);
  kscan2<<<1, 1024, 0, stream>>>(bsum, (NE + 1023) / 1024);
  kscan3<<<(NE + 1 + 255) / 256, 256, 0, stream>>>(toff, bsum, NE, NT);
  kscatter_inv<<<(NT + 255) / 256, 256, 0, stream>>>(tji, toff, NT, tcnt, tslot);

  kscan1<<<(NN + 1023) / 1024, 256, 0, stream>>>(ncnt, NN, noff, bsum);
  kscan2<<<1, 1024, 0, stream>>>(bsum, (NN + 1023) / 1024);
  kscan3<<<(NN + 1 + 255) / 256, 256, 0, stream>>>(noff, bsum, NN, NE);
  kscatter_inv_dir<<<(NE + 255) / 256, 256, 0, stream>>>(eidx + NE, noff, NE, ncnt, eslot,
                                                         edir, dir_s);

  kprepw<<<5, 256, 0, stream>>>(W_t1, 144, 160, 64, Wp_t1);
  kprepw<<<2, 256, 0, stream>>>(W_t2, 64, 64, 64, Wp_t2);
  kprepw<<<8, 256, 0, stream>>>(W_m1, 256, 256, 64, Wp_m1);
  kprepw<<<4, 256, 0, stream>>>(W_m2, 64, 64, 128, Wp_m2);

  ktrip_mfma<<<NT / 64, 256, 0, stream>>>(tkj, tji, erbf_bf, afeat_bf, tslot,
                                          Wp_t1, b_t1, Wp_t2, b_t2, tmsg_s);
  kmsg_mfma<<<NE / 64, 256, 0, stream>>>(eidx, s_bf, erbf_bf, toff, tmsg_s, eslot,
                                         Wp_m1, b_m1, Wp_m2, b_m2, msg_s);
  kagg<<<(NN + 3) / 4, 256, 0, stream>>>(noff, msg_s, dir_s, aggs, aggv);

  float* out_s = (float*)d_out;
  float* out_v = out_s + (size_t)NN * 64;
  knode<<<(NN + 63) / 64, 64, 0, stream>>>(s, v, aggs, aggv, W_u1, b_u1, W_u2, b_u2,
                                           W_g1, b_g1, W_g2, b_g2, ln_g, ln_b, out_s, out_v);
}

// Round 7
// 870.747 us; speedup vs baseline: 4.4857x; 1.3305x over previous
//
#include <hip/hip_runtime.h>
#include <cstdint>
#include <cstddef>

#define NN 50000
#define NE 800000
#define NT 800000

typedef unsigned short u16;
typedef unsigned int u32;
typedef __attribute__((ext_vector_type(8))) short short8;
typedef __attribute__((ext_vector_type(4))) float f32x4;

__device__ __forceinline__ float silu_f(float x) { return x / (1.f + __expf(-x)); }
__device__ __forceinline__ float sigm_f(float x) { return 1.f / (1.f + __expf(-x)); }
__device__ __forceinline__ u16 f2b(float x) {
  u32 u = __float_as_uint(x);
  u32 r = u + 0x7fffu + ((u >> 16) & 1u);
  return (u16)(r >> 16);
}
__device__ __forceinline__ float b2f(u16 h) { return __uint_as_float(((u32)h) << 16); }

// XOR-swizzled LDS elem offset for row-major [*][RW] u16 tiles (16B-chunk ^ (r&7)).
template <int RW>
__device__ __forceinline__ int lx(int r, int c) {
  return r * RW + ((((c >> 3) ^ (r & 7)) << 3) | (c & 7));
}

// ---------------- bf16 pre-conversion (streaming)
__global__ __launch_bounds__(256) void kcvt(const float* __restrict__ in,
                                            u16* __restrict__ out, int n4) {
  int i = blockIdx.x * 256 + threadIdx.x;
  if (i >= n4) return;
  float4 v = ((const float4*)in)[i];
  uint2 p;
  p.x = (u32)f2b(v.x) | ((u32)f2b(v.y) << 16);
  p.y = (u32)f2b(v.z) | ((u32)f2b(v.w) << 16);
  ((uint2*)out)[i] = p;
}

// ---------------- CSR building
__global__ __launch_bounds__(256) void khist(const int* __restrict__ keys, int n,
                                             int* __restrict__ cnt) {
  int i = blockIdx.x * 256 + threadIdx.x;
  if (i < n) atomicAdd(&cnt[keys[i]], 1);
}

__global__ __launch_bounds__(256) void kscan1(const int* __restrict__ in, int n,
                                              int* __restrict__ out, int* __restrict__ bsum) {
  __shared__ int sh[256];
  int tid = threadIdx.x;
  size_t base = (size_t)blockIdx.x * 1024;
  int v[4];
  int acc = 0;
#pragma unroll
  for (int q = 0; q < 4; ++q) {
    size_t i = base + (size_t)tid * 4 + q;
    int x = (i < (size_t)n) ? in[i] : 0;
    v[q] = acc;
    acc += x;
  }
  sh[tid] = acc;
  __syncthreads();
  for (int off = 1; off < 256; off <<= 1) {
    int y = (tid >= off) ? sh[tid - off] : 0;
    __syncthreads();
    sh[tid] += y;
    __syncthreads();
  }
  int excl = (tid == 0) ? 0 : sh[tid - 1];
  if (tid == 255) bsum[blockIdx.x] = sh[255];
#pragma unroll
  for (int q = 0; q < 4; ++q) {
    size_t i = base + (size_t)tid * 4 + q;
    if (i < (size_t)n) out[i] = excl + v[q];
  }
}

__global__ __launch_bounds__(1024) void kscan2(int* __restrict__ bsum, int nb) {
  __shared__ int sh[1024];
  int tid = threadIdx.x;
  sh[tid] = (tid < nb) ? bsum[tid] : 0;
  __syncthreads();
  for (int off = 1; off < 1024; off <<= 1) {
    int y = (tid >= off) ? sh[tid - off] : 0;
    __syncthreads();
    sh[tid] += y;
    __syncthreads();
  }
  if (tid < nb) bsum[tid] = (tid == 0) ? 0 : sh[tid - 1];
}

__global__ __launch_bounds__(256) void kscan3(int* __restrict__ out, const int* __restrict__ bsum,
                                              int n, int total) {
  int i = blockIdx.x * 256 + threadIdx.x;
  if (i < n) out[i] += bsum[i >> 10];
  else if (i == n) out[n] = total;
}

__global__ __launch_bounds__(256) void kscatter_inv(const int* __restrict__ keys,
                                                    const int* __restrict__ off, int n,
                                                    int* __restrict__ cnt, int* __restrict__ inv) {
  int i = blockIdx.x * 256 + threadIdx.x;
  if (i < n) {
    int k = keys[i];
    int slot = off[k] + (atomicSub(&cnt[k], 1) - 1);
    inv[i] = slot;
  }
}

__global__ __launch_bounds__(256) void kscatter_inv_dir(const int* __restrict__ keys,
                                                        const int* __restrict__ off, int n,
                                                        int* __restrict__ cnt, int* __restrict__ inv,
                                                        const float* __restrict__ dir,
                                                        float* __restrict__ dir_s) {
  int i = blockIdx.x * 256 + threadIdx.x;
  if (i < n) {
    int k = keys[i];
    int slot = off[k] + (atomicSub(&cnt[k], 1) - 1);
    inv[i] = slot;
    dir_s[(size_t)slot * 3 + 0] = dir[(size_t)i * 3 + 0];
    dir_s[(size_t)slot * 3 + 1] = dir[(size_t)i * 3 + 1];
    dir_s[(size_t)slot * 3 + 2] = dir[(size_t)i * 3 + 2];
  }
}

// ---------------- Weight prep: f32 [K x N] -> bf16 B-fragment pack (proven)
__global__ __launch_bounds__(256) void kprepw(const float* __restrict__ W, int K, int Kp, int N,
                                              u16* __restrict__ out) {
  int tid = blockIdx.x * 256 + threadIdx.x;
  int total = (Kp / 32) * (N / 16) * 64;
  if (tid >= total) return;
  int l = tid & 63;
  int f = tid >> 6;
  int nt = f % (N / 16);
  int kt = f / (N / 16);
  int k0 = kt * 32 + (l >> 4) * 8;
  int n = nt * 16 + (l & 15);
  u16 vals[8];
#pragma unroll
  for (int j = 0; j < 8; ++j) {
    int kk = k0 + j;
    vals[j] = (kk < K) ? f2b(W[(size_t)kk * N + n]) : (u16)0;
  }
  uint4* dst = (uint4*)(out + (size_t)f * 512 + l * 8);
  uint4 p;
  p.x = (u32)vals[0] | ((u32)vals[1] << 16);
  p.y = (u32)vals[2] | ((u32)vals[3] << 16);
  p.z = (u32)vals[4] | ((u32)vals[5] << 16);
  p.w = (u32)vals[6] | ((u32)vals[7] << 16);
  *dst = p;
}

// ---------------- Kernel T (MFMA, proven): triplet MLP -> tmsg_s[tslot[t]][64] bf16
__global__ __launch_bounds__(256) void ktrip_mfma(
    const int* __restrict__ tkj, const int* __restrict__ tji,
    const u16* __restrict__ erbf_bf, const u16* __restrict__ afeat_bf,
    const int* __restrict__ tslot,
    const u16* __restrict__ Wp1, const float* __restrict__ b1,
    const u16* __restrict__ Wp2, const float* __restrict__ b2,
    u16* __restrict__ tmsg_s) {
  __shared__ u16 Xs[64 * 192];
  __shared__ u16 Hs[64 * 64];
  const int tid = threadIdx.x;
  const int l = tid & 63;
  const int w = tid >> 6;
  const int t0 = blockIdx.x * 64;

  {
    const int hw = tid >> 5, p = tid & 31;
    for (int it = 0; it < 16; ++it) {
      int task = it * 8 + hw;
      int sel = task >> 6, r = task & 63;
      int t = t0 + r;
      int idx = sel ? tji[t] : tkj[t];
      u32 pk = *(const u32*)&erbf_bf[(size_t)idx * 64 + p * 2];
      *(u32*)&Xs[lx<192>(r, sel * 64 + p * 2)] = pk;
    }
    {
      int r = tid >> 2, c = (tid & 3) * 4;
      uint2 p2 = *(const uint2*)&afeat_bf[(size_t)(t0 + r) * 16 + c];
      *(uint2*)&Xs[lx<192>(r, 128 + c)] = p2;
    }
    for (int i = 0; i < 2; ++i) {
      int idx = i * 256 + tid;
      int r = idx >> 3, c = 144 + (idx & 7) * 2;
      *(u32*)&Xs[lx<192>(r, c)] = 0;
    }
  }
  __syncthreads();

  f32x4 acc1[4];
  {
    float bias = b1[w * 16 + (l & 15)];
#pragma unroll
    for (int mt = 0; mt < 4; ++mt) acc1[mt] = (f32x4){bias, bias, bias, bias};
    for (int ks = 0; ks < 5; ++ks) {
      short8 bf = *(const short8*)(Wp1 + ((size_t)(ks * 4 + w) * 64 + l) * 8);
#pragma unroll
      for (int mt = 0; mt < 4; ++mt) {
        short8 af = *(const short8*)&Xs[lx<192>(mt * 16 + (l & 15), ks * 32 + ((l >> 4) << 3))];
        acc1[mt] = __builtin_amdgcn_mfma_f32_16x16x32_bf16(af, bf, acc1[mt], 0, 0, 0);
      }
    }
  }
#pragma unroll
  for (int mt = 0; mt < 4; ++mt)
#pragma unroll
    for (int q = 0; q < 4; ++q) {
      int r = mt * 16 + (l >> 4) * 4 + q;
      Hs[lx<64>(r, w * 16 + (l & 15))] = f2b(silu_f(acc1[mt][q]));
    }
  __syncthreads();

  f32x4 acc2[4];
  {
    float bias = b2[w * 16 + (l & 15)];
#pragma unroll
    for (int mt = 0; mt < 4; ++mt) acc2[mt] = (f32x4){bias, bias, bias, bias};
    for (int ks = 0; ks < 2; ++ks) {
      short8 bf = *(const short8*)(Wp2 + ((size_t)(ks * 4 + w) * 64 + l) * 8);
#pragma unroll
      for (int mt = 0; mt < 4; ++mt) {
        short8 af = *(const short8*)&Hs[lx<64>(mt * 16 + (l & 15), ks * 32 + ((l >> 4) << 3))];
        acc2[mt] = __builtin_amdgcn_mfma_f32_16x16x32_bf16(af, bf, acc2[mt], 0, 0, 0);
      }
    }
  }
  __syncthreads();
#pragma unroll
  for (int mt = 0; mt < 4; ++mt)
#pragma unroll
    for (int q = 0; q < 4; ++q) {
      int r = mt * 16 + (l >> 4) * 4 + q;
      Xs[lx<64>(r, w * 16 + (l & 15))] = f2b(acc2[mt][q]);
    }
  __syncthreads();
  for (int i = 0; i < 2; ++i) {
    int idx = i * 256 + tid;
    int r = idx >> 3, c0 = (idx & 7) << 3;
    int slot = tslot[t0 + r];
    uint4 val = *(const uint4*)&Xs[lx<64>(r, c0)];
    *(uint4*)(tmsg_s + (size_t)slot * 64 + c0) = val;
  }
}

// ---------------- Kernel M (MFMA, proven): edge MLP -> msg_s[eslot[e]][128] bf16
__global__ __launch_bounds__(256) void kmsg_mfma(
    const int* __restrict__ eidx, const u16* __restrict__ s_bf,
    const u16* __restrict__ erbf_bf,
    const int* __restrict__ toff, const u16* __restrict__ tmsg_s,
    const int* __restrict__ eslot,
    const u16* __restrict__ Wp1, const float* __restrict__ b1,
    const u16* __restrict__ Wp2, const float* __restrict__ b2,
    u16* __restrict__ msg_s) {
  __shared__ u16 Xs[64 * 256];
  __shared__ u16 Hs[64 * 64];
  const int tid = threadIdx.x;
  const int l = tid & 63;
  const int w = tid >> 6;
  const int e0 = blockIdx.x * 64;

  for (int i = 0; i < 2; ++i) {
    int idx = i * 256 + tid;
    int r = idx >> 3, c0 = (idx & 7) << 3;
    uint4 vv = *(const uint4*)&erbf_bf[(size_t)(e0 + r) * 64 + c0];
    *(uint4*)&Xs[lx<256>(r, 128 + c0)] = vv;
  }
  {
    const int hw = tid >> 5, p = tid & 31;
    for (int it = 0; it < 24; ++it) {
      int task = it * 8 + hw;
      int sel = task >> 6, r = task & 63;
      int e = e0 + r;
      if (sel < 2) {
        int node = eidx[sel * NE + e];
        u32 pk = *(const u32*)&s_bf[(size_t)node * 64 + p * 2];
        *(u32*)&Xs[lx<256>(r, sel * 64 + p * 2)] = pk;
      } else {
        int r0 = toff[e], r1 = toff[e + 1];
        float a0 = 0.f, a1 = 0.f;
        for (int ri = r0; ri < r1; ++ri) {
          u32 pk = *(const u32*)&tmsg_s[(size_t)ri * 64 + p * 2];
          a0 += b2f((u16)(pk & 0xffff));
          a1 += b2f((u16)(pk >> 16));
        }
        *(u32*)&Xs[lx<256>(r, 192 + p * 2)] = (u32)f2b(a0) | ((u32)f2b(a1) << 16);
      }
    }
  }
  __syncthreads();

  f32x4 acc1[4];
  {
    float bias = b1[w * 16 + (l & 15)];
#pragma unroll
    for (int mt = 0; mt < 4; ++mt) acc1[mt] = (f32x4){bias, bias, bias, bias};
    for (int ks = 0; ks < 8; ++ks) {
      short8 bf = *(const short8*)(Wp1 + ((size_t)(ks * 4 + w) * 64 + l) * 8);
#pragma unroll
      for (int mt = 0; mt < 4; ++mt) {
        short8 af = *(const short8*)&Xs[lx<256>(mt * 16 + (l & 15), ks * 32 + ((l >> 4) << 3))];
        acc1[mt] = __builtin_amdgcn_mfma_f32_16x16x32_bf16(af, bf, acc1[mt], 0, 0, 0);
      }
    }
  }
#pragma unroll
  for (int mt = 0; mt < 4; ++mt)
#pragma unroll
    for (int q = 0; q < 4; ++q) {
      int r = mt * 16 + (l >> 4) * 4 + q;
      Hs[lx<64>(r, w * 16 + (l & 15))] = f2b(silu_f(acc1[mt][q]));
    }
  __syncthreads();

  f32x4 acc2[2][4];
#pragma unroll
  for (int pp = 0; pp < 2; ++pp) {
    int nt = w * 2 + pp;
    float bias = b2[nt * 16 + (l & 15)];
#pragma unroll
    for (int mt = 0; mt < 4; ++mt) acc2[pp][mt] = (f32x4){bias, bias, bias, bias};
    for (int ks = 0; ks < 2; ++ks) {
      short8 bf = *(const short8*)(Wp2 + ((size_t)(ks * 8 + nt) * 64 + l) * 8);
#pragma unroll
      for (int mt = 0; mt < 4; ++mt) {
        short8 af = *(const short8*)&Hs[lx<64>(mt * 16 + (l & 15), ks * 32 + ((l >> 4) << 3))];
        acc2[pp][mt] = __builtin_amdgcn_mfma_f32_16x16x32_bf16(af, bf, acc2[pp][mt], 0, 0, 0);
      }
    }
  }
  __syncthreads();
#pragma unroll
  for (int pp = 0; pp < 2; ++pp)
#pragma unroll
    for (int mt = 0; mt < 4; ++mt)
#pragma unroll
      for (int q = 0; q < 4; ++q) {
        int r = mt * 16 + (l >> 4) * 4 + q;
        Xs[lx<128>(r, (w * 2 + pp) * 16 + (l & 15))] = f2b(acc2[pp][mt][q]);
      }
  __syncthreads();
  for (int i = 0; i < 4; ++i) {
    int idx = i * 256 + tid;
    int r = idx >> 4, c0 = (idx & 15) << 3;
    int slot = eslot[e0 + r];
    uint4 val = *(const uint4*)&Xs[lx<128>(r, c0)];
    *(uint4*)(msg_s + (size_t)slot * 128 + c0) = val;
  }
}

// ---------------- Kernel A: streaming CSR reduction; aggs out as bf16, aggv f32
__global__ __launch_bounds__(256) void kagg(
    const int* __restrict__ noff, const u16* __restrict__ msg_s,
    const float* __restrict__ dir_s,
    u16* __restrict__ aggs_bf, float* __restrict__ aggv) {
  const int lane = threadIdx.x & 63;
  const int wv = threadIdx.x >> 6;
  const int n = blockIdx.x * 4 + wv;
  if (n >= NN) return;
  const int r0 = noff[n], r1 = noff[n + 1];
  float as = 0.f, a0 = 0.f, a1 = 0.f, a2 = 0.f;
  for (int r = r0; r < r1; ++r) {
    const u16* row = msg_s + (size_t)r * 128;
    float ms = b2f(row[lane]);
    float mc = b2f(row[64 + lane]);
    float dx = dir_s[(size_t)r * 3 + 0];
    float dy = dir_s[(size_t)r * 3 + 1];
    float dz = dir_s[(size_t)r * 3 + 2];
    as += ms;
    a0 += mc * dx;
    a1 += mc * dy;
    a2 += mc * dz;
  }
  aggs_bf[(size_t)n * 64 + lane] = f2b(as);
  float* av = aggv + (size_t)n * 192 + (size_t)lane * 3;
  av[0] = a0;
  av[1] = a1;
  av[2] = a2;
}

// ---------------- Kernel N (MFMA): node update, 64 nodes/block, 256 threads
// X [64][192] = s_bf | aggs_bf | vnorm ; dual layer1 (U,G); LN + gated v-update epilogue
__global__ __launch_bounds__(256) void knode_mfma(
    const u16* __restrict__ s_bf, const float* __restrict__ v,
    const u16* __restrict__ aggs_bf, const float* __restrict__ aggv,
    const u16* __restrict__ WpU1, const float* __restrict__ bU1,
    const u16* __restrict__ WpU2, const float* __restrict__ bU2,
    const u16* __restrict__ WpG1, const float* __restrict__ bG1,
    const u16* __restrict__ WpG2, const float* __restrict__ bG2,
    const float* __restrict__ lng, const float* __restrict__ lnb,
    float* __restrict__ outs, float* __restrict__ outv) {
  __shared__ __align__(16) char smem[64 * 192 * 2 + 2 * 64 * 64 * 2];  // 40KB
  u16* Xs = (u16*)smem;                      // [64][192] swizzled
  u16* Hu = (u16*)(smem + 64 * 192 * 2);     // [64][64]
  u16* Hg = Hu + 64 * 64;                    // [64][64]
  float* Fs = (float*)smem;                  // [64][68] padded f32, aliases Xs (17KB<24KB)

  const int tid = threadIdx.x;
  const int l = tid & 63;
  const int w = tid >> 6;
  const int n0 = blockIdx.x * 64;

  // ---- stage: cols 0..63 s_bf, 64..127 aggs_bf (pure copies; nodes contiguous)
  for (int i = 0; i < 2; ++i) {
    int idx = i * 256 + tid;                 // 512 tasks: 64 rows x 8 chunks
    int r = idx >> 3, c0 = (idx & 7) << 3;
    int nr = n0 + r; if (nr >= NN) nr = NN - 1;
    uint4 a = *(const uint4*)&s_bf[(size_t)nr * 64 + c0];
    *(uint4*)&Xs[lx<192>(r, c0)] = a;
    uint4 b = *(const uint4*)&aggs_bf[(size_t)nr * 64 + c0];
    *(uint4*)&Xs[lx<192>(r, 64 + c0)] = b;
  }
  // cols 128..191: v_norm computed on the fly
  for (int it = 0; it < 16; ++it) {
    int idx = it * 256 + tid;                // 4096 norms
    int r = idx >> 6, c = idx & 63;
    int nr = n0 + r; if (nr >= NN) nr = NN - 1;
    const float* vp = v + (size_t)nr * 192 + c * 3;
    float x = vp[0], y = vp[1], z = vp[2];
    Xs[lx<192>(r, 128 + c)] = f2b(sqrtf(x * x + y * y + z * z));
  }
  __syncthreads();

  // ---- layer 1 (dual B): K=192, 6 k-steps
  f32x4 au[4], ag[4];
  {
    float biu = bU1[w * 16 + (l & 15)], big = bG1[w * 16 + (l & 15)];
#pragma unroll
    for (int mt = 0; mt < 4; ++mt) {
      au[mt] = (f32x4){biu, biu, biu, biu};
      ag[mt] = (f32x4){big, big, big, big};
    }
    for (int ks = 0; ks < 6; ++ks) {
      short8 bu = *(const short8*)(WpU1 + ((size_t)(ks * 4 + w) * 64 + l) * 8);
      short8 bg = *(const short8*)(WpG1 + ((size_t)(ks * 4 + w) * 64 + l) * 8);
#pragma unroll
      for (int mt = 0; mt < 4; ++mt) {
        short8 af = *(const short8*)&Xs[lx<192>(mt * 16 + (l & 15), ks * 32 + ((l >> 4) << 3))];
        au[mt] = __builtin_amdgcn_mfma_f32_16x16x32_bf16(af, bu, au[mt], 0, 0, 0);
        ag[mt] = __builtin_amdgcn_mfma_f32_16x16x32_bf16(af, bg, ag[mt], 0, 0, 0);
      }
    }
  }
#pragma unroll
  for (int mt = 0; mt < 4; ++mt)
#pragma unroll
    for (int q = 0; q < 4; ++q) {
      int r = mt * 16 + (l >> 4) * 4 + q;
      Hu[lx<64>(r, w * 16 + (l & 15))] = f2b(silu_f(au[mt][q]));
      Hg[lx<64>(r, w * 16 + (l & 15))] = f2b(silu_f(ag[mt][q]));
    }
  __syncthreads();

  // ---- layer 2 (both paths) into registers
  f32x4 ou[4], og[4];
  {
    float biu = bU2[w * 16 + (l & 15)], big = bG2[w * 16 + (l & 15)];
#pragma unroll
    for (int mt = 0; mt < 4; ++mt) {
      ou[mt] = (f32x4){biu, biu, biu, biu};
      og[mt] = (f32x4){big, big, big, big};
    }
    for (int ks = 0; ks < 2; ++ks) {
      short8 bu = *(const short8*)(WpU2 + ((size_t)(ks * 4 + w) * 64 + l) * 8);
      short8 bg = *(const short8*)(WpG2 + ((size_t)(ks * 4 + w) * 64 + l) * 8);
#pragma unroll
      for (int mt = 0; mt < 4; ++mt) {
        short8 afu = *(const short8*)&Hu[lx<64>(mt * 16 + (l & 15), ks * 32 + ((l >> 4) << 3))];
        ou[mt] = __builtin_amdgcn_mfma_f32_16x16x32_bf16(afu, bu, ou[mt], 0, 0, 0);
        short8 afg = *(const short8*)&Hg[lx<64>(mt * 16 + (l & 15), ks * 32 + ((l >> 4) << 3))];
        og[mt] = __builtin_amdgcn_mfma_f32_16x16x32_bf16(afg, bg, og[mt], 0, 0, 0);
      }
    }
  }
  // residual: s_new = s + mlp_u (s from staged Xs cols 0..63)
#pragma unroll
  for (int mt = 0; mt < 4; ++mt)
#pragma unroll
    for (int q = 0; q < 4; ++q) {
      int r = mt * 16 + (l >> 4) * 4 + q;
      ou[mt][q] += b2f(Xs[lx<192>(r, w * 16 + (l & 15))]);
    }
  __syncthreads();  // all Xs reads done; Fs may overwrite

  // ---- LN phase: ou -> Fs, per-node mean/var via 4-lane groups
#pragma unroll
  for (int mt = 0; mt < 4; ++mt)
#pragma unroll
    for (int q = 0; q < 4; ++q) {
      int r = mt * 16 + (l >> 4) * 4 + q;
      Fs[r * 68 + w * 16 + (l & 15)] = ou[mt][q];
    }
  __syncthreads();
  {
    int r = tid >> 2, c0 = (tid & 3) * 16;
    float xv[16];
#pragma unroll
    for (int j4 = 0; j4 < 4; ++j4) {
      float4 t = *(const float4*)&Fs[r * 68 + c0 + j4 * 4];
      xv[j4 * 4 + 0] = t.x; xv[j4 * 4 + 1] = t.y;
      xv[j4 * 4 + 2] = t.z; xv[j4 * 4 + 3] = t.w;
    }
    float sm = 0.f, sq = 0.f;
#pragma unroll
    for (int j = 0; j < 16; ++j) { sm += xv[j]; sq += xv[j] * xv[j]; }
    sm += __shfl_xor(sm, 1); sq += __shfl_xor(sq, 1);
    sm += __shfl_xor(sm, 2); sq += __shfl_xor(sq, 2);
    float mu = sm * (1.f / 64.f);
    float var = sq * (1.f / 64.f) - mu * mu;
    float rstd = rsqrtf(var + 1e-5f);
    if (n0 + r < NN) {
      float* op = outs + (size_t)(n0 + r) * 64 + c0;
#pragma unroll
      for (int j4 = 0; j4 < 4; ++j4) {
        float4 o;
        float y0 = (xv[j4 * 4 + 0] - mu) * rstd * lng[c0 + j4 * 4 + 0] + lnb[c0 + j4 * 4 + 0];
        float y1 = (xv[j4 * 4 + 1] - mu) * rstd * lng[c0 + j4 * 4 + 1] + lnb[c0 + j4 * 4 + 1];
        float y2 = (xv[j4 * 4 + 2] - mu) * rstd * lng[c0 + j4 * 4 + 2] + lnb[c0 + j4 * 4 + 2];
        float y3 = (xv[j4 * 4 + 3] - mu) * rstd * lng[c0 + j4 * 4 + 3] + lnb[c0 + j4 * 4 + 3];
        o.x = silu_f(y0); o.y = silu_f(y1); o.z = silu_f(y2); o.w = silu_f(y3);
        *(float4*)(op + j4 * 4) = o;
      }
    }
  }
  __syncthreads();

  // ---- gate phase: og -> Fs, then v_new = v + sigmoid(og)*aggv
#pragma unroll
  for (int mt = 0; mt < 4; ++mt)
#pragma unroll
    for (int q = 0; q < 4; ++q) {
      int r = mt * 16 + (l >> 4) * 4 + q;
      Fs[r * 68 + w * 16 + (l & 15)] = og[mt][q];
    }
  __syncthreads();
  {
    int r = tid >> 2, c0 = (tid & 3) * 16;
    int nr = n0 + r;
    if (nr < NN) {
      float gate[16];
#pragma unroll
      for (int j = 0; j < 16; ++j) gate[j] = sigm_f(Fs[r * 68 + c0 + j]);
      const float4* vp = (const float4*)(v + (size_t)nr * 192 + c0 * 3);
      const float4* ap = (const float4*)(aggv + (size_t)nr * 192 + c0 * 3);
      float4* op = (float4*)(outv + (size_t)nr * 192 + c0 * 3);
#pragma unroll
      for (int j4 = 0; j4 < 12; ++j4) {
        float4 vv = vp[j4], av = ap[j4], o;
        o.x = vv.x + gate[(j4 * 4 + 0) / 3] * av.x;
        o.y = vv.y + gate[(j4 * 4 + 1) / 3] * av.y;
        o.z = vv.z + gate[(j4 * 4 + 2) / 3] * av.z;
        o.w = vv.w + gate[(j4 * 4 + 3) / 3] * av.w;
        op[j4] = o;
      }
    }
  }
}

extern "C" void kernel_launch(void* const* d_in, const int* in_sizes, int n_in,
                              void* d_out, int out_size, void* d_ws, size_t ws_size,
                              hipStream_t stream) {
  const float* s     = (const float*)d_in[0];
  const float* v     = (const float*)d_in[1];
  const int*   eidx  = (const int*)d_in[2];
  const float* erbf  = (const float*)d_in[3];
  const float* edir  = (const float*)d_in[4];
  const int*   tkj   = (const int*)d_in[5];
  const int*   tji   = (const int*)d_in[6];
  const float* afeat = (const float*)d_in[7];
  const float* W_t1  = (const float*)d_in[8];
  const float* b_t1  = (const float*)d_in[9];
  const float* W_t2  = (const float*)d_in[10];
  const float* b_t2  = (const float*)d_in[11];
  const float* W_m1  = (const float*)d_in[12];
  const float* b_m1  = (const float*)d_in[13];
  const float* W_m2  = (const float*)d_in[14];
  const float* b_m2  = (const float*)d_in[15];
  const float* W_u1  = (const float*)d_in[16];
  const float* b_u1  = (const float*)d_in[17];
  const float* W_u2  = (const float*)d_in[18];
  const float* b_u2  = (const float*)d_in[19];
  const float* W_g1  = (const float*)d_in[20];
  const float* b_g1  = (const float*)d_in[21];
  const float* W_g2  = (const float*)d_in[22];
  const float* b_g2  = (const float*)d_in[23];
  const float* ln_g  = (const float*)d_in[24];
  const float* ln_b  = (const float*)d_in[25];

  char* w = (char*)d_ws;
  auto alloc = [&](size_t bytes) -> char* {
    char* p = w;
    w += (bytes + 255) & ~(size_t)255;
    return p;
  };
  int* toff  = (int*)alloc((size_t)(NE + 1) * 4);
  int* noff  = (int*)alloc((size_t)(NN + 1) * 4);
  int* tcnt  = (int*)alloc((size_t)NE * 4);
  int* ncnt  = (int*)alloc((size_t)NN * 4);
  int* tslot = (int*)alloc((size_t)NT * 4);
  int* eslot = (int*)alloc((size_t)NE * 4);
  int* bsum  = (int*)alloc(1024 * 4);
  float* dir_s = (float*)alloc((size_t)NE * 3 * 4);
  u16* msg_s  = (u16*)alloc((size_t)NE * 128 * 2);      // 204.8 MB
  u16* tmsg_s = (u16*)alloc((size_t)NT * 64 * 2);       // 102.4 MB
  u16* erbf_bf = (u16*)alloc((size_t)NE * 64 * 2);      // 102.4 MB
  u16* s_bf    = (u16*)alloc((size_t)NN * 64 * 2);      // 6.4 MB
  u16* Wp_t1 = (u16*)alloc((size_t)5 * 4 * 512 * 2);
  u16* Wp_t2 = (u16*)alloc((size_t)2 * 4 * 512 * 2);
  u16* Wp_m1 = (u16*)alloc((size_t)8 * 4 * 512 * 2);
  u16* Wp_m2 = (u16*)alloc((size_t)2 * 8 * 512 * 2);
  u16* Wp_u1 = (u16*)alloc((size_t)6 * 4 * 512 * 2);    // Kp=192
  u16* Wp_u2 = (u16*)alloc((size_t)2 * 4 * 512 * 2);
  u16* Wp_g1 = (u16*)alloc((size_t)6 * 4 * 512 * 2);
  u16* Wp_g2 = (u16*)alloc((size_t)2 * 4 * 512 * 2);
  // afeat_bf aliases msg_s head: read only by ktrip, msg_s written later by kmsg
  u16* afeat_bf = msg_s;
  // aggv (f32) + aggs_bf alias tmsg_s (dead after kmsg): 38.4 + 6.4 = 44.8 <= 102.4 MB
  float* aggv = (float*)tmsg_s;
  u16* aggs_bf = tmsg_s + (size_t)NN * 384;  // after NN*192 floats

  hipMemsetAsync(tcnt, 0, (size_t)NE * 4, stream);
  hipMemsetAsync(ncnt, 0, (size_t)NN * 4, stream);

  kcvt<<<(NE * 16 + 255) / 256, 256, 0, stream>>>(erbf, erbf_bf, NE * 16);
  kcvt<<<(NN * 16 + 255) / 256, 256, 0, stream>>>(s, s_bf, NN * 16);
  kcvt<<<(NT * 4 + 255) / 256, 256, 0, stream>>>(afeat, afeat_bf, NT * 4);

  khist<<<(NT + 255) / 256, 256, 0, stream>>>(tji, NT, tcnt);
  khist<<<(NE + 255) / 256, 256, 0, stream>>>(eidx + NE, NE, ncnt);

  kscan1<<<(NE + 1023) / 1024, 256, 0, stream>>>(tcnt, NE, toff, bsum);
  kscan2<<<1, 1024, 0, stream>>>(bsum, (NE + 1023) / 1024);
  kscan3<<<(NE + 1 + 255) / 256, 256, 0, stream>>>(toff, bsum, NE, NT);
  kscatter_inv<<<(NT + 255) / 256, 256, 0, stream>>>(tji, toff, NT, tcnt, tslot);

  kscan1<<<(NN + 1023) / 1024, 256, 0, stream>>>(ncnt, NN, noff, bsum);
  kscan2<<<1, 1024, 0, stream>>>(bsum, (NN + 1023) / 1024);
  kscan3<<<(NN + 1 + 255) / 256, 256, 0, stream>>>(noff, bsum, NN, NE);
  kscatter_inv_dir<<<(NE + 255) / 256, 256, 0, stream>>>(eidx + NE, noff, NE, ncnt, eslot,
                                                         edir, dir_s);

  kprepw<<<5, 256, 0, stream>>>(W_t1, 144, 160, 64, Wp_t1);
  kprepw<<<2, 256, 0, stream>>>(W_t2, 64, 64, 64, Wp_t2);
  kprepw<<<8, 256, 0, stream>>>(W_m1, 256, 256, 64, Wp_m1);
  kprepw<<<4, 256, 0, stream>>>(W_m2, 64, 64, 128, Wp_m2);
  kprepw<<<6, 256, 0, stream>>>(W_u1, 192, 192, 64, Wp_u1);
  kprepw<<<2, 256, 0, stream>>>(W_u2, 64, 64, 64, Wp_u2);
  kprepw<<<6, 256, 0, stream>>>(W_g1, 192, 192, 64, Wp_g1);
  kprepw<<<2, 256, 0, stream>>>(W_g2, 64, 64, 64, Wp_g2);

  ktrip_mfma<<<NT / 64, 256, 0, stream>>>(tkj, tji, erbf_bf, afeat_bf, tslot,
                                          Wp_t1, b_t1, Wp_t2, b_t2, tmsg_s);
  kmsg_mfma<<<NE / 64, 256, 0, stream>>>(eidx, s_bf, erbf_bf, toff, tmsg_s, eslot,
                                         Wp_m1, b_m1, Wp_m2, b_m2, msg_s);
  kagg<<<(NN + 3) / 4, 256, 0, stream>>>(noff, msg_s, dir_s, aggs_bf, aggv);

  float* out_s = (float*)d_out;
  float* out_v = out_s + (size_t)NN * 64;
  knode_mfma<<<(NN + 63) / 64, 256, 0, stream>>>(s_bf, v, aggs_bf, aggv,
                                                 Wp_u1, b_u1, Wp_u2, b_u2,
                                                 Wp_g1, b_g1, Wp_g2, b_g2,
                                                 ln_g, ln_b, out_s, out_v);
}

// Round 8
// 726.710 us; speedup vs baseline: 5.3747x; 1.1982x over previous
//
#include <hip/hip_runtime.h>
#include <cstdint>
#include <cstddef>

#define NN 50000
#define NE 800000
#define NT 800000

typedef unsigned short u16;
typedef unsigned int u32;
typedef __attribute__((ext_vector_type(8))) short short8;
typedef __attribute__((ext_vector_type(4))) float f32x4;

__device__ __forceinline__ float silu_f(float x) { return x / (1.f + __expf(-x)); }
__device__ __forceinline__ float sigm_f(float x) { return 1.f / (1.f + __expf(-x)); }
__device__ __forceinline__ u16 f2b(float x) {
  u32 u = __float_as_uint(x);
  u32 r = u + 0x7fffu + ((u >> 16) & 1u);
  return (u16)(r >> 16);
}
__device__ __forceinline__ float b2f(u16 h) { return __uint_as_float(((u32)h) << 16); }

// XOR-swizzled LDS elem offset for row-major [*][RW] u16 tiles (16B-chunk ^ (r&7)).
template <int RW>
__device__ __forceinline__ int lx(int r, int c) {
  return r * RW + ((((c >> 3) ^ (r & 7)) << 3) | (c & 7));
}

// ---------------- bf16 pre-conversion (streaming)
__global__ __launch_bounds__(256) void kcvt(const float* __restrict__ in,
                                            u16* __restrict__ out, int n4) {
  int i = blockIdx.x * 256 + threadIdx.x;
  if (i >= n4) return;
  float4 v = ((const float4*)in)[i];
  uint2 p;
  p.x = (u32)f2b(v.x) | ((u32)f2b(v.y) << 16);
  p.y = (u32)f2b(v.z) | ((u32)f2b(v.w) << 16);
  ((uint2*)out)[i] = p;
}

// ---------------- CSR building
__global__ __launch_bounds__(256) void khist(const int* __restrict__ keys, int n,
                                             int* __restrict__ cnt) {
  int i = blockIdx.x * 256 + threadIdx.x;
  if (i < n) atomicAdd(&cnt[keys[i]], 1);
}

__global__ __launch_bounds__(256) void kscan1(const int* __restrict__ in, int n,
                                              int* __restrict__ out, int* __restrict__ bsum) {
  __shared__ int sh[256];
  int tid = threadIdx.x;
  size_t base = (size_t)blockIdx.x * 1024;
  int v[4];
  int acc = 0;
#pragma unroll
  for (int q = 0; q < 4; ++q) {
    size_t i = base + (size_t)tid * 4 + q;
    int x = (i < (size_t)n) ? in[i] : 0;
    v[q] = acc;
    acc += x;
  }
  sh[tid] = acc;
  __syncthreads();
  for (int off = 1; off < 256; off <<= 1) {
    int y = (tid >= off) ? sh[tid - off] : 0;
    __syncthreads();
    sh[tid] += y;
    __syncthreads();
  }
  int excl = (tid == 0) ? 0 : sh[tid - 1];
  if (tid == 255) bsum[blockIdx.x] = sh[255];
#pragma unroll
  for (int q = 0; q < 4; ++q) {
    size_t i = base + (size_t)tid * 4 + q;
    if (i < (size_t)n) out[i] = excl + v[q];
  }
}

__global__ __launch_bounds__(1024) void kscan2(int* __restrict__ bsum, int nb) {
  __shared__ int sh[1024];
  int tid = threadIdx.x;
  sh[tid] = (tid < nb) ? bsum[tid] : 0;
  __syncthreads();
  for (int off = 1; off < 1024; off <<= 1) {
    int y = (tid >= off) ? sh[tid - off] : 0;
    __syncthreads();
    sh[tid] += y;
    __syncthreads();
  }
  if (tid < nb) bsum[tid] = (tid == 0) ? 0 : sh[tid - 1];
}

__global__ __launch_bounds__(256) void kscan3(int* __restrict__ out, const int* __restrict__ bsum,
                                              int n, int total) {
  int i = blockIdx.x * 256 + threadIdx.x;
  if (i < n) out[i] += bsum[i >> 10];
  else if (i == n) out[n] = total;
}

__global__ __launch_bounds__(256) void kscatter_inv(const int* __restrict__ keys,
                                                    const int* __restrict__ off, int n,
                                                    int* __restrict__ cnt, int* __restrict__ inv) {
  int i = blockIdx.x * 256 + threadIdx.x;
  if (i < n) {
    int k = keys[i];
    int slot = off[k] + (atomicSub(&cnt[k], 1) - 1);
    inv[i] = slot;
  }
}

__global__ __launch_bounds__(256) void kscatter_inv_dir(const int* __restrict__ keys,
                                                        const int* __restrict__ off, int n,
                                                        int* __restrict__ cnt, int* __restrict__ inv,
                                                        const float* __restrict__ dir,
                                                        float* __restrict__ dir_s) {
  int i = blockIdx.x * 256 + threadIdx.x;
  if (i < n) {
    int k = keys[i];
    int slot = off[k] + (atomicSub(&cnt[k], 1) - 1);
    inv[i] = slot;
    dir_s[(size_t)slot * 3 + 0] = dir[(size_t)i * 3 + 0];
    dir_s[(size_t)slot * 3 + 1] = dir[(size_t)i * 3 + 1];
    dir_s[(size_t)slot * 3 + 2] = dir[(size_t)i * 3 + 2];
  }
}

// ---------------- Weight prep (proven)
__global__ __launch_bounds__(256) void kprepw(const float* __restrict__ W, int K, int Kp, int N,
                                              u16* __restrict__ out) {
  int tid = blockIdx.x * 256 + threadIdx.x;
  int total = (Kp / 32) * (N / 16) * 64;
  if (tid >= total) return;
  int l = tid & 63;
  int f = tid >> 6;
  int nt = f % (N / 16);
  int kt = f / (N / 16);
  int k0 = kt * 32 + (l >> 4) * 8;
  int n = nt * 16 + (l & 15);
  u16 vals[8];
#pragma unroll
  for (int j = 0; j < 8; ++j) {
    int kk = k0 + j;
    vals[j] = (kk < K) ? f2b(W[(size_t)kk * N + n]) : (u16)0;
  }
  uint4* dst = (uint4*)(out + (size_t)f * 512 + l * 8);
  uint4 p;
  p.x = (u32)vals[0] | ((u32)vals[1] << 16);
  p.y = (u32)vals[2] | ((u32)vals[3] << 16);
  p.z = (u32)vals[4] | ((u32)vals[5] << 16);
  p.w = (u32)vals[6] | ((u32)vals[7] << 16);
  *dst = p;
}

// ---------------- Kernel T (MFMA): triplet MLP -> tmsg_s[tslot[t]][64] bf16
// Staging now uint4-wide: 2x64 gathered erbf rows = 1024 chunk-tasks, 4/thread.
__global__ __launch_bounds__(256) void ktrip_mfma(
    const int* __restrict__ tkj, const int* __restrict__ tji,
    const u16* __restrict__ erbf_bf, const u16* __restrict__ afeat_bf,
    const int* __restrict__ tslot,
    const u16* __restrict__ Wp1, const float* __restrict__ b1,
    const u16* __restrict__ Wp2, const float* __restrict__ b2,
    u16* __restrict__ tmsg_s) {
  __shared__ u16 Xs[64 * 192];
  __shared__ u16 Hs[64 * 64];
  const int tid = threadIdx.x;
  const int l = tid & 63;
  const int w = tid >> 6;
  const int t0 = blockIdx.x * 64;

  // gathered erbf rows: idx in [0,1024): sel=idx>>9, r=(idx>>3)&63, chunk=idx&7
#pragma unroll
  for (int it = 0; it < 4; ++it) {
    int idx = it * 256 + tid;
    int sel = idx >> 9, r = (idx >> 3) & 63, ch = idx & 7;
    int t = t0 + r;
    int node = sel ? tji[t] : tkj[t];
    uint4 vv = *(const uint4*)&erbf_bf[(size_t)node * 64 + ch * 8];
    *(uint4*)&Xs[lx<192>(r, sel * 64 + ch * 8)] = vv;
  }
  {
    int r = tid >> 2, c = (tid & 3) * 4;
    uint2 p2 = *(const uint2*)&afeat_bf[(size_t)(t0 + r) * 16 + c];
    *(uint2*)&Xs[lx<192>(r, 128 + c)] = p2;
  }
#pragma unroll
  for (int i = 0; i < 2; ++i) {
    int idx = i * 256 + tid;
    int r = idx >> 3, c = 144 + (idx & 7) * 2;
    *(u32*)&Xs[lx<192>(r, c)] = 0;
  }
  __syncthreads();

  f32x4 acc1[4];
  {
    float bias = b1[w * 16 + (l & 15)];
#pragma unroll
    for (int mt = 0; mt < 4; ++mt) acc1[mt] = (f32x4){bias, bias, bias, bias};
    for (int ks = 0; ks < 5; ++ks) {
      short8 bf = *(const short8*)(Wp1 + ((size_t)(ks * 4 + w) * 64 + l) * 8);
#pragma unroll
      for (int mt = 0; mt < 4; ++mt) {
        short8 af = *(const short8*)&Xs[lx<192>(mt * 16 + (l & 15), ks * 32 + ((l >> 4) << 3))];
        acc1[mt] = __builtin_amdgcn_mfma_f32_16x16x32_bf16(af, bf, acc1[mt], 0, 0, 0);
      }
    }
  }
#pragma unroll
  for (int mt = 0; mt < 4; ++mt)
#pragma unroll
    for (int q = 0; q < 4; ++q) {
      int r = mt * 16 + (l >> 4) * 4 + q;
      Hs[lx<64>(r, w * 16 + (l & 15))] = f2b(silu_f(acc1[mt][q]));
    }
  __syncthreads();

  f32x4 acc2[4];
  {
    float bias = b2[w * 16 + (l & 15)];
#pragma unroll
    for (int mt = 0; mt < 4; ++mt) acc2[mt] = (f32x4){bias, bias, bias, bias};
    for (int ks = 0; ks < 2; ++ks) {
      short8 bf = *(const short8*)(Wp2 + ((size_t)(ks * 4 + w) * 64 + l) * 8);
#pragma unroll
      for (int mt = 0; mt < 4; ++mt) {
        short8 af = *(const short8*)&Hs[lx<64>(mt * 16 + (l & 15), ks * 32 + ((l >> 4) << 3))];
        acc2[mt] = __builtin_amdgcn_mfma_f32_16x16x32_bf16(af, bf, acc2[mt], 0, 0, 0);
      }
    }
  }
  __syncthreads();
#pragma unroll
  for (int mt = 0; mt < 4; ++mt)
#pragma unroll
    for (int q = 0; q < 4; ++q) {
      int r = mt * 16 + (l >> 4) * 4 + q;
      Xs[lx<64>(r, w * 16 + (l & 15))] = f2b(acc2[mt][q]);
    }
  __syncthreads();
  for (int i = 0; i < 2; ++i) {
    int idx = i * 256 + tid;
    int r = idx >> 3, c0 = (idx & 7) << 3;
    int slot = tslot[t0 + r];
    uint4 val = *(const uint4*)&Xs[lx<64>(r, c0)];
    *(uint4*)(tmsg_s + (size_t)slot * 64 + c0) = val;
  }
}

// ---------------- Kernel M (MFMA): edge MLP -> msg_s[eslot[e]][128] bf16
// Staging uint4-wide: s gathers 1024 chunk-tasks (4/thread); aagg sum per-lane uint4 chunks.
__global__ __launch_bounds__(256) void kmsg_mfma(
    const int* __restrict__ eidx, const u16* __restrict__ s_bf,
    const u16* __restrict__ erbf_bf,
    const int* __restrict__ toff, const u16* __restrict__ tmsg_s,
    const int* __restrict__ eslot,
    const u16* __restrict__ Wp1, const float* __restrict__ b1,
    const u16* __restrict__ Wp2, const float* __restrict__ b2,
    u16* __restrict__ msg_s) {
  __shared__ u16 Xs[64 * 256];
  __shared__ u16 Hs[64 * 64];
  const int tid = threadIdx.x;
  const int l = tid & 63;
  const int w = tid >> 6;
  const int e0 = blockIdx.x * 64;

  // erbf stream cols 128..191: 512 uint4, 2/thread
#pragma unroll
  for (int i = 0; i < 2; ++i) {
    int idx = i * 256 + tid;
    int r = idx >> 3, c0 = (idx & 7) << 3;
    uint4 vv = *(const uint4*)&erbf_bf[(size_t)(e0 + r) * 64 + c0];
    *(uint4*)&Xs[lx<256>(r, 128 + c0)] = vv;
  }
  // s[src], s[dst] gathers: idx in [0,1024): sel=idx>>9, r=(idx>>3)&63, chunk=idx&7
#pragma unroll
  for (int it = 0; it < 4; ++it) {
    int idx = it * 256 + tid;
    int sel = idx >> 9, r = (idx >> 3) & 63, ch = idx & 7;
    int node = eidx[sel * NE + e0 + r];
    uint4 vv = *(const uint4*)&s_bf[(size_t)node * 64 + ch * 8];
    *(uint4*)&Xs[lx<256>(r, sel * 64 + ch * 8)] = vv;
  }
  // aagg contiguous CSR sum: 512 lane-tasks (edge r, chunk ch), 2/thread
#pragma unroll
  for (int it = 0; it < 2; ++it) {
    int idx = it * 256 + tid;
    int r = idx >> 3, ch = idx & 7;
    int e = e0 + r;
    int r0 = toff[e], r1 = toff[e + 1];
    float a[8];
#pragma unroll
    for (int j = 0; j < 8; ++j) a[j] = 0.f;
    for (int ri = r0; ri < r1; ++ri) {
      uint4 pk = *(const uint4*)&tmsg_s[(size_t)ri * 64 + ch * 8];
      a[0] += b2f((u16)(pk.x & 0xffff)); a[1] += b2f((u16)(pk.x >> 16));
      a[2] += b2f((u16)(pk.y & 0xffff)); a[3] += b2f((u16)(pk.y >> 16));
      a[4] += b2f((u16)(pk.z & 0xffff)); a[5] += b2f((u16)(pk.z >> 16));
      a[6] += b2f((u16)(pk.w & 0xffff)); a[7] += b2f((u16)(pk.w >> 16));
    }
    uint4 p;
    p.x = (u32)f2b(a[0]) | ((u32)f2b(a[1]) << 16);
    p.y = (u32)f2b(a[2]) | ((u32)f2b(a[3]) << 16);
    p.z = (u32)f2b(a[4]) | ((u32)f2b(a[5]) << 16);
    p.w = (u32)f2b(a[6]) | ((u32)f2b(a[7]) << 16);
    *(uint4*)&Xs[lx<256>(r, 192 + ch * 8)] = p;
  }
  __syncthreads();

  f32x4 acc1[4];
  {
    float bias = b1[w * 16 + (l & 15)];
#pragma unroll
    for (int mt = 0; mt < 4; ++mt) acc1[mt] = (f32x4){bias, bias, bias, bias};
    for (int ks = 0; ks < 8; ++ks) {
      short8 bf = *(const short8*)(Wp1 + ((size_t)(ks * 4 + w) * 64 + l) * 8);
#pragma unroll
      for (int mt = 0; mt < 4; ++mt) {
        short8 af = *(const short8*)&Xs[lx<256>(mt * 16 + (l & 15), ks * 32 + ((l >> 4) << 3))];
        acc1[mt] = __builtin_amdgcn_mfma_f32_16x16x32_bf16(af, bf, acc1[mt], 0, 0, 0);
      }
    }
  }
#pragma unroll
  for (int mt = 0; mt < 4; ++mt)
#pragma unroll
    for (int q = 0; q < 4; ++q) {
      int r = mt * 16 + (l >> 4) * 4 + q;
      Hs[lx<64>(r, w * 16 + (l & 15))] = f2b(silu_f(acc1[mt][q]));
    }
  __syncthreads();

  f32x4 acc2[2][4];
#pragma unroll
  for (int pp = 0; pp < 2; ++pp) {
    int nt = w * 2 + pp;
    float bias = b2[nt * 16 + (l & 15)];
#pragma unroll
    for (int mt = 0; mt < 4; ++mt) acc2[pp][mt] = (f32x4){bias, bias, bias, bias};
    for (int ks = 0; ks < 2; ++ks) {
      short8 bf = *(const short8*)(Wp2 + ((size_t)(ks * 8 + nt) * 64 + l) * 8);
#pragma unroll
      for (int mt = 0; mt < 4; ++mt) {
        short8 af = *(const short8*)&Hs[lx<64>(mt * 16 + (l & 15), ks * 32 + ((l >> 4) << 3))];
        acc2[pp][mt] = __builtin_amdgcn_mfma_f32_16x16x32_bf16(af, bf, acc2[pp][mt], 0, 0, 0);
      }
    }
  }
  __syncthreads();
#pragma unroll
  for (int pp = 0; pp < 2; ++pp)
#pragma unroll
    for (int mt = 0; mt < 4; ++mt)
#pragma unroll
      for (int q = 0; q < 4; ++q) {
        int r = mt * 16 + (l >> 4) * 4 + q;
        Xs[lx<128>(r, (w * 2 + pp) * 16 + (l & 15))] = f2b(acc2[pp][mt][q]);
      }
  __syncthreads();
  for (int i = 0; i < 4; ++i) {
    int idx = i * 256 + tid;
    int r = idx >> 4, c0 = (idx & 15) << 3;
    int slot = eslot[e0 + r];
    uint4 val = *(const uint4*)&Xs[lx<128>(r, c0)];
    *(uint4*)(msg_s + (size_t)slot * 128 + c0) = val;
  }
}

// ---------------- Kernel A: streaming CSR reduction; one u32 per lane per row
__global__ __launch_bounds__(256) void kagg(
    const int* __restrict__ noff, const u16* __restrict__ msg_s,
    const float* __restrict__ dir_s,
    u16* __restrict__ aggs_bf, float* __restrict__ aggv) {
  const int lane = threadIdx.x & 63;
  const int wv = threadIdx.x >> 6;
  const int n = blockIdx.x * 4 + wv;
  if (n >= NN) return;
  const int r0 = noff[n], r1 = noff[n + 1];
  const int half = lane >> 5, m = lane & 31;
  float a0 = 0.f, a1 = 0.f;
  float v00 = 0.f, v01 = 0.f, v02 = 0.f, v10 = 0.f, v11 = 0.f, v12 = 0.f;
  for (int r = r0; r < r1; ++r) {
    u32 pk = *(const u32*)&msg_s[(size_t)r * 128 + lane * 2];
    float x0 = b2f((u16)(pk & 0xffff));
    float x1 = b2f((u16)(pk >> 16));
    if (half == 0) {
      a0 += x0; a1 += x1;
    } else {
      float dx = dir_s[(size_t)r * 3 + 0];
      float dy = dir_s[(size_t)r * 3 + 1];
      float dz = dir_s[(size_t)r * 3 + 2];
      v00 += x0 * dx; v01 += x0 * dy; v02 += x0 * dz;
      v10 += x1 * dx; v11 += x1 * dy; v12 += x1 * dz;
    }
  }
  if (half == 0) {
    *(u32*)&aggs_bf[(size_t)n * 64 + m * 2] = (u32)f2b(a0) | ((u32)f2b(a1) << 16);
  } else {
    float* av = aggv + (size_t)n * 192 + (size_t)(m * 2) * 3;
    av[0] = v00; av[1] = v01; av[2] = v02;
    av[3] = v10; av[4] = v11; av[5] = v12;
  }
}

// ---------------- Kernel N (MFMA, proven round 7)
__global__ __launch_bounds__(256) void knode_mfma(
    const u16* __restrict__ s_bf, const float* __restrict__ v,
    const u16* __restrict__ aggs_bf, const float* __restrict__ aggv,
    const u16* __restrict__ WpU1, const float* __restrict__ bU1,
    const u16* __restrict__ WpU2, const float* __restrict__ bU2,
    const u16* __restrict__ WpG1, const float* __restrict__ bG1,
    const u16* __restrict__ WpG2, const float* __restrict__ bG2,
    const float* __restrict__ lng, const float* __restrict__ lnb,
    float* __restrict__ outs, float* __restrict__ outv) {
  __shared__ __align__(16) char smem[64 * 192 * 2 + 2 * 64 * 64 * 2];  // 40KB
  u16* Xs = (u16*)smem;
  u16* Hu = (u16*)(smem + 64 * 192 * 2);
  u16* Hg = Hu + 64 * 64;
  float* Fs = (float*)smem;

  const int tid = threadIdx.x;
  const int l = tid & 63;
  const int w = tid >> 6;
  const int n0 = blockIdx.x * 64;

  for (int i = 0; i < 2; ++i) {
    int idx = i * 256 + tid;
    int r = idx >> 3, c0 = (idx & 7) << 3;
    int nr = n0 + r; if (nr >= NN) nr = NN - 1;
    uint4 a = *(const uint4*)&s_bf[(size_t)nr * 64 + c0];
    *(uint4*)&Xs[lx<192>(r, c0)] = a;
    uint4 b = *(const uint4*)&aggs_bf[(size_t)nr * 64 + c0];
    *(uint4*)&Xs[lx<192>(r, 64 + c0)] = b;
  }
  for (int it = 0; it < 16; ++it) {
    int idx = it * 256 + tid;
    int r = idx >> 6, c = idx & 63;
    int nr = n0 + r; if (nr >= NN) nr = NN - 1;
    const float* vp = v + (size_t)nr * 192 + c * 3;
    float x = vp[0], y = vp[1], z = vp[2];
    Xs[lx<192>(r, 128 + c)] = f2b(sqrtf(x * x + y * y + z * z));
  }
  __syncthreads();

  f32x4 au[4], ag[4];
  {
    float biu = bU1[w * 16 + (l & 15)], big = bG1[w * 16 + (l & 15)];
#pragma unroll
    for (int mt = 0; mt < 4; ++mt) {
      au[mt] = (f32x4){biu, biu, biu, biu};
      ag[mt] = (f32x4){big, big, big, big};
    }
    for (int ks = 0; ks < 6; ++ks) {
      short8 bu = *(const short8*)(WpU1 + ((size_t)(ks * 4 + w) * 64 + l) * 8);
      short8 bg = *(const short8*)(WpG1 + ((size_t)(ks * 4 + w) * 64 + l) * 8);
#pragma unroll
      for (int mt = 0; mt < 4; ++mt) {
        short8 af = *(const short8*)&Xs[lx<192>(mt * 16 + (l & 15), ks * 32 + ((l >> 4) << 3))];
        au[mt] = __builtin_amdgcn_mfma_f32_16x16x32_bf16(af, bu, au[mt], 0, 0, 0);
        ag[mt] = __builtin_amdgcn_mfma_f32_16x16x32_bf16(af, bg, ag[mt], 0, 0, 0);
      }
    }
  }
#pragma unroll
  for (int mt = 0; mt < 4; ++mt)
#pragma unroll
    for (int q = 0; q < 4; ++q) {
      int r = mt * 16 + (l >> 4) * 4 + q;
      Hu[lx<64>(r, w * 16 + (l & 15))] = f2b(silu_f(au[mt][q]));
      Hg[lx<64>(r, w * 16 + (l & 15))] = f2b(silu_f(ag[mt][q]));
    }
  __syncthreads();

  f32x4 ou[4], og[4];
  {
    float biu = bU2[w * 16 + (l & 15)], big = bG2[w * 16 + (l & 15)];
#pragma unroll
    for (int mt = 0; mt < 4; ++mt) {
      ou[mt] = (f32x4){biu, biu, biu, biu};
      og[mt] = (f32x4){big, big, big, big};
    }
    for (int ks = 0; ks < 2; ++ks) {
      short8 bu = *(const short8*)(WpU2 + ((size_t)(ks * 4 + w) * 64 + l) * 8);
      short8 bg = *(const short8*)(WpG2 + ((size_t)(ks * 4 + w) * 64 + l) * 8);
#pragma unroll
      for (int mt = 0; mt < 4; ++mt) {
        short8 afu = *(const short8*)&Hu[lx<64>(mt * 16 + (l & 15), ks * 32 + ((l >> 4) << 3))];
        ou[mt] = __builtin_amdgcn_mfma_f32_16x16x32_bf16(afu, bu, ou[mt], 0, 0, 0);
        short8 afg = *(const short8*)&Hg[lx<64>(mt * 16 + (l & 15), ks * 32 + ((l >> 4) << 3))];
        og[mt] = __builtin_amdgcn_mfma_f32_16x16x32_bf16(afg, bg, og[mt], 0, 0, 0);
      }
    }
  }
#pragma unroll
  for (int mt = 0; mt < 4; ++mt)
#pragma unroll
    for (int q = 0; q < 4; ++q) {
      int r = mt * 16 + (l >> 4) * 4 + q;
      ou[mt][q] += b2f(Xs[lx<192>(r, w * 16 + (l & 15))]);
    }
  __syncthreads();

#pragma unroll
  for (int mt = 0; mt < 4; ++mt)
#pragma unroll
    for (int q = 0; q < 4; ++q) {
      int r = mt * 16 + (l >> 4) * 4 + q;
      Fs[r * 68 + w * 16 + (l & 15)] = ou[mt][q];
    }
  __syncthreads();
  {
    int r = tid >> 2, c0 = (tid & 3) * 16;
    float xv[16];
#pragma unroll
    for (int j4 = 0; j4 < 4; ++j4) {
      float4 t = *(const float4*)&Fs[r * 68 + c0 + j4 * 4];
      xv[j4 * 4 + 0] = t.x; xv[j4 * 4 + 1] = t.y;
      xv[j4 * 4 + 2] = t.z; xv[j4 * 4 + 3] = t.w;
    }
    float sm = 0.f, sq = 0.f;
#pragma unroll
    for (int j = 0; j < 16; ++j) { sm += xv[j]; sq += xv[j] * xv[j]; }
    sm += __shfl_xor(sm, 1); sq += __shfl_xor(sq, 1);
    sm += __shfl_xor(sm, 2); sq += __shfl_xor(sq, 2);
    float mu = sm * (1.f / 64.f);
    float var = sq * (1.f / 64.f) - mu * mu;
    float rstd = rsqrtf(var + 1e-5f);
    if (n0 + r < NN) {
      float* op = outs + (size_t)(n0 + r) * 64 + c0;
#pragma unroll
      for (int j4 = 0; j4 < 4; ++j4) {
        float4 o;
        float y0 = (xv[j4 * 4 + 0] - mu) * rstd * lng[c0 + j4 * 4 + 0] + lnb[c0 + j4 * 4 + 0];
        float y1 = (xv[j4 * 4 + 1] - mu) * rstd * lng[c0 + j4 * 4 + 1] + lnb[c0 + j4 * 4 + 1];
        float y2 = (xv[j4 * 4 + 2] - mu) * rstd * lng[c0 + j4 * 4 + 2] + lnb[c0 + j4 * 4 + 2];
        float y3 = (xv[j4 * 4 + 3] - mu) * rstd * lng[c0 + j4 * 4 + 3] + lnb[c0 + j4 * 4 + 3];
        o.x = silu_f(y0); o.y = silu_f(y1); o.z = silu_f(y2); o.w = silu_f(y3);
        *(float4*)(op + j4 * 4) = o;
      }
    }
  }
  __syncthreads();

#pragma unroll
  for (int mt = 0; mt < 4; ++mt)
#pragma unroll
    for (int q = 0; q < 4; ++q) {
      int r = mt * 16 + (l >> 4) * 4 + q;
      Fs[r * 68 + w * 16 + (l & 15)] = og[mt][q];
    }
  __syncthreads();
  {
    int r = tid >> 2, c0 = (tid & 3) * 16;
    int nr = n0 + r;
    if (nr < NN) {
      float gate[16];
#pragma unroll
      for (int j = 0; j < 16; ++j) gate[j] = sigm_f(Fs[r * 68 + c0 + j]);
      const float4* vp = (const float4*)(v + (size_t)nr * 192 + c0 * 3);
      const float4* ap = (const float4*)(aggv + (size_t)nr * 192 + c0 * 3);
      float4* op = (float4*)(outv + (size_t)nr * 192 + c0 * 3);
#pragma unroll
      for (int j4 = 0; j4 < 12; ++j4) {
        float4 vv = vp[j4], av = ap[j4], o;
        o.x = vv.x + gate[(j4 * 4 + 0) / 3] * av.x;
        o.y = vv.y + gate[(j4 * 4 + 1) / 3] * av.y;
        o.z = vv.z + gate[(j4 * 4 + 2) / 3] * av.z;
        o.w = vv.w + gate[(j4 * 4 + 3) / 3] * av.w;
        op[j4] = o;
      }
    }
  }
}

extern "C" void kernel_launch(void* const* d_in, const int* in_sizes, int n_in,
                              void* d_out, int out_size, void* d_ws, size_t ws_size,
                              hipStream_t stream) {
  const float* s     = (const float*)d_in[0];
  const float* v     = (const float*)d_in[1];
  const int*   eidx  = (const int*)d_in[2];
  const float* erbf  = (const float*)d_in[3];
  const float* edir  = (const float*)d_in[4];
  const int*   tkj   = (const int*)d_in[5];
  const int*   tji   = (const int*)d_in[6];
  const float* afeat = (const float*)d_in[7];
  const float* W_t1  = (const float*)d_in[8];
  const float* b_t1  = (const float*)d_in[9];
  const float* W_t2  = (const float*)d_in[10];
  const float* b_t2  = (const float*)d_in[11];
  const float* W_m1  = (const float*)d_in[12];
  const float* b_m1  = (const float*)d_in[13];
  const float* W_m2  = (const float*)d_in[14];
  const float* b_m2  = (const float*)d_in[15];
  const float* W_u1  = (const float*)d_in[16];
  const float* b_u1  = (const float*)d_in[17];
  const float* W_u2  = (const float*)d_in[18];
  const float* b_u2  = (const float*)d_in[19];
  const float* W_g1  = (const float*)d_in[20];
  const float* b_g1  = (const float*)d_in[21];
  const float* W_g2  = (const float*)d_in[22];
  const float* b_g2  = (const float*)d_in[23];
  const float* ln_g  = (const float*)d_in[24];
  const float* ln_b  = (const float*)d_in[25];

  char* w = (char*)d_ws;
  auto alloc = [&](size_t bytes) -> char* {
    char* p = w;
    w += (bytes + 255) & ~(size_t)255;
    return p;
  };
  int* toff  = (int*)alloc((size_t)(NE + 1) * 4);
  int* noff  = (int*)alloc((size_t)(NN + 1) * 4);
  int* tcnt  = (int*)alloc((size_t)NE * 4);
  int* ncnt  = (int*)alloc((size_t)NN * 4);
  int* tslot = (int*)alloc((size_t)NT * 4);
  int* eslot = (int*)alloc((size_t)NE * 4);
  int* bsum  = (int*)alloc(1024 * 4);
  float* dir_s = (float*)alloc((size_t)NE * 3 * 4);
  u16* msg_s  = (u16*)alloc((size_t)NE * 128 * 2);
  u16* tmsg_s = (u16*)alloc((size_t)NT * 64 * 2);
  u16* erbf_bf = (u16*)alloc((size_t)NE * 64 * 2);
  u16* s_bf    = (u16*)alloc((size_t)NN * 64 * 2);
  u16* Wp_t1 = (u16*)alloc((size_t)5 * 4 * 512 * 2);
  u16* Wp_t2 = (u16*)alloc((size_t)2 * 4 * 512 * 2);
  u16* Wp_m1 = (u16*)alloc((size_t)8 * 4 * 512 * 2);
  u16* Wp_m2 = (u16*)alloc((size_t)2 * 8 * 512 * 2);
  u16* Wp_u1 = (u16*)alloc((size_t)6 * 4 * 512 * 2);
  u16* Wp_u2 = (u16*)alloc((size_t)2 * 4 * 512 * 2);
  u16* Wp_g1 = (u16*)alloc((size_t)6 * 4 * 512 * 2);
  u16* Wp_g2 = (u16*)alloc((size_t)2 * 4 * 512 * 2);
  u16* afeat_bf = msg_s;
  float* aggv = (float*)tmsg_s;
  u16* aggs_bf = tmsg_s + (size_t)NN * 384;

  hipMemsetAsync(tcnt, 0, (size_t)NE * 4, stream);
  hipMemsetAsync(ncnt, 0, (size_t)NN * 4, stream);

  kcvt<<<(NE * 16 + 255) / 256, 256, 0, stream>>>(erbf, erbf_bf, NE * 16);
  kcvt<<<(NN * 16 + 255) / 256, 256, 0, stream>>>(s, s_bf, NN * 16);
  kcvt<<<(NT * 4 + 255) / 256, 256, 0, stream>>>(afeat, afeat_bf, NT * 4);

  khist<<<(NT + 255) / 256, 256, 0, stream>>>(tji, NT, tcnt);
  khist<<<(NE + 255) / 256, 256, 0, stream>>>(eidx + NE, NE, ncnt);

  kscan1<<<(NE + 1023) / 1024, 256, 0, stream>>>(tcnt, NE, toff, bsum);
  kscan2<<<1, 1024, 0, stream>>>(bsum, (NE + 1023) / 1024);
  kscan3<<<(NE + 1 + 255) / 256, 256, 0, stream>>>(toff, bsum, NE, NT);
  kscatter_inv<<<(NT + 255) / 256, 256, 0, stream>>>(tji, toff, NT, tcnt, tslot);

  kscan1<<<(NN + 1023) / 1024, 256, 0, stream>>>(ncnt, NN, noff, bsum);
  kscan2<<<1, 1024, 0, stream>>>(bsum, (NN + 1023) / 1024);
  kscan3<<<(NN + 1 + 255) / 256, 256, 0, stream>>>(noff, bsum, NN, NE);
  kscatter_inv_dir<<<(NE + 255) / 256, 256, 0, stream>>>(eidx + NE, noff, NE, ncnt, eslot,
                                                         edir, dir_s);

  kprepw<<<5, 256, 0, stream>>>(W_t1, 144, 160, 64, Wp_t1);
  kprepw<<<2, 256, 0, stream>>>(W_t2, 64, 64, 64, Wp_t2);
  kprepw<<<8, 256, 0, stream>>>(W_m1, 256, 256, 64, Wp_m1);
  kprepw<<<4, 256, 0, stream>>>(W_m2, 64, 64, 128, Wp_m2);
  kprepw<<<6, 256, 0, stream>>>(W_u1, 192, 192, 64, Wp_u1);
  kprepw<<<2, 256, 0, stream>>>(W_u2, 64, 64, 64, Wp_u2);
  kprepw<<<6, 256, 0, stream>>>(W_g1, 192, 192, 64, Wp_g1);
  kprepw<<<2, 256, 0, stream>>>(W_g2, 64, 64, 64, Wp_g2);

  ktrip_mfma<<<NT / 64, 256, 0, stream>>>(tkj, tji, erbf_bf, afeat_bf, tslot,
                                          Wp_t1, b_t1, Wp_t2, b_t2, tmsg_s);
  kmsg_mfma<<<NE / 64, 256, 0, stream>>>(eidx, s_bf, erbf_bf, toff, tmsg_s, eslot,
                                         Wp_m1, b_m1, Wp_m2, b_m2, msg_s);
  kagg<<<(NN + 3) / 4, 256, 0, stream>>>(noff, msg_s, dir_s, aggs_bf, aggv);

  float* out_s = (float*)d_out;
  float* out_v = out_s + (size_t)NN * 64;
  knode_mfma<<<(NN + 63) / 64, 256, 0, stream>>>(s_bf, v, aggs_bf, aggv,
                                                 Wp_u1, b_u1, Wp_u2, b_u2,
                                                 Wp_g1, b_g1, Wp_g2, b_g2,
                                                 ln_g, ln_b, out_s, out_v);
}

// Round 9
// 684.881 us; speedup vs baseline: 5.7030x; 1.0611x over previous
//
#include <hip/hip_runtime.h>
#include <cstdint>
#include <cstddef>

#define NN 50000
#define NE 800000
#define NT 800000

typedef unsigned short u16;
typedef unsigned int u32;
typedef __attribute__((ext_vector_type(8))) short short8;
typedef __attribute__((ext_vector_type(4))) float f32x4;

__device__ __forceinline__ float silu_f(float x) { return x / (1.f + __expf(-x)); }
__device__ __forceinline__ float sigm_f(float x) { return 1.f / (1.f + __expf(-x)); }
__device__ __forceinline__ u16 f2b(float x) {
  u32 u = __float_as_uint(x);
  u32 r = u + 0x7fffu + ((u >> 16) & 1u);
  return (u16)(r >> 16);
}
__device__ __forceinline__ float b2f(u16 h) { return __uint_as_float(((u32)h) << 16); }

// XOR-swizzled LDS elem offset for row-major [*][RW] u16 tiles (16B-chunk ^ (r&7)).
template <int RW>
__device__ __forceinline__ int lx(int r, int c) {
  return r * RW + ((((c >> 3) ^ (r & 7)) << 3) | (c & 7));
}

// ---------------- bf16 pre-conversion (streaming)
__global__ __launch_bounds__(256) void kcvt(const float* __restrict__ in,
                                            u16* __restrict__ out, int n4) {
  int i = blockIdx.x * 256 + threadIdx.x;
  if (i >= n4) return;
  float4 v = ((const float4*)in)[i];
  uint2 p;
  p.x = (u32)f2b(v.x) | ((u32)f2b(v.y) << 16);
  p.y = (u32)f2b(v.z) | ((u32)f2b(v.w) << 16);
  ((uint2*)out)[i] = p;
}

// ---------------- CSR building
__global__ __launch_bounds__(256) void khist(const int* __restrict__ keys, int n,
                                             int* __restrict__ cnt) {
  int i = blockIdx.x * 256 + threadIdx.x;
  if (i < n) atomicAdd(&cnt[keys[i]], 1);
}

__global__ __launch_bounds__(256) void kscan1(const int* __restrict__ in, int n,
                                              int* __restrict__ out, int* __restrict__ bsum) {
  __shared__ int sh[256];
  int tid = threadIdx.x;
  size_t base = (size_t)blockIdx.x * 1024;
  int v[4];
  int acc = 0;
#pragma unroll
  for (int q = 0; q < 4; ++q) {
    size_t i = base + (size_t)tid * 4 + q;
    int x = (i < (size_t)n) ? in[i] : 0;
    v[q] = acc;
    acc += x;
  }
  sh[tid] = acc;
  __syncthreads();
  for (int off = 1; off < 256; off <<= 1) {
    int y = (tid >= off) ? sh[tid - off] : 0;
    __syncthreads();
    sh[tid] += y;
    __syncthreads();
  }
  int excl = (tid == 0) ? 0 : sh[tid - 1];
  if (tid == 255) bsum[blockIdx.x] = sh[255];
#pragma unroll
  for (int q = 0; q < 4; ++q) {
    size_t i = base + (size_t)tid * 4 + q;
    if (i < (size_t)n) out[i] = excl + v[q];
  }
}

__global__ __launch_bounds__(1024) void kscan2(int* __restrict__ bsum, int nb) {
  __shared__ int sh[1024];
  int tid = threadIdx.x;
  sh[tid] = (tid < nb) ? bsum[tid] : 0;
  __syncthreads();
  for (int off = 1; off < 1024; off <<= 1) {
    int y = (tid >= off) ? sh[tid - off] : 0;
    __syncthreads();
    sh[tid] += y;
    __syncthreads();
  }
  if (tid < nb) bsum[tid] = (tid == 0) ? 0 : sh[tid - 1];
}

__global__ __launch_bounds__(256) void kscan3(int* __restrict__ out, const int* __restrict__ bsum,
                                              int n, int total) {
  int i = blockIdx.x * 256 + threadIdx.x;
  if (i < n) out[i] += bsum[i >> 10];
  else if (i == n) out[n] = total;
}

// triplet scatter: tids[slot] = triplet id; also pre-sort afeat (f32->bf16) into slot order
__global__ __launch_bounds__(256) void kscatter_inv_afeat(
    const int* __restrict__ keys, const int* __restrict__ off, int n,
    int* __restrict__ cnt, int* __restrict__ tids,
    const float* __restrict__ afeat, u16* __restrict__ afeat_s) {
  int i = blockIdx.x * 256 + threadIdx.x;
  if (i < n) {
    int k = keys[i];
    int slot = off[k] + (atomicSub(&cnt[k], 1) - 1);
    tids[slot] = i;
    const float4* src = (const float4*)(afeat + (size_t)i * 16);
    uint2* dst = (uint2*)(afeat_s + (size_t)slot * 16);
#pragma unroll
    for (int q = 0; q < 4; ++q) {
      float4 v = src[q];
      uint2 p;
      p.x = (u32)f2b(v.x) | ((u32)f2b(v.y) << 16);
      p.y = (u32)f2b(v.z) | ((u32)f2b(v.w) << 16);
      dst[q] = p;
    }
  }
}

__global__ __launch_bounds__(256) void kscatter_inv_dir(const int* __restrict__ keys,
                                                        const int* __restrict__ off, int n,
                                                        int* __restrict__ cnt, int* __restrict__ inv,
                                                        const float* __restrict__ dir,
                                                        float* __restrict__ dir_s) {
  int i = blockIdx.x * 256 + threadIdx.x;
  if (i < n) {
    int k = keys[i];
    int slot = off[k] + (atomicSub(&cnt[k], 1) - 1);
    inv[i] = slot;
    dir_s[(size_t)slot * 3 + 0] = dir[(size_t)i * 3 + 0];
    dir_s[(size_t)slot * 3 + 1] = dir[(size_t)i * 3 + 1];
    dir_s[(size_t)slot * 3 + 2] = dir[(size_t)i * 3 + 2];
  }
}

// ---------------- Weight prep (proven)
__global__ __launch_bounds__(256) void kprepw(const float* __restrict__ W, int K, int Kp, int N,
                                              u16* __restrict__ out) {
  int tid = blockIdx.x * 256 + threadIdx.x;
  int total = (Kp / 32) * (N / 16) * 64;
  if (tid >= total) return;
  int l = tid & 63;
  int f = tid >> 6;
  int nt = f % (N / 16);
  int kt = f / (N / 16);
  int k0 = kt * 32 + (l >> 4) * 8;
  int n = nt * 16 + (l & 15);
  u16 vals[8];
#pragma unroll
  for (int j = 0; j < 8; ++j) {
    int kk = k0 + j;
    vals[j] = (kk < K) ? f2b(W[(size_t)kk * N + n]) : (u16)0;
  }
  uint4* dst = (uint4*)(out + (size_t)f * 512 + l * 8);
  uint4 p;
  p.x = (u32)vals[0] | ((u32)vals[1] << 16);
  p.y = (u32)vals[2] | ((u32)vals[3] << 16);
  p.z = (u32)vals[4] | ((u32)vals[5] << 16);
  p.w = (u32)vals[6] | ((u32)vals[7] << 16);
  *dst = p;
}

// ---------------- Kernel T (MFMA): triplet MLP in SLOT order -> tmsg_s contiguous
// Block handles slots st0..st0+63; t = tids[slot]; afeat pre-sorted; output streams.
__global__ __launch_bounds__(256) void ktrip_mfma(
    const int* __restrict__ tkj, const int* __restrict__ tji,
    const u16* __restrict__ erbf_bf, const u16* __restrict__ afeat_s,
    const int* __restrict__ tids,
    const u16* __restrict__ Wp1, const float* __restrict__ b1,
    const u16* __restrict__ Wp2, const float* __restrict__ b2,
    u16* __restrict__ tmsg_s) {
  __shared__ u16 Xs[64 * 192];
  __shared__ u16 Hs[64 * 64];
  const int tid = threadIdx.x;
  const int l = tid & 63;
  const int w = tid >> 6;
  const int st0 = blockIdx.x * 64;

  // gathered erbf rows: idx in [0,1024): sel=idx>>9, r=(idx>>3)&63, chunk=idx&7
#pragma unroll
  for (int it = 0; it < 4; ++it) {
    int idx = it * 256 + tid;
    int sel = idx >> 9, r = (idx >> 3) & 63, ch = idx & 7;
    int t = tids[st0 + r];
    int node = sel ? tji[t] : tkj[t];
    uint4 vv = *(const uint4*)&erbf_bf[(size_t)node * 64 + ch * 8];
    *(uint4*)&Xs[lx<192>(r, sel * 64 + ch * 8)] = vv;
  }
  {
    int r = tid >> 2, c = (tid & 3) * 4;
    uint2 p2 = *(const uint2*)&afeat_s[(size_t)(st0 + r) * 16 + c];
    *(uint2*)&Xs[lx<192>(r, 128 + c)] = p2;
  }
#pragma unroll
  for (int i = 0; i < 2; ++i) {
    int idx = i * 256 + tid;
    int r = idx >> 3, c = 144 + (idx & 7) * 2;
    *(u32*)&Xs[lx<192>(r, c)] = 0;
  }
  __syncthreads();

  f32x4 acc1[4];
  {
    float bias = b1[w * 16 + (l & 15)];
#pragma unroll
    for (int mt = 0; mt < 4; ++mt) acc1[mt] = (f32x4){bias, bias, bias, bias};
    for (int ks = 0; ks < 5; ++ks) {
      short8 bf = *(const short8*)(Wp1 + ((size_t)(ks * 4 + w) * 64 + l) * 8);
#pragma unroll
      for (int mt = 0; mt < 4; ++mt) {
        short8 af = *(const short8*)&Xs[lx<192>(mt * 16 + (l & 15), ks * 32 + ((l >> 4) << 3))];
        acc1[mt] = __builtin_amdgcn_mfma_f32_16x16x32_bf16(af, bf, acc1[mt], 0, 0, 0);
      }
    }
  }
#pragma unroll
  for (int mt = 0; mt < 4; ++mt)
#pragma unroll
    for (int q = 0; q < 4; ++q) {
      int r = mt * 16 + (l >> 4) * 4 + q;
      Hs[lx<64>(r, w * 16 + (l & 15))] = f2b(silu_f(acc1[mt][q]));
    }
  __syncthreads();

  f32x4 acc2[4];
  {
    float bias = b2[w * 16 + (l & 15)];
#pragma unroll
    for (int mt = 0; mt < 4; ++mt) acc2[mt] = (f32x4){bias, bias, bias, bias};
    for (int ks = 0; ks < 2; ++ks) {
      short8 bf = *(const short8*)(Wp2 + ((size_t)(ks * 4 + w) * 64 + l) * 8);
#pragma unroll
      for (int mt = 0; mt < 4; ++mt) {
        short8 af = *(const short8*)&Hs[lx<64>(mt * 16 + (l & 15), ks * 32 + ((l >> 4) << 3))];
        acc2[mt] = __builtin_amdgcn_mfma_f32_16x16x32_bf16(af, bf, acc2[mt], 0, 0, 0);
      }
    }
  }
  __syncthreads();
#pragma unroll
  for (int mt = 0; mt < 4; ++mt)
#pragma unroll
    for (int q = 0; q < 4; ++q) {
      int r = mt * 16 + (l >> 4) * 4 + q;
      Xs[lx<64>(r, w * 16 + (l & 15))] = f2b(acc2[mt][q]);
    }
  __syncthreads();
  // contiguous out copy: 512 uint4 streams
  for (int i = 0; i < 2; ++i) {
    int idx = i * 256 + tid;
    int r = idx >> 3, c0 = (idx & 7) << 3;
    uint4 val = *(const uint4*)&Xs[lx<64>(r, c0)];
    *(uint4*)(tmsg_s + (size_t)(st0 + r) * 64 + c0) = val;
  }
}

// ---------------- Kernel M (MFMA, proven round 8): edge MLP -> msg_s[eslot[e]][128] bf16
__global__ __launch_bounds__(256) void kmsg_mfma(
    const int* __restrict__ eidx, const u16* __restrict__ s_bf,
    const u16* __restrict__ erbf_bf,
    const int* __restrict__ toff, const u16* __restrict__ tmsg_s,
    const int* __restrict__ eslot,
    const u16* __restrict__ Wp1, const float* __restrict__ b1,
    const u16* __restrict__ Wp2, const float* __restrict__ b2,
    u16* __restrict__ msg_s) {
  __shared__ u16 Xs[64 * 256];
  __shared__ u16 Hs[64 * 64];
  const int tid = threadIdx.x;
  const int l = tid & 63;
  const int w = tid >> 6;
  const int e0 = blockIdx.x * 64;

#pragma unroll
  for (int i = 0; i < 2; ++i) {
    int idx = i * 256 + tid;
    int r = idx >> 3, c0 = (idx & 7) << 3;
    uint4 vv = *(const uint4*)&erbf_bf[(size_t)(e0 + r) * 64 + c0];
    *(uint4*)&Xs[lx<256>(r, 128 + c0)] = vv;
  }
#pragma unroll
  for (int it = 0; it < 4; ++it) {
    int idx = it * 256 + tid;
    int sel = idx >> 9, r = (idx >> 3) & 63, ch = idx & 7;
    int node = eidx[sel * NE + e0 + r];
    uint4 vv = *(const uint4*)&s_bf[(size_t)node * 64 + ch * 8];
    *(uint4*)&Xs[lx<256>(r, sel * 64 + ch * 8)] = vv;
  }
#pragma unroll
  for (int it = 0; it < 2; ++it) {
    int idx = it * 256 + tid;
    int r = idx >> 3, ch = idx & 7;
    int e = e0 + r;
    int r0 = toff[e], r1 = toff[e + 1];
    float a[8];
#pragma unroll
    for (int j = 0; j < 8; ++j) a[j] = 0.f;
    for (int ri = r0; ri < r1; ++ri) {
      uint4 pk = *(const uint4*)&tmsg_s[(size_t)ri * 64 + ch * 8];
      a[0] += b2f((u16)(pk.x & 0xffff)); a[1] += b2f((u16)(pk.x >> 16));
      a[2] += b2f((u16)(pk.y & 0xffff)); a[3] += b2f((u16)(pk.y >> 16));
      a[4] += b2f((u16)(pk.z & 0xffff)); a[5] += b2f((u16)(pk.z >> 16));
      a[6] += b2f((u16)(pk.w & 0xffff)); a[7] += b2f((u16)(pk.w >> 16));
    }
    uint4 p;
    p.x = (u32)f2b(a[0]) | ((u32)f2b(a[1]) << 16);
    p.y = (u32)f2b(a[2]) | ((u32)f2b(a[3]) << 16);
    p.z = (u32)f2b(a[4]) | ((u32)f2b(a[5]) << 16);
    p.w = (u32)f2b(a[6]) | ((u32)f2b(a[7]) << 16);
    *(uint4*)&Xs[lx<256>(r, 192 + ch * 8)] = p;
  }
  __syncthreads();

  f32x4 acc1[4];
  {
    float bias = b1[w * 16 + (l & 15)];
#pragma unroll
    for (int mt = 0; mt < 4; ++mt) acc1[mt] = (f32x4){bias, bias, bias, bias};
    for (int ks = 0; ks < 8; ++ks) {
      short8 bf = *(const short8*)(Wp1 + ((size_t)(ks * 4 + w) * 64 + l) * 8);
#pragma unroll
      for (int mt = 0; mt < 4; ++mt) {
        short8 af = *(const short8*)&Xs[lx<256>(mt * 16 + (l & 15), ks * 32 + ((l >> 4) << 3))];
        acc1[mt] = __builtin_amdgcn_mfma_f32_16x16x32_bf16(af, bf, acc1[mt], 0, 0, 0);
      }
    }
  }
#pragma unroll
  for (int mt = 0; mt < 4; ++mt)
#pragma unroll
    for (int q = 0; q < 4; ++q) {
      int r = mt * 16 + (l >> 4) * 4 + q;
      Hs[lx<64>(r, w * 16 + (l & 15))] = f2b(silu_f(acc1[mt][q]));
    }
  __syncthreads();

  f32x4 acc2[2][4];
#pragma unroll
  for (int pp = 0; pp < 2; ++pp) {
    int nt = w * 2 + pp;
    float bias = b2[nt * 16 + (l & 15)];
#pragma unroll
    for (int mt = 0; mt < 4; ++mt) acc2[pp][mt] = (f32x4){bias, bias, bias, bias};
    for (int ks = 0; ks < 2; ++ks) {
      short8 bf = *(const short8*)(Wp2 + ((size_t)(ks * 8 + nt) * 64 + l) * 8);
#pragma unroll
      for (int mt = 0; mt < 4; ++mt) {
        short8 af = *(const short8*)&Hs[lx<64>(mt * 16 + (l & 15), ks * 32 + ((l >> 4) << 3))];
        acc2[pp][mt] = __builtin_amdgcn_mfma_f32_16x16x32_bf16(af, bf, acc2[pp][mt], 0, 0, 0);
      }
    }
  }
  __syncthreads();
#pragma unroll
  for (int pp = 0; pp < 2; ++pp)
#pragma unroll
    for (int mt = 0; mt < 4; ++mt)
#pragma unroll
      for (int q = 0; q < 4; ++q) {
        int r = mt * 16 + (l >> 4) * 4 + q;
        Xs[lx<128>(r, (w * 2 + pp) * 16 + (l & 15))] = f2b(acc2[pp][mt][q]);
      }
  __syncthreads();
  for (int i = 0; i < 4; ++i) {
    int idx = i * 256 + tid;
    int r = idx >> 4, c0 = (idx & 15) << 3;
    int slot = eslot[e0 + r];
    uint4 val = *(const uint4*)&Xs[lx<128>(r, c0)];
    *(uint4*)(msg_s + (size_t)slot * 128 + c0) = val;
  }
}

// ---------------- Kernel A: streaming CSR reduction, 4 rows/iter, uint4 loads
// lane = lrow*16 + lcol: lrow = row phase (0..3), lcol = 16B chunk (0..15).
// lcol<8 -> m_s cols lcol*8..+7 ; lcol>=8 -> coeff cols (lcol-8)*8..+7 (x dir).
__global__ __launch_bounds__(256) void kagg(
    const int* __restrict__ noff, const u16* __restrict__ msg_s,
    const float* __restrict__ dir_s,
    u16* __restrict__ aggs_bf, float* __restrict__ aggv) {
  const int lane = threadIdx.x & 63;
  const int wv = threadIdx.x >> 6;
  const int n = blockIdx.x * 4 + wv;
  if (n >= NN) return;
  const int r0 = noff[n], r1 = noff[n + 1];
  const int lrow = lane >> 4, lcol = lane & 15;
  const bool is_ms = (lcol < 8);

  float a[8];
  float v0[8], v1[8], v2[8];
#pragma unroll
  for (int j = 0; j < 8; ++j) { a[j] = 0.f; v0[j] = 0.f; v1[j] = 0.f; v2[j] = 0.f; }

  for (int r4 = r0; r4 < r1; r4 += 4) {
    int r = r4 + lrow;
    if (r < r1) {
      uint4 pk = *(const uint4*)&msg_s[(size_t)r * 128 + lcol * 8];
      float x[8];
      x[0] = b2f((u16)(pk.x & 0xffff)); x[1] = b2f((u16)(pk.x >> 16));
      x[2] = b2f((u16)(pk.y & 0xffff)); x[3] = b2f((u16)(pk.y >> 16));
      x[4] = b2f((u16)(pk.z & 0xffff)); x[5] = b2f((u16)(pk.z >> 16));
      x[6] = b2f((u16)(pk.w & 0xffff)); x[7] = b2f((u16)(pk.w >> 16));
      if (is_ms) {
#pragma unroll
        for (int j = 0; j < 8; ++j) a[j] += x[j];
      } else {
        float dx = dir_s[(size_t)r * 3 + 0];
        float dy = dir_s[(size_t)r * 3 + 1];
        float dz = dir_s[(size_t)r * 3 + 2];
#pragma unroll
        for (int j = 0; j < 8; ++j) {
          v0[j] += x[j] * dx; v1[j] += x[j] * dy; v2[j] += x[j] * dz;
        }
      }
    }
  }
  // reduce across lrow phases (lanes differing in bits 4,5)
#pragma unroll
  for (int j = 0; j < 8; ++j) {
    a[j] += __shfl_xor(a[j], 16);  a[j] += __shfl_xor(a[j], 32);
    v0[j] += __shfl_xor(v0[j], 16); v0[j] += __shfl_xor(v0[j], 32);
    v1[j] += __shfl_xor(v1[j], 16); v1[j] += __shfl_xor(v1[j], 32);
    v2[j] += __shfl_xor(v2[j], 16); v2[j] += __shfl_xor(v2[j], 32);
  }
  if (lrow == 0) {
    if (is_ms) {
      uint4 p;
      p.x = (u32)f2b(a[0]) | ((u32)f2b(a[1]) << 16);
      p.y = (u32)f2b(a[2]) | ((u32)f2b(a[3]) << 16);
      p.z = (u32)f2b(a[4]) | ((u32)f2b(a[5]) << 16);
      p.w = (u32)f2b(a[6]) | ((u32)f2b(a[7]) << 16);
      *(uint4*)&aggs_bf[(size_t)n * 64 + lcol * 8] = p;
    } else {
      int c0 = (lcol - 8) * 8;
      float* av = aggv + (size_t)n * 192 + (size_t)c0 * 3;  // 24 contiguous floats
      float4 o0 = {v0[0], v1[0], v2[0], v0[1]};
      float4 o1 = {v1[1], v2[1], v0[2], v1[2]};
      float4 o2 = {v2[2], v0[3], v1[3], v2[3]};
      float4 o3 = {v0[4], v1[4], v2[4], v0[5]};
      float4 o4 = {v1[5], v2[5], v0[6], v1[6]};
      float4 o5 = {v2[6], v0[7], v1[7], v2[7]};
      float4* av4 = (float4*)av;
      av4[0] = o0; av4[1] = o1; av4[2] = o2; av4[3] = o3; av4[4] = o4; av4[5] = o5;
    }
  }
}

// ---------------- Kernel N (MFMA, proven round 7)
__global__ __launch_bounds__(256) void knode_mfma(
    const u16* __restrict__ s_bf, const float* __restrict__ v,
    const u16* __restrict__ aggs_bf, const float* __restrict__ aggv,
    const u16* __restrict__ WpU1, const float* __restrict__ bU1,
    const u16* __restrict__ WpU2, const float* __restrict__ bU2,
    const u16* __restrict__ WpG1, const float* __restrict__ bG1,
    const u16* __restrict__ WpG2, const float* __restrict__ bG2,
    const float* __restrict__ lng, const float* __restrict__ lnb,
    float* __restrict__ outs, float* __restrict__ outv) {
  __shared__ __align__(16) char smem[64 * 192 * 2 + 2 * 64 * 64 * 2];  // 40KB
  u16* Xs = (u16*)smem;
  u16* Hu = (u16*)(smem + 64 * 192 * 2);
  u16* Hg = Hu + 64 * 64;
  float* Fs = (float*)smem;

  const int tid = threadIdx.x;
  const int l = tid & 63;
  const int w = tid >> 6;
  const int n0 = blockIdx.x * 64;

  for (int i = 0; i < 2; ++i) {
    int idx = i * 256 + tid;
    int r = idx >> 3, c0 = (idx & 7) << 3;
    int nr = n0 + r; if (nr >= NN) nr = NN - 1;
    uint4 a = *(const uint4*)&s_bf[(size_t)nr * 64 + c0];
    *(uint4*)&Xs[lx<192>(r, c0)] = a;
    uint4 b = *(const uint4*)&aggs_bf[(size_t)nr * 64 + c0];
    *(uint4*)&Xs[lx<192>(r, 64 + c0)] = b;
  }
  for (int it = 0; it < 16; ++it) {
    int idx = it * 256 + tid;
    int r = idx >> 6, c = idx & 63;
    int nr = n0 + r; if (nr >= NN) nr = NN - 1;
    const float* vp = v + (size_t)nr * 192 + c * 3;
    float x = vp[0], y = vp[1], z = vp[2];
    Xs[lx<192>(r, 128 + c)] = f2b(sqrtf(x * x + y * y + z * z));
  }
  __syncthreads();

  f32x4 au[4], ag[4];
  {
    float biu = bU1[w * 16 + (l & 15)], big = bG1[w * 16 + (l & 15)];
#pragma unroll
    for (int mt = 0; mt < 4; ++mt) {
      au[mt] = (f32x4){biu, biu, biu, biu};
      ag[mt] = (f32x4){big, big, big, big};
    }
    for (int ks = 0; ks < 6; ++ks) {
      short8 bu = *(const short8*)(WpU1 + ((size_t)(ks * 4 + w) * 64 + l) * 8);
      short8 bg = *(const short8*)(WpG1 + ((size_t)(ks * 4 + w) * 64 + l) * 8);
#pragma unroll
      for (int mt = 0; mt < 4; ++mt) {
        short8 af = *(const short8*)&Xs[lx<192>(mt * 16 + (l & 15), ks * 32 + ((l >> 4) << 3))];
        au[mt] = __builtin_amdgcn_mfma_f32_16x16x32_bf16(af, bu, au[mt], 0, 0, 0);
        ag[mt] = __builtin_amdgcn_mfma_f32_16x16x32_bf16(af, bg, ag[mt], 0, 0, 0);
      }
    }
  }
#pragma unroll
  for (int mt = 0; mt < 4; ++mt)
#pragma unroll
    for (int q = 0; q < 4; ++q) {
      int r = mt * 16 + (l >> 4) * 4 + q;
      Hu[lx<64>(r, w * 16 + (l & 15))] = f2b(silu_f(au[mt][q]));
      Hg[lx<64>(r, w * 16 + (l & 15))] = f2b(silu_f(ag[mt][q]));
    }
  __syncthreads();

  f32x4 ou[4], og[4];
  {
    float biu = bU2[w * 16 + (l & 15)], big = bG2[w * 16 + (l & 15)];
#pragma unroll
    for (int mt = 0; mt < 4; ++mt) {
      ou[mt] = (f32x4){biu, biu, biu, biu};
      og[mt] = (f32x4){big, big, big, big};
    }
    for (int ks = 0; ks < 2; ++ks) {
      short8 bu = *(const short8*)(WpU2 + ((size_t)(ks * 4 + w) * 64 + l) * 8);
      short8 bg = *(const short8*)(WpG2 + ((size_t)(ks * 4 + w) * 64 + l) * 8);
#pragma unroll
      for (int mt = 0; mt < 4; ++mt) {
        short8 afu = *(const short8*)&Hu[lx<64>(mt * 16 + (l & 15), ks * 32 + ((l >> 4) << 3))];
        ou[mt] = __builtin_amdgcn_mfma_f32_16x16x32_bf16(afu, bu, ou[mt], 0, 0, 0);
        short8 afg = *(const short8*)&Hg[lx<64>(mt * 16 + (l & 15), ks * 32 + ((l >> 4) << 3))];
        og[mt] = __builtin_amdgcn_mfma_f32_16x16x32_bf16(afg, bg, og[mt], 0, 0, 0);
      }
    }
  }
#pragma unroll
  for (int mt = 0; mt < 4; ++mt)
#pragma unroll
    for (int q = 0; q < 4; ++q) {
      int r = mt * 16 + (l >> 4) * 4 + q;
      ou[mt][q] += b2f(Xs[lx<192>(r, w * 16 + (l & 15))]);
    }
  __syncthreads();

#pragma unroll
  for (int mt = 0; mt < 4; ++mt)
#pragma unroll
    for (int q = 0; q < 4; ++q) {
      int r = mt * 16 + (l >> 4) * 4 + q;
      Fs[r * 68 + w * 16 + (l & 15)] = ou[mt][q];
    }
  __syncthreads();
  {
    int r = tid >> 2, c0 = (tid & 3) * 16;
    float xv[16];
#pragma unroll
    for (int j4 = 0; j4 < 4; ++j4) {
      float4 t = *(const float4*)&Fs[r * 68 + c0 + j4 * 4];
      xv[j4 * 4 + 0] = t.x; xv[j4 * 4 + 1] = t.y;
      xv[j4 * 4 + 2] = t.z; xv[j4 * 4 + 3] = t.w;
    }
    float sm = 0.f, sq = 0.f;
#pragma unroll
    for (int j = 0; j < 16; ++j) { sm += xv[j]; sq += xv[j] * xv[j]; }
    sm += __shfl_xor(sm, 1); sq += __shfl_xor(sq, 1);
    sm += __shfl_xor(sm, 2); sq += __shfl_xor(sq, 2);
    float mu = sm * (1.f / 64.f);
    float var = sq * (1.f / 64.f) - mu * mu;
    float rstd = rsqrtf(var + 1e-5f);
    if (n0 + r < NN) {
      float* op = outs + (size_t)(n0 + r) * 64 + c0;
#pragma unroll
      for (int j4 = 0; j4 < 4; ++j4) {
        float4 o;
        float y0 = (xv[j4 * 4 + 0] - mu) * rstd * lng[c0 + j4 * 4 + 0] + lnb[c0 + j4 * 4 + 0];
        float y1 = (xv[j4 * 4 + 1] - mu) * rstd * lng[c0 + j4 * 4 + 1] + lnb[c0 + j4 * 4 + 1];
        float y2 = (xv[j4 * 4 + 2] - mu) * rstd * lng[c0 + j4 * 4 + 2] + lnb[c0 + j4 * 4 + 2];
        float y3 = (xv[j4 * 4 + 3] - mu) * rstd * lng[c0 + j4 * 4 + 3] + lnb[c0 + j4 * 4 + 3];
        o.x = silu_f(y0); o.y = silu_f(y1); o.z = silu_f(y2); o.w = silu_f(y3);
        *(float4*)(op + j4 * 4) = o;
      }
    }
  }
  __syncthreads();

#pragma unroll
  for (int mt = 0; mt < 4; ++mt)
#pragma unroll
    for (int q = 0; q < 4; ++q) {
      int r = mt * 16 + (l >> 4) * 4 + q;
      Fs[r * 68 + w * 16 + (l & 15)] = og[mt][q];
    }
  __syncthreads();
  {
    int r = tid >> 2, c0 = (tid & 3) * 16;
    int nr = n0 + r;
    if (nr < NN) {
      float gate[16];
#pragma unroll
      for (int j = 0; j < 16; ++j) gate[j] = sigm_f(Fs[r * 68 + c0 + j]);
      const float4* vp = (const float4*)(v + (size_t)nr * 192 + c0 * 3);
      const float4* ap = (const float4*)(aggv + (size_t)nr * 192 + c0 * 3);
      float4* op = (float4*)(outv + (size_t)nr * 192 + c0 * 3);
#pragma unroll
      for (int j4 = 0; j4 < 12; ++j4) {
        float4 vv = vp[j4], av = ap[j4], o;
        o.x = vv.x + gate[(j4 * 4 + 0) / 3] * av.x;
        o.y = vv.y + gate[(j4 * 4 + 1) / 3] * av.y;
        o.z = vv.z + gate[(j4 * 4 + 2) / 3] * av.z;
        o.w = vv.w + gate[(j4 * 4 + 3) / 3] * av.w;
        op[j4] = o;
      }
    }
  }
}

extern "C" void kernel_launch(void* const* d_in, const int* in_sizes, int n_in,
                              void* d_out, int out_size, void* d_ws, size_t ws_size,
                              hipStream_t stream) {
  const float* s     = (const float*)d_in[0];
  const float* v     = (const float*)d_in[1];
  const int*   eidx  = (const int*)d_in[2];
  const float* erbf  = (const float*)d_in[3];
  const float* edir  = (const float*)d_in[4];
  const int*   tkj   = (const int*)d_in[5];
  const int*   tji   = (const int*)d_in[6];
  const float* afeat = (const float*)d_in[7];
  const float* W_t1  = (const float*)d_in[8];
  const float* b_t1  = (const float*)d_in[9];
  const float* W_t2  = (const float*)d_in[10];
  const float* b_t2  = (const float*)d_in[11];
  const float* W_m1  = (const float*)d_in[12];
  const float* b_m1  = (const float*)d_in[13];
  const float* W_m2  = (const float*)d_in[14];
  const float* b_m2  = (const float*)d_in[15];
  const float* W_u1  = (const float*)d_in[16];
  const float* b_u1  = (const float*)d_in[17];
  const float* W_u2  = (const float*)d_in[18];
  const float* b_u2  = (const float*)d_in[19];
  const float* W_g1  = (const float*)d_in[20];
  const float* b_g1  = (const float*)d_in[21];
  const float* W_g2  = (const float*)d_in[22];
  const float* b_g2  = (const float*)d_in[23];
  const float* ln_g  = (const float*)d_in[24];
  const float* ln_b  = (const float*)d_in[25];

  char* w = (char*)d_ws;
  auto alloc = [&](size_t bytes) -> char* {
    char* p = w;
    w += (bytes + 255) & ~(size_t)255;
    return p;
  };
  int* toff  = (int*)alloc((size_t)(NE + 1) * 4);
  int* noff  = (int*)alloc((size_t)(NN + 1) * 4);
  int* tcnt  = (int*)alloc((size_t)NE * 4);
  int* ncnt  = (int*)alloc((size_t)NN * 4);
  int* tids  = (int*)alloc((size_t)NT * 4);
  int* eslot = (int*)alloc((size_t)NE * 4);
  int* bsum  = (int*)alloc(1024 * 4);
  float* dir_s = (float*)alloc((size_t)NE * 3 * 4);
  u16* msg_s  = (u16*)alloc((size_t)NE * 128 * 2);
  u16* tmsg_s = (u16*)alloc((size_t)NT * 64 * 2);
  u16* erbf_bf = (u16*)alloc((size_t)NE * 64 * 2);
  u16* s_bf    = (u16*)alloc((size_t)NN * 64 * 2);
  u16* Wp_t1 = (u16*)alloc((size_t)5 * 4 * 512 * 2);
  u16* Wp_t2 = (u16*)alloc((size_t)2 * 4 * 512 * 2);
  u16* Wp_m1 = (u16*)alloc((size_t)8 * 4 * 512 * 2);
  u16* Wp_m2 = (u16*)alloc((size_t)2 * 8 * 512 * 2);
  u16* Wp_u1 = (u16*)alloc((size_t)6 * 4 * 512 * 2);
  u16* Wp_u2 = (u16*)alloc((size_t)2 * 4 * 512 * 2);
  u16* Wp_g1 = (u16*)alloc((size_t)6 * 4 * 512 * 2);
  u16* Wp_g2 = (u16*)alloc((size_t)2 * 4 * 512 * 2);
  // afeat_s (slot-sorted bf16) aliases msg_s head: read only by ktrip, msg_s written later
  u16* afeat_s = msg_s;
  float* aggv = (float*)tmsg_s;
  u16* aggs_bf = tmsg_s + (size_t)NN * 384;

  hipMemsetAsync(tcnt, 0, (size_t)NE * 4, stream);
  hipMemsetAsync(ncnt, 0, (size_t)NN * 4, stream);

  kcvt<<<(NE * 16 + 255) / 256, 256, 0, stream>>>(erbf, erbf_bf, NE * 16);
  kcvt<<<(NN * 16 + 255) / 256, 256, 0, stream>>>(s, s_bf, NN * 16);

  khist<<<(NT + 255) / 256, 256, 0, stream>>>(tji, NT, tcnt);
  khist<<<(NE + 255) / 256, 256, 0, stream>>>(eidx + NE, NE, ncnt);

  kscan1<<<(NE + 1023) / 1024, 256, 0, stream>>>(tcnt, NE, toff, bsum);
  kscan2<<<1, 1024, 0, stream>>>(bsum, (NE + 1023) / 1024);
  kscan3<<<(NE + 1 + 255) / 256, 256, 0, stream>>>(toff, bsum, NE, NT);
  kscatter_inv_afeat<<<(NT + 255) / 256, 256, 0, stream>>>(tji, toff, NT, tcnt, tids,
                                                           afeat, afeat_s);

  kscan1<<<(NN + 1023) / 1024, 256, 0, stream>>>(ncnt, NN, noff, bsum);
  kscan2<<<1, 1024, 0, stream>>>(bsum, (NN + 1023) / 1024);
  kscan3<<<(NN + 1 + 255) / 256, 256, 0, stream>>>(noff, bsum, NN, NE);
  kscatter_inv_dir<<<(NE + 255) / 256, 256, 0, stream>>>(eidx + NE, noff, NE, ncnt, eslot,
                                                         edir, dir_s);

  kprepw<<<5, 256, 0, stream>>>(W_t1, 144, 160, 64, Wp_t1);
  kprepw<<<2, 256, 0, stream>>>(W_t2, 64, 64, 64, Wp_t2);
  kprepw<<<8, 256, 0, stream>>>(W_m1, 256, 256, 64, Wp_m1);
  kprepw<<<4, 256, 0, stream>>>(W_m2, 64, 64, 128, Wp_m2);
  kprepw<<<6, 256, 0, stream>>>(W_u1, 192, 192, 64, Wp_u1);
  kprepw<<<2, 256, 0, stream>>>(W_u2, 64, 64, 64, Wp_u2);
  kprepw<<<6, 256, 0, stream>>>(W_g1, 192, 192, 64, Wp_g1);
  kprepw<<<2, 256, 0, stream>>>(W_g2, 64, 64, 64, Wp_g2);

  ktrip_mfma<<<NT / 64, 256, 0, stream>>>(tkj, tji, erbf_bf, afeat_s, tids,
                                          Wp_t1, b_t1, Wp_t2, b_t2, tmsg_s);
  kmsg_mfma<<<NE / 64, 256, 0, stream>>>(eidx, s_bf, erbf_bf, toff, tmsg_s, eslot,
                                         Wp_m1, b_m1, Wp_m2, b_m2, msg_s);
  kagg<<<(NN + 3) / 4, 256, 0, stream>>>(noff, msg_s, dir_s, aggs_bf, aggv);

  float* out_s = (float*)d_out;
  float* out_v = out_s + (size_t)NN * 64;
  knode_mfma<<<(NN + 63) / 64, 256, 0, stream>>>(s_bf, v, aggs_bf, aggv,
                                                 Wp_u1, b_u1, Wp_u2, b_u2,
                                                 Wp_g1, b_g1, Wp_g2, b_g2,
                                                 ln_g, ln_b, out_s, out_v);
}

// Round 10
// 643.539 us; speedup vs baseline: 6.0694x; 1.0642x over previous
//
#include <hip/hip_runtime.h>
#include <cstdint>
#include <cstddef>

#define NN 50000
#define NE 800000
#define NT 800000

typedef unsigned short u16;
typedef unsigned int u32;
typedef __attribute__((ext_vector_type(8))) short short8;
typedef __attribute__((ext_vector_type(4))) float f32x4;

__device__ __forceinline__ float silu_f(float x) { return x / (1.f + __expf(-x)); }
__device__ __forceinline__ float sigm_f(float x) { return 1.f / (1.f + __expf(-x)); }
__device__ __forceinline__ u16 f2b(float x) {
  u32 u = __float_as_uint(x);
  u32 r = u + 0x7fffu + ((u >> 16) & 1u);
  return (u16)(r >> 16);
}
__device__ __forceinline__ float b2f(u16 h) { return __uint_as_float(((u32)h) << 16); }

// XOR-swizzled LDS elem offset for row-major [*][RW] u16 tiles (16B-chunk ^ (r&7)).
template <int RW>
__device__ __forceinline__ int lx(int r, int c) {
  return r * RW + ((((c >> 3) ^ (r & 7)) << 3) | (c & 7));
}

// ---------------- combined bf16 pre-conversion: erbf (NE*16 float4) then s (NN*16 float4)
__global__ __launch_bounds__(256) void kcvt2(const float* __restrict__ erbf,
                                             u16* __restrict__ erbf_bf,
                                             const float* __restrict__ s,
                                             u16* __restrict__ s_bf) {
  int i = blockIdx.x * 256 + threadIdx.x;
  const float* in;
  u16* out;
  int j;
  if (i < NE * 16) { in = erbf; out = erbf_bf; j = i; }
  else { j = i - NE * 16; if (j >= NN * 16) return; in = s; out = s_bf; }
  float4 v = ((const float4*)in)[j];
  uint2 p;
  p.x = (u32)f2b(v.x) | ((u32)f2b(v.y) << 16);
  p.y = (u32)f2b(v.z) | ((u32)f2b(v.w) << 16);
  ((uint2*)out)[j] = p;
}

// ---------------- combined histogram: tji -> tcnt, then edge-dst -> ncnt
__global__ __launch_bounds__(256) void khist2(const int* __restrict__ tji,
                                              const int* __restrict__ edst,
                                              int* __restrict__ tcnt,
                                              int* __restrict__ ncnt) {
  int i = blockIdx.x * 256 + threadIdx.x;
  if (i < NT) atomicAdd(&tcnt[tji[i]], 1);
  else {
    int j = i - NT;
    if (j < NE) atomicAdd(&ncnt[edst[j]], 1);
  }
}

// ---------------- combined 2-range scans
__global__ __launch_bounds__(256) void kscan1b(
    const int* __restrict__ inA, int nA, int* __restrict__ outA, int* __restrict__ bsA, int BA,
    const int* __restrict__ inB, int nB, int* __restrict__ outB, int* __restrict__ bsB) {
  __shared__ int sh[256];
  const int* in; int n; int* out; int* bs; int blk;
  if ((int)blockIdx.x < BA) { in = inA; n = nA; out = outA; bs = bsA; blk = blockIdx.x; }
  else { in = inB; n = nB; out = outB; bs = bsB; blk = blockIdx.x - BA; }
  int tid = threadIdx.x;
  size_t base = (size_t)blk * 1024;
  int v[4];
  int acc = 0;
#pragma unroll
  for (int q = 0; q < 4; ++q) {
    size_t i = base + (size_t)tid * 4 + q;
    int x = (i < (size_t)n) ? in[i] : 0;
    v[q] = acc;
    acc += x;
  }
  sh[tid] = acc;
  __syncthreads();
  for (int off = 1; off < 256; off <<= 1) {
    int y = (tid >= off) ? sh[tid - off] : 0;
    __syncthreads();
    sh[tid] += y;
    __syncthreads();
  }
  int excl = (tid == 0) ? 0 : sh[tid - 1];
  if (tid == 255) bs[blk] = sh[255];
#pragma unroll
  for (int q = 0; q < 4; ++q) {
    size_t i = base + (size_t)tid * 4 + q;
    if (i < (size_t)n) out[i] = excl + v[q];
  }
}

__global__ __launch_bounds__(1024) void kscan2b(int* __restrict__ bsA, int nbA,
                                                int* __restrict__ bsB, int nbB) {
  __shared__ int sh[1024];
  int* bs = (blockIdx.x == 0) ? bsA : bsB;
  int nb = (blockIdx.x == 0) ? nbA : nbB;
  int tid = threadIdx.x;
  sh[tid] = (tid < nb) ? bs[tid] : 0;
  __syncthreads();
  for (int off = 1; off < 1024; off <<= 1) {
    int y = (tid >= off) ? sh[tid - off] : 0;
    __syncthreads();
    sh[tid] += y;
    __syncthreads();
  }
  if (tid < nb) bs[tid] = (tid == 0) ? 0 : sh[tid - 1];
}

__global__ __launch_bounds__(256) void kscan3b(
    int* __restrict__ outA, const int* __restrict__ bsA, int nA, int totalA,
    int* __restrict__ outB, const int* __restrict__ bsB, int nB, int totalB) {
  int i = blockIdx.x * 256 + threadIdx.x;
  if (i <= nA) {
    if (i < nA) outA[i] += bsA[i >> 10];
    else outA[nA] = totalA;
  } else {
    int j = i - (nA + 1);
    if (j < nB) outB[j] += bsB[j >> 10];
    else if (j == nB) outB[nB] = totalB;
  }
}

// triplet scatter: tids[slot] = triplet id; pre-sort afeat (f32->bf16) into slot order
__global__ __launch_bounds__(256) void kscatter_inv_afeat(
    const int* __restrict__ keys, const int* __restrict__ off, int n,
    int* __restrict__ cnt, int* __restrict__ tids,
    const float* __restrict__ afeat, u16* __restrict__ afeat_s) {
  int i = blockIdx.x * 256 + threadIdx.x;
  if (i < n) {
    int k = keys[i];
    int slot = off[k] + (atomicSub(&cnt[k], 1) - 1);
    tids[slot] = i;
    const float4* src = (const float4*)(afeat + (size_t)i * 16);
    uint2* dst = (uint2*)(afeat_s + (size_t)slot * 16);
#pragma unroll
    for (int q = 0; q < 4; ++q) {
      float4 v = src[q];
      uint2 p;
      p.x = (u32)f2b(v.x) | ((u32)f2b(v.y) << 16);
      p.y = (u32)f2b(v.z) | ((u32)f2b(v.w) << 16);
      dst[q] = p;
    }
  }
}

// edge scatter: FORWARD map eids[slot] = edge id; pre-sort edge_dir into slot order
__global__ __launch_bounds__(256) void kscatter_fwd_dir(const int* __restrict__ keys,
                                                        const int* __restrict__ off, int n,
                                                        int* __restrict__ cnt,
                                                        int* __restrict__ eids,
                                                        const float* __restrict__ dir,
                                                        float* __restrict__ dir_s) {
  int i = blockIdx.x * 256 + threadIdx.x;
  if (i < n) {
    int k = keys[i];
    int slot = off[k] + (atomicSub(&cnt[k], 1) - 1);
    eids[slot] = i;
    dir_s[(size_t)slot * 3 + 0] = dir[(size_t)i * 3 + 0];
    dir_s[(size_t)slot * 3 + 1] = dir[(size_t)i * 3 + 1];
    dir_s[(size_t)slot * 3 + 2] = dir[(size_t)i * 3 + 2];
  }
}

// ---------------- Combined weight prep: all 8 weights, 140 fragments, 1 launch
__global__ __launch_bounds__(256) void kprepw_all(
    const float* __restrict__ Wt1, const float* __restrict__ Wt2,
    const float* __restrict__ Wm1, const float* __restrict__ Wm2,
    const float* __restrict__ Wu1, const float* __restrict__ Wu2,
    const float* __restrict__ Wg1, const float* __restrict__ Wg2,
    u16* __restrict__ Pt1, u16* __restrict__ Pt2,
    u16* __restrict__ Pm1, u16* __restrict__ Pm2,
    u16* __restrict__ Pu1, u16* __restrict__ Pu2,
    u16* __restrict__ Pg1, u16* __restrict__ Pg2) {
  int gid = blockIdx.x * 256 + threadIdx.x;
  int f = gid >> 6, l = gid & 63;
  const float* W; u16* out; int K, N, fl;
  if (f < 20)       { W = Wt1; out = Pt1; K = 144; N = 64;  fl = f; }        // Kp=160
  else if (f < 28)  { W = Wt2; out = Pt2; K = 64;  N = 64;  fl = f - 20; }
  else if (f < 60)  { W = Wm1; out = Pm1; K = 256; N = 64;  fl = f - 28; }
  else if (f < 76)  { W = Wm2; out = Pm2; K = 64;  N = 128; fl = f - 60; }
  else if (f < 100) { W = Wu1; out = Pu1; K = 192; N = 64;  fl = f - 76; }
  else if (f < 108) { W = Wu2; out = Pu2; K = 64;  N = 64;  fl = f - 100; }
  else if (f < 132) { W = Wg1; out = Pg1; K = 192; N = 64;  fl = f - 108; }
  else if (f < 140) { W = Wg2; out = Pg2; K = 64;  N = 64;  fl = f - 132; }
  else return;
  int nt = fl % (N / 16);
  int kt = fl / (N / 16);
  int k0 = kt * 32 + (l >> 4) * 8;
  int n = nt * 16 + (l & 15);
  u16 vals[8];
#pragma unroll
  for (int j = 0; j < 8; ++j) {
    int kk = k0 + j;
    vals[j] = (kk < K) ? f2b(W[(size_t)kk * N + n]) : (u16)0;
  }
  uint4* dst = (uint4*)(out + (size_t)fl * 512 + l * 8);
  uint4 p;
  p.x = (u32)vals[0] | ((u32)vals[1] << 16);
  p.y = (u32)vals[2] | ((u32)vals[3] << 16);
  p.z = (u32)vals[4] | ((u32)vals[5] << 16);
  p.w = (u32)vals[6] | ((u32)vals[7] << 16);
  *dst = p;
}

// ---------------- Kernel T (MFMA, proven): triplet MLP in SLOT order -> tmsg_s contiguous
__global__ __launch_bounds__(256) void ktrip_mfma(
    const int* __restrict__ tkj, const int* __restrict__ tji,
    const u16* __restrict__ erbf_bf, const u16* __restrict__ afeat_s,
    const int* __restrict__ tids,
    const u16* __restrict__ Wp1, const float* __restrict__ b1,
    const u16* __restrict__ Wp2, const float* __restrict__ b2,
    u16* __restrict__ tmsg_s) {
  __shared__ u16 Xs[64 * 192];
  __shared__ u16 Hs[64 * 64];
  const int tid = threadIdx.x;
  const int l = tid & 63;
  const int w = tid >> 6;
  const int st0 = blockIdx.x * 64;

#pragma unroll
  for (int it = 0; it < 4; ++it) {
    int idx = it * 256 + tid;
    int sel = idx >> 9, r = (idx >> 3) & 63, ch = idx & 7;
    int t = tids[st0 + r];
    int node = sel ? tji[t] : tkj[t];
    uint4 vv = *(const uint4*)&erbf_bf[(size_t)node * 64 + ch * 8];
    *(uint4*)&Xs[lx<192>(r, sel * 64 + ch * 8)] = vv;
  }
  {
    int r = tid >> 2, c = (tid & 3) * 4;
    uint2 p2 = *(const uint2*)&afeat_s[(size_t)(st0 + r) * 16 + c];
    *(uint2*)&Xs[lx<192>(r, 128 + c)] = p2;
  }
#pragma unroll
  for (int i = 0; i < 2; ++i) {
    int idx = i * 256 + tid;
    int r = idx >> 3, c = 144 + (idx & 7) * 2;
    *(u32*)&Xs[lx<192>(r, c)] = 0;
  }
  __syncthreads();

  f32x4 acc1[4];
  {
    float bias = b1[w * 16 + (l & 15)];
#pragma unroll
    for (int mt = 0; mt < 4; ++mt) acc1[mt] = (f32x4){bias, bias, bias, bias};
    for (int ks = 0; ks < 5; ++ks) {
      short8 bf = *(const short8*)(Wp1 + ((size_t)(ks * 4 + w) * 64 + l) * 8);
#pragma unroll
      for (int mt = 0; mt < 4; ++mt) {
        short8 af = *(const short8*)&Xs[lx<192>(mt * 16 + (l & 15), ks * 32 + ((l >> 4) << 3))];
        acc1[mt] = __builtin_amdgcn_mfma_f32_16x16x32_bf16(af, bf, acc1[mt], 0, 0, 0);
      }
    }
  }
#pragma unroll
  for (int mt = 0; mt < 4; ++mt)
#pragma unroll
    for (int q = 0; q < 4; ++q) {
      int r = mt * 16 + (l >> 4) * 4 + q;
      Hs[lx<64>(r, w * 16 + (l & 15))] = f2b(silu_f(acc1[mt][q]));
    }
  __syncthreads();

  f32x4 acc2[4];
  {
    float bias = b2[w * 16 + (l & 15)];
#pragma unroll
    for (int mt = 0; mt < 4; ++mt) acc2[mt] = (f32x4){bias, bias, bias, bias};
    for (int ks = 0; ks < 2; ++ks) {
      short8 bf = *(const short8*)(Wp2 + ((size_t)(ks * 4 + w) * 64 + l) * 8);
#pragma unroll
      for (int mt = 0; mt < 4; ++mt) {
        short8 af = *(const short8*)&Hs[lx<64>(mt * 16 + (l & 15), ks * 32 + ((l >> 4) << 3))];
        acc2[mt] = __builtin_amdgcn_mfma_f32_16x16x32_bf16(af, bf, acc2[mt], 0, 0, 0);
      }
    }
  }
  __syncthreads();
#pragma unroll
  for (int mt = 0; mt < 4; ++mt)
#pragma unroll
    for (int q = 0; q < 4; ++q) {
      int r = mt * 16 + (l >> 4) * 4 + q;
      Xs[lx<64>(r, w * 16 + (l & 15))] = f2b(acc2[mt][q]);
    }
  __syncthreads();
  for (int i = 0; i < 2; ++i) {
    int idx = i * 256 + tid;
    int r = idx >> 3, c0 = (idx & 7) << 3;
    uint4 val = *(const uint4*)&Xs[lx<64>(r, c0)];
    *(uint4*)(tmsg_s + (size_t)(st0 + r) * 64 + c0) = val;
  }
}

// ---------------- Kernel M (MFMA): edge MLP in SLOT order -> msg_s contiguous
// e = eids[slot]; gathers indirect; output streams; s[dst] nearly-sequential.
__global__ __launch_bounds__(256) void kmsg_mfma(
    const int* __restrict__ eidx, const u16* __restrict__ s_bf,
    const u16* __restrict__ erbf_bf,
    const int* __restrict__ toff, const u16* __restrict__ tmsg_s,
    const int* __restrict__ eids,
    const u16* __restrict__ Wp1, const float* __restrict__ b1,
    const u16* __restrict__ Wp2, const float* __restrict__ b2,
    u16* __restrict__ msg_s) {
  __shared__ u16 Xs[64 * 256];
  __shared__ u16 Hs[64 * 64];
  const int tid = threadIdx.x;
  const int l = tid & 63;
  const int w = tid >> 6;
  const int sl0 = blockIdx.x * 64;

  // erbf gather cols 128..191: 512 uint4 tasks
#pragma unroll
  for (int i = 0; i < 2; ++i) {
    int idx = i * 256 + tid;
    int r = idx >> 3, c0 = (idx & 7) << 3;
    int e = eids[sl0 + r];
    uint4 vv = *(const uint4*)&erbf_bf[(size_t)e * 64 + c0];
    *(uint4*)&Xs[lx<256>(r, 128 + c0)] = vv;
  }
  // s[src], s[dst] gathers: 1024 tasks
#pragma unroll
  for (int it = 0; it < 4; ++it) {
    int idx = it * 256 + tid;
    int sel = idx >> 9, r = (idx >> 3) & 63, ch = idx & 7;
    int e = eids[sl0 + r];
    int node = eidx[sel * NE + e];
    uint4 vv = *(const uint4*)&s_bf[(size_t)node * 64 + ch * 8];
    *(uint4*)&Xs[lx<256>(r, sel * 64 + ch * 8)] = vv;
  }
  // aagg contiguous CSR sum: 512 tasks
#pragma unroll
  for (int it = 0; it < 2; ++it) {
    int idx = it * 256 + tid;
    int r = idx >> 3, ch = idx & 7;
    int e = eids[sl0 + r];
    int r0 = toff[e], r1 = toff[e + 1];
    float a[8];
#pragma unroll
    for (int j = 0; j < 8; ++j) a[j] = 0.f;
    for (int ri = r0; ri < r1; ++ri) {
      uint4 pk = *(const uint4*)&tmsg_s[(size_t)ri * 64 + ch * 8];
      a[0] += b2f((u16)(pk.x & 0xffff)); a[1] += b2f((u16)(pk.x >> 16));
      a[2] += b2f((u16)(pk.y & 0xffff)); a[3] += b2f((u16)(pk.y >> 16));
      a[4] += b2f((u16)(pk.z & 0xffff)); a[5] += b2f((u16)(pk.z >> 16));
      a[6] += b2f((u16)(pk.w & 0xffff)); a[7] += b2f((u16)(pk.w >> 16));
    }
    uint4 p;
    p.x = (u32)f2b(a[0]) | ((u32)f2b(a[1]) << 16);
    p.y = (u32)f2b(a[2]) | ((u32)f2b(a[3]) << 16);
    p.z = (u32)f2b(a[4]) | ((u32)f2b(a[5]) << 16);
    p.w = (u32)f2b(a[6]) | ((u32)f2b(a[7]) << 16);
    *(uint4*)&Xs[lx<256>(r, 192 + ch * 8)] = p;
  }
  __syncthreads();

  f32x4 acc1[4];
  {
    float bias = b1[w * 16 + (l & 15)];
#pragma unroll
    for (int mt = 0; mt < 4; ++mt) acc1[mt] = (f32x4){bias, bias, bias, bias};
    for (int ks = 0; ks < 8; ++ks) {
      short8 bf = *(const short8*)(Wp1 + ((size_t)(ks * 4 + w) * 64 + l) * 8);
#pragma unroll
      for (int mt = 0; mt < 4; ++mt) {
        short8 af = *(const short8*)&Xs[lx<256>(mt * 16 + (l & 15), ks * 32 + ((l >> 4) << 3))];
        acc1[mt] = __builtin_amdgcn_mfma_f32_16x16x32_bf16(af, bf, acc1[mt], 0, 0, 0);
      }
    }
  }
#pragma unroll
  for (int mt = 0; mt < 4; ++mt)
#pragma unroll
    for (int q = 0; q < 4; ++q) {
      int r = mt * 16 + (l >> 4) * 4 + q;
      Hs[lx<64>(r, w * 16 + (l & 15))] = f2b(silu_f(acc1[mt][q]));
    }
  __syncthreads();

  f32x4 acc2[2][4];
#pragma unroll
  for (int pp = 0; pp < 2; ++pp) {
    int nt = w * 2 + pp;
    float bias = b2[nt * 16 + (l & 15)];
#pragma unroll
    for (int mt = 0; mt < 4; ++mt) acc2[pp][mt] = (f32x4){bias, bias, bias, bias};
    for (int ks = 0; ks < 2; ++ks) {
      short8 bf = *(const short8*)(Wp2 + ((size_t)(ks * 8 + nt) * 64 + l) * 8);
#pragma unroll
      for (int mt = 0; mt < 4; ++mt) {
        short8 af = *(const short8*)&Hs[lx<64>(mt * 16 + (l & 15), ks * 32 + ((l >> 4) << 3))];
        acc2[pp][mt] = __builtin_amdgcn_mfma_f32_16x16x32_bf16(af, bf, acc2[pp][mt], 0, 0, 0);
      }
    }
  }
  __syncthreads();
#pragma unroll
  for (int pp = 0; pp < 2; ++pp)
#pragma unroll
    for (int mt = 0; mt < 4; ++mt)
#pragma unroll
      for (int q = 0; q < 4; ++q) {
        int r = mt * 16 + (l >> 4) * 4 + q;
        Xs[lx<128>(r, (w * 2 + pp) * 16 + (l & 15))] = f2b(acc2[pp][mt][q]);
      }
  __syncthreads();
  // contiguous out copy: 1024 uint4 streams
  for (int i = 0; i < 4; ++i) {
    int idx = i * 256 + tid;
    int r = idx >> 4, c0 = (idx & 15) << 3;
    uint4 val = *(const uint4*)&Xs[lx<128>(r, c0)];
    *(uint4*)(msg_s + (size_t)(sl0 + r) * 128 + c0) = val;
  }
}

// ---------------- Kernel A (proven round 9): streaming CSR reduction, 4 rows/iter
__global__ __launch_bounds__(256) void kagg(
    const int* __restrict__ noff, const u16* __restrict__ msg_s,
    const float* __restrict__ dir_s,
    u16* __restrict__ aggs_bf, float* __restrict__ aggv) {
  const int lane = threadIdx.x & 63;
  const int wv = threadIdx.x >> 6;
  const int n = blockIdx.x * 4 + wv;
  if (n >= NN) return;
  const int r0 = noff[n], r1 = noff[n + 1];
  const int lrow = lane >> 4, lcol = lane & 15;
  const bool is_ms = (lcol < 8);

  float a[8];
  float v0[8], v1[8], v2[8];
#pragma unroll
  for (int j = 0; j < 8; ++j) { a[j] = 0.f; v0[j] = 0.f; v1[j] = 0.f; v2[j] = 0.f; }

  for (int r4 = r0; r4 < r1; r4 += 4) {
    int r = r4 + lrow;
    if (r < r1) {
      uint4 pk = *(const uint4*)&msg_s[(size_t)r * 128 + lcol * 8];
      float x[8];
      x[0] = b2f((u16)(pk.x & 0xffff)); x[1] = b2f((u16)(pk.x >> 16));
      x[2] = b2f((u16)(pk.y & 0xffff)); x[3] = b2f((u16)(pk.y >> 16));
      x[4] = b2f((u16)(pk.z & 0xffff)); x[5] = b2f((u16)(pk.z >> 16));
      x[6] = b2f((u16)(pk.w & 0xffff)); x[7] = b2f((u16)(pk.w >> 16));
      if (is_ms) {
#pragma unroll
        for (int j = 0; j < 8; ++j) a[j] += x[j];
      } else {
        float dx = dir_s[(size_t)r * 3 + 0];
        float dy = dir_s[(size_t)r * 3 + 1];
        float dz = dir_s[(size_t)r * 3 + 2];
#pragma unroll
        for (int j = 0; j < 8; ++j) {
          v0[j] += x[j] * dx; v1[j] += x[j] * dy; v2[j] += x[j] * dz;
        }
      }
    }
  }
#pragma unroll
  for (int j = 0; j < 8; ++j) {
    a[j] += __shfl_xor(a[j], 16);  a[j] += __shfl_xor(a[j], 32);
    v0[j] += __shfl_xor(v0[j], 16); v0[j] += __shfl_xor(v0[j], 32);
    v1[j] += __shfl_xor(v1[j], 16); v1[j] += __shfl_xor(v1[j], 32);
    v2[j] += __shfl_xor(v2[j], 16); v2[j] += __shfl_xor(v2[j], 32);
  }
  if (lrow == 0) {
    if (is_ms) {
      uint4 p;
      p.x = (u32)f2b(a[0]) | ((u32)f2b(a[1]) << 16);
      p.y = (u32)f2b(a[2]) | ((u32)f2b(a[3]) << 16);
      p.z = (u32)f2b(a[4]) | ((u32)f2b(a[5]) << 16);
      p.w = (u32)f2b(a[6]) | ((u32)f2b(a[7]) << 16);
      *(uint4*)&aggs_bf[(size_t)n * 64 + lcol * 8] = p;
    } else {
      int c0 = (lcol - 8) * 8;
      float* av = aggv + (size_t)n * 192 + (size_t)c0 * 3;
      float4 o0 = {v0[0], v1[0], v2[0], v0[1]};
      float4 o1 = {v1[1], v2[1], v0[2], v1[2]};
      float4 o2 = {v2[2], v0[3], v1[3], v2[3]};
      float4 o3 = {v0[4], v1[4], v2[4], v0[5]};
      float4 o4 = {v1[5], v2[5], v0[6], v1[6]};
      float4 o5 = {v2[6], v0[7], v1[7], v2[7]};
      float4* av4 = (float4*)av;
      av4[0] = o0; av4[1] = o1; av4[2] = o2; av4[3] = o3; av4[4] = o4; av4[5] = o5;
    }
  }
}

// ---------------- Kernel N (MFMA, proven round 7)
__global__ __launch_bounds__(256) void knode_mfma(
    const u16* __restrict__ s_bf, const float* __restrict__ v,
    const u16* __restrict__ aggs_bf, const float* __restrict__ aggv,
    const u16* __restrict__ WpU1, const float* __restrict__ bU1,
    const u16* __restrict__ WpU2, const float* __restrict__ bU2,
    const u16* __restrict__ WpG1, const float* __restrict__ bG1,
    const u16* __restrict__ WpG2, const float* __restrict__ bG2,
    const float* __restrict__ lng, const float* __restrict__ lnb,
    float* __restrict__ outs, float* __restrict__ outv) {
  __shared__ __align__(16) char smem[64 * 192 * 2 + 2 * 64 * 64 * 2];  // 40KB
  u16* Xs = (u16*)smem;
  u16* Hu = (u16*)(smem + 64 * 192 * 2);
  u16* Hg = Hu + 64 * 64;
  float* Fs = (float*)smem;

  const int tid = threadIdx.x;
  const int l = tid & 63;
  const int w = tid >> 6;
  const int n0 = blockIdx.x * 64;

  for (int i = 0; i < 2; ++i) {
    int idx = i * 256 + tid;
    int r = idx >> 3, c0 = (idx & 7) << 3;
    int nr = n0 + r; if (nr >= NN) nr = NN - 1;
    uint4 a = *(const uint4*)&s_bf[(size_t)nr * 64 + c0];
    *(uint4*)&Xs[lx<192>(r, c0)] = a;
    uint4 b = *(const uint4*)&aggs_bf[(size_t)nr * 64 + c0];
    *(uint4*)&Xs[lx<192>(r, 64 + c0)] = b;
  }
  for (int it = 0; it < 16; ++it) {
    int idx = it * 256 + tid;
    int r = idx >> 6, c = idx & 63;
    int nr = n0 + r; if (nr >= NN) nr = NN - 1;
    const float* vp = v + (size_t)nr * 192 + c * 3;
    float x = vp[0], y = vp[1], z = vp[2];
    Xs[lx<192>(r, 128 + c)] = f2b(sqrtf(x * x + y * y + z * z));
  }
  __syncthreads();

  f32x4 au[4], ag[4];
  {
    float biu = bU1[w * 16 + (l & 15)], big = bG1[w * 16 + (l & 15)];
#pragma unroll
    for (int mt = 0; mt < 4; ++mt) {
      au[mt] = (f32x4){biu, biu, biu, biu};
      ag[mt] = (f32x4){big, big, big, big};
    }
    for (int ks = 0; ks < 6; ++ks) {
      short8 bu = *(const short8*)(WpU1 + ((size_t)(ks * 4 + w) * 64 + l) * 8);
      short8 bg = *(const short8*)(WpG1 + ((size_t)(ks * 4 + w) * 64 + l) * 8);
#pragma unroll
      for (int mt = 0; mt < 4; ++mt) {
        short8 af = *(const short8*)&Xs[lx<192>(mt * 16 + (l & 15), ks * 32 + ((l >> 4) << 3))];
        au[mt] = __builtin_amdgcn_mfma_f32_16x16x32_bf16(af, bu, au[mt], 0, 0, 0);
        ag[mt] = __builtin_amdgcn_mfma_f32_16x16x32_bf16(af, bg, ag[mt], 0, 0, 0);
      }
    }
  }
#pragma unroll
  for (int mt = 0; mt < 4; ++mt)
#pragma unroll
    for (int q = 0; q < 4; ++q) {
      int r = mt * 16 + (l >> 4) * 4 + q;
      Hu[lx<64>(r, w * 16 + (l & 15))] = f2b(silu_f(au[mt][q]));
      Hg[lx<64>(r, w * 16 + (l & 15))] = f2b(silu_f(ag[mt][q]));
    }
  __syncthreads();

  f32x4 ou[4], og[4];
  {
    float biu = bU2[w * 16 + (l & 15)], big = bG2[w * 16 + (l & 15)];
#pragma unroll
    for (int mt = 0; mt < 4; ++mt) {
      ou[mt] = (f32x4){biu, biu, biu, biu};
      og[mt] = (f32x4){big, big, big, big};
    }
    for (int ks = 0; ks < 2; ++ks) {
      short8 bu = *(const short8*)(WpU2 + ((size_t)(ks * 4 + w) * 64 + l) * 8);
      short8 bg = *(const short8*)(WpG2 + ((size_t)(ks * 4 + w) * 64 + l) * 8);
#pragma unroll
      for (int mt = 0; mt < 4; ++mt) {
        short8 afu = *(const short8*)&Hu[lx<64>(mt * 16 + (l & 15), ks * 32 + ((l >> 4) << 3))];
        ou[mt] = __builtin_amdgcn_mfma_f32_16x16x32_bf16(afu, bu, ou[mt], 0, 0, 0);
        short8 afg = *(const short8*)&Hg[lx<64>(mt * 16 + (l & 15), ks * 32 + ((l >> 4) << 3))];
        og[mt] = __builtin_amdgcn_mfma_f32_16x16x32_bf16(afg, bg, og[mt], 0, 0, 0);
      }
    }
  }
#pragma unroll
  for (int mt = 0; mt < 4; ++mt)
#pragma unroll
    for (int q = 0; q < 4; ++q) {
      int r = mt * 16 + (l >> 4) * 4 + q;
      ou[mt][q] += b2f(Xs[lx<192>(r, w * 16 + (l & 15))]);
    }
  __syncthreads();

#pragma unroll
  for (int mt = 0; mt < 4; ++mt)
#pragma unroll
    for (int q = 0; q < 4; ++q) {
      int r = mt * 16 + (l >> 4) * 4 + q;
      Fs[r * 68 + w * 16 + (l & 15)] = ou[mt][q];
    }
  __syncthreads();
  {
    int r = tid >> 2, c0 = (tid & 3) * 16;
    float xv[16];
#pragma unroll
    for (int j4 = 0; j4 < 4; ++j4) {
      float4 t = *(const float4*)&Fs[r * 68 + c0 + j4 * 4];
      xv[j4 * 4 + 0] = t.x; xv[j4 * 4 + 1] = t.y;
      xv[j4 * 4 + 2] = t.z; xv[j4 * 4 + 3] = t.w;
    }
    float sm = 0.f, sq = 0.f;
#pragma unroll
    for (int j = 0; j < 16; ++j) { sm += xv[j]; sq += xv[j] * xv[j]; }
    sm += __shfl_xor(sm, 1); sq += __shfl_xor(sq, 1);
    sm += __shfl_xor(sm, 2); sq += __shfl_xor(sq, 2);
    float mu = sm * (1.f / 64.f);
    float var = sq * (1.f / 64.f) - mu * mu;
    float rstd = rsqrtf(var + 1e-5f);
    if (n0 + r < NN) {
      float* op = outs + (size_t)(n0 + r) * 64 + c0;
#pragma unroll
      for (int j4 = 0; j4 < 4; ++j4) {
        float4 o;
        float y0 = (xv[j4 * 4 + 0] - mu) * rstd * lng[c0 + j4 * 4 + 0] + lnb[c0 + j4 * 4 + 0];
        float y1 = (xv[j4 * 4 + 1] - mu) * rstd * lng[c0 + j4 * 4 + 1] + lnb[c0 + j4 * 4 + 1];
        float y2 = (xv[j4 * 4 + 2] - mu) * rstd * lng[c0 + j4 * 4 + 2] + lnb[c0 + j4 * 4 + 2];
        float y3 = (xv[j4 * 4 + 3] - mu) * rstd * lng[c0 + j4 * 4 + 3] + lnb[c0 + j4 * 4 + 3];
        o.x = silu_f(y0); o.y = silu_f(y1); o.z = silu_f(y2); o.w = silu_f(y3);
        *(float4*)(op + j4 * 4) = o;
      }
    }
  }
  __syncthreads();

#pragma unroll
  for (int mt = 0; mt < 4; ++mt)
#pragma unroll
    for (int q = 0; q < 4; ++q) {
      int r = mt * 16 + (l >> 4) * 4 + q;
      Fs[r * 68 + w * 16 + (l & 15)] = og[mt][q];
    }
  __syncthreads();
  {
    int r = tid >> 2, c0 = (tid & 3) * 16;
    int nr = n0 + r;
    if (nr < NN) {
      float gate[16];
#pragma unroll
      for (int j = 0; j < 16; ++j) gate[j] = sigm_f(Fs[r * 68 + c0 + j]);
      const float4* vp = (const float4*)(v + (size_t)nr * 192 + c0 * 3);
      const float4* ap = (const float4*)(aggv + (size_t)nr * 192 + c0 * 3);
      float4* op = (float4*)(outv + (size_t)nr * 192 + c0 * 3);
#pragma unroll
      for (int j4 = 0; j4 < 12; ++j4) {
        float4 vv = vp[j4], av = ap[j4], o;
        o.x = vv.x + gate[(j4 * 4 + 0) / 3] * av.x;
        o.y = vv.y + gate[(j4 * 4 + 1) / 3] * av.y;
        o.z = vv.z + gate[(j4 * 4 + 2) / 3] * av.z;
        o.w = vv.w + gate[(j4 * 4 + 3) / 3] * av.w;
        op[j4] = o;
      }
    }
  }
}

extern "C" void kernel_launch(void* const* d_in, const int* in_sizes, int n_in,
                              void* d_out, int out_size, void* d_ws, size_t ws_size,
                              hipStream_t stream) {
  const float* s     = (const float*)d_in[0];
  const float* v     = (const float*)d_in[1];
  const int*   eidx  = (const int*)d_in[2];
  const float* erbf  = (const float*)d_in[3];
  const float* edir  = (const float*)d_in[4];
  const int*   tkj   = (const int*)d_in[5];
  const int*   tji   = (const int*)d_in[6];
  const float* afeat = (const float*)d_in[7];
  const float* W_t1  = (const float*)d_in[8];
  const float* b_t1  = (const float*)d_in[9];
  const float* W_t2  = (const float*)d_in[10];
  const float* b_t2  = (const float*)d_in[11];
  const float* W_m1  = (const float*)d_in[12];
  const float* b_m1  = (const float*)d_in[13];
  const float* W_m2  = (const float*)d_in[14];
  const float* b_m2  = (const float*)d_in[15];
  const float* W_u1  = (const float*)d_in[16];
  const float* b_u1  = (const float*)d_in[17];
  const float* W_u2  = (const float*)d_in[18];
  const float* b_u2  = (const float*)d_in[19];
  const float* W_g1  = (const float*)d_in[20];
  const float* b_g1  = (const float*)d_in[21];
  const float* W_g2  = (const float*)d_in[22];
  const float* b_g2  = (const float*)d_in[23];
  const float* ln_g  = (const float*)d_in[24];
  const float* ln_b  = (const float*)d_in[25];

  char* w = (char*)d_ws;
  auto alloc = [&](size_t bytes) -> char* {
    char* p = w;
    w += (bytes + 255) & ~(size_t)255;
    return p;
  };
  int* toff  = (int*)alloc((size_t)(NE + 1) * 4);
  int* noff  = (int*)alloc((size_t)(NN + 1) * 4);
  int* tcnt  = (int*)alloc((size_t)NE * 4);
  int* ncnt  = (int*)alloc((size_t)NN * 4);
  int* tids  = (int*)alloc((size_t)NT * 4);
  int* eids  = (int*)alloc((size_t)NE * 4);
  int* bsum  = (int*)alloc(2048 * 4);
  float* dir_s = (float*)alloc((size_t)NE * 3 * 4);
  u16* msg_s  = (u16*)alloc((size_t)NE * 128 * 2);
  u16* tmsg_s = (u16*)alloc((size_t)NT * 64 * 2);
  u16* erbf_bf = (u16*)alloc((size_t)NE * 64 * 2);
  u16* s_bf    = (u16*)alloc((size_t)NN * 64 * 2);
  u16* Wp_t1 = (u16*)alloc((size_t)5 * 4 * 512 * 2);
  u16* Wp_t2 = (u16*)alloc((size_t)2 * 4 * 512 * 2);
  u16* Wp_m1 = (u16*)alloc((size_t)8 * 4 * 512 * 2);
  u16* Wp_m2 = (u16*)alloc((size_t)2 * 8 * 512 * 2);
  u16* Wp_u1 = (u16*)alloc((size_t)6 * 4 * 512 * 2);
  u16* Wp_u2 = (u16*)alloc((size_t)2 * 4 * 512 * 2);
  u16* Wp_g1 = (u16*)alloc((size_t)6 * 4 * 512 * 2);
  u16* Wp_g2 = (u16*)alloc((size_t)2 * 4 * 512 * 2);
  u16* afeat_s = msg_s;  // alias: read only by ktrip; msg_s written later by kmsg
  float* aggv = (float*)tmsg_s;  // alias: tmsg_s dead after kmsg
  u16* aggs_bf = tmsg_s + (size_t)NN * 384;

  // tcnt and ncnt are adjacent in the bump allocator: one memset covers both
  hipMemsetAsync(tcnt, 0, (size_t)((char*)(ncnt + NN) - (char*)tcnt), stream);

  kcvt2<<<(NE * 16 + NN * 16 + 255) / 256, 256, 0, stream>>>(erbf, erbf_bf, s, s_bf);
  khist2<<<(NT + NE + 255) / 256, 256, 0, stream>>>(tji, eidx + NE, tcnt, ncnt);

  const int Bt = (NE + 1023) / 1024, Bn = (NN + 1023) / 1024;
  kscan1b<<<Bt + Bn, 256, 0, stream>>>(tcnt, NE, toff, bsum, Bt, ncnt, NN, noff, bsum + 1024);
  kscan2b<<<2, 1024, 0, stream>>>(bsum, Bt, bsum + 1024, Bn);
  kscan3b<<<(NE + 1 + NN + 1 + 255) / 256, 256, 0, stream>>>(toff, bsum, NE, NT,
                                                             noff, bsum + 1024, NN, NE);

  kscatter_inv_afeat<<<(NT + 255) / 256, 256, 0, stream>>>(tji, toff, NT, tcnt, tids,
                                                           afeat, afeat_s);
  kscatter_fwd_dir<<<(NE + 255) / 256, 256, 0, stream>>>(eidx + NE, noff, NE, ncnt, eids,
                                                         edir, dir_s);

  kprepw_all<<<35, 256, 0, stream>>>(W_t1, W_t2, W_m1, W_m2, W_u1, W_u2, W_g1, W_g2,
                                     Wp_t1, Wp_t2, Wp_m1, Wp_m2, Wp_u1, Wp_u2, Wp_g1, Wp_g2);

  ktrip_mfma<<<NT / 64, 256, 0, stream>>>(tkj, tji, erbf_bf, afeat_s, tids,
                                          Wp_t1, b_t1, Wp_t2, b_t2, tmsg_s);
  kmsg_mfma<<<NE / 64, 256, 0, stream>>>(eidx, s_bf, erbf_bf, toff, tmsg_s, eids,
                                         Wp_m1, b_m1, Wp_m2, b_m2, msg_s);
  kagg<<<(NN + 3) / 4, 256, 0, stream>>>(noff, msg_s, dir_s, aggs_bf, aggv);

  float* out_s = (float*)d_out;
  float* out_v = out_s + (size_t)NN * 64;
  knode_mfma<<<(NN + 63) / 64, 256, 0, stream>>>(s_bf, v, aggs_bf, aggv,
                                                 Wp_u1, b_u1, Wp_u2, b_u2,
                                                 Wp_g1, b_g1, Wp_g2, b_g2,
                                                 ln_g, ln_b, out_s, out_v);
}